// Round 11
// baseline (557.823 us; speedup 1.0000x reference)
//
#include <hip/hip_runtime.h>
#include <math.h>

// ---------- common types / helpers ----------
typedef __bf16 bf16x8 __attribute__((ext_vector_type(8)));
typedef float f32x4 __attribute__((ext_vector_type(4)));

#define LOG2E 1.4426950408889634f

__device__ __forceinline__ unsigned short bf16r(float f) {
  unsigned u = __float_as_uint(f);
  u = (u + 0x7fffu + ((u >> 16) & 1u)) >> 16;
  return (unsigned short)u;
}
__device__ __forceinline__ float bf2f(unsigned short h) {
  return __uint_as_float(((unsigned)h) << 16);
}

// async global->LDS, 16B per lane; LDS dest is wave-uniform base + lane*16B (linear)
#define GLOAD16(gsrc, ldst)                                                        \
  __builtin_amdgcn_global_load_lds(                                                \
      (const __attribute__((address_space(1))) void*)(gsrc),                       \
      (__attribute__((address_space(3))) void*)(ldst), 16, 0, 0)

// ---------- fused conversion kernel: all 5 f32->bf16 weight/input converts ----------
__global__ void conv_all(const float* __restrict__ x, const float* __restrict__ wq,
                         const float* __restrict__ wkva, const float* __restrict__ wkvb,
                         const float* __restrict__ wo,
                         unsigned short* __restrict__ xb, unsigned short* __restrict__ wqb,
                         unsigned short* __restrict__ wab, unsigned short* __restrict__ wbb,
                         unsigned short* __restrict__ wob) {
  int bid = blockIdx.x;
  const float* src; unsigned short* dst; long nsrc;
  if (bid < 8192)       {               src = x;    dst = xb;  nsrc = 8388608; }
  else if (bid < 14336) { bid -= 8192;  src = wq;   dst = wqb; nsrc = 6291456; }
  else if (bid < 15616) { bid -= 14336; src = wkva; dst = wab; nsrc = 1179648; } // pad to 640 rows
  else if (bid < 17664) { bid -= 15616; src = wkvb; dst = wbb; nsrc = 2097152; }
  else                  { bid -= 17664; src = wo;   dst = wob; nsrc = 4194304; }
  long i = ((long)bid * 256 + threadIdx.x) * 4;
  ushort4 o;
  if (i < nsrc) {
    float4 v = *(const float4*)&src[i];
    o.x = bf16r(v.x); o.y = bf16r(v.y); o.z = bf16r(v.z); o.w = bf16r(v.w);
  } else {
    o.x = 0; o.y = 0; o.z = 0; o.w = 0;
  }
  *(ushort4*)&dst[i] = o;
}

// =====================================================================
// 8-phase deep-pipelined GEMM (m201-style). BM=256, 8 waves 2Mx4N,
// BK=64, dbuf-2 LDS, 2 K-tiles per iter, 8 phases/iter + odd-nt tail.
// Phase (tau, mh, kh): reads A-quadrant (4 b128) + B k-half (NR b128),
// stages 1-2 64x64 units (1 gload/wave each), MFMA cluster.
// Stage calendar (unit X of tile T+2 staged right after X(T)'s last read):
//   j0: A1,A3(2i+1)  j1: B-first(2i+1)  j2: B-second(2i+1)  j3: A0,A2(2i+2)
//   j4: A1,A3(2i+2)  j5: B-first(2i+2)  j6: B-second(2i+2)  j7: A0,A2(2i+3)
// Waits: vmcnt(2) at each tile start (only prev phase's A pair in flight),
// vmcnt(0) when next tile's stages were skipped. One barrier/phase.
// Odd nt: peeled tail tile (vmcnt(0); 4 barrier-free phases, no staging).
// MODE: 0 f32*alpha; 1 bf16*alpha; 2 bf16 exp2(acc*alpha)+rowsum atomics;
//       4 scatter into q192 [b*16+by][s][192].
// =====================================================================
template <int BN, int MODE>
__global__ __launch_bounds__(512) void gemm8p(
    const unsigned short* __restrict__ A, const unsigned short* __restrict__ B,
    void* __restrict__ Cv, float* __restrict__ laux,
    int Mrows, int K, int lda, int ldb, int ldc, int zs,
    long sAh, long sAl, long sBh, long sBl, long sCh, long sCl, float alpha)
{
  constexpr int BM = 256;
  constexpr int WN = BN / 4;
  constexpr int NR = WN / 16;
  constexpr int BU = BN / 64;
  constexpr int BU1 = (BU + 1) / 2;

  __shared__ unsigned short As[2][BM * 64];
  __shared__ unsigned short Bs[2][BN * 64];

  const int tid = threadIdx.x;
  const int w = tid >> 6, l = tid & 63, lg = l & 15, lh = l >> 4;
  const int wmi = w >> 2, wni = w & 3;
  const int lrow = l >> 3;
  const int swz8 = ((l & 7) ^ lrow) * 8;

  // XCD-bijective chunked swizzle over linearized grid
  const int gx = gridDim.x, gy = gridDim.y;
  const int nwg = gx * gy * gridDim.z;
  int id = blockIdx.x + gx * (blockIdx.y + gy * blockIdx.z);
  if ((nwg & 7) == 0) id = (id & 7) * (nwg >> 3) + (id >> 3);
  const int bx = id % gx;
  const int t1 = id / gx;
  const int by = t1 % gy;
  const int z = t1 / gy;
  const int zh = z >> zs, zl = z & ((1 << zs) - 1);

  const unsigned short* Ab = A + zh * sAh + zl * sAl + (long)(bx * BM) * lda;
  const unsigned short* Bb = B + zh * sBh + zl * sBl + (long)(by * BN) * ldb;

  const int nt = K >> 6;

  auto stA = [&](int T, int u) {
    if (T >= nt) return;
    const int rr = u * 64 + w * 8;
    GLOAD16(Ab + (long)(rr + lrow) * lda + (T << 6) + swz8, &As[T & 1][rr * 64]);
  };
  auto stB = [&](int T, int u) {
    if (T >= nt) return;
    const int rr = u * 64 + w * 8;
    GLOAD16(Bb + (long)(rr + lrow) * ldb + (T << 6) + swz8, &Bs[T & 1][rr * 64]);
  };

  // prologue: tile 0 fully; tile 1 units A0, A2
  stA(0, 0); stA(0, 1); stA(0, 2); stA(0, 3);
#pragma unroll
  for (int u = 0; u < BU; ++u) stB(0, u);
  stA(1, 0); stA(1, 2);

  f32x4 acc[8][NR] = {};

  const int nit = nt >> 1;
  for (int i = 0; i < nit; ++i) {
    const int t0 = 2 * i;
#pragma unroll
    for (int j = 0; j < 8; ++j) {
      const int tau = t0 + (j >> 2);
      const int jj = j & 3;
      const int mh = jj & 1, kh = jj >> 1;
      if (jj == 0) {
        if (tau + 1 < nt) asm volatile("s_waitcnt vmcnt(2)" ::: "memory");
        else              asm volatile("s_waitcnt vmcnt(0)" ::: "memory");
      } else {
        asm volatile("" ::: "memory");
      }
      __builtin_amdgcn_s_barrier();
      // stage per calendar (targets verified dead regions)
      if (j == 0)      { stA(t0 + 1, 1); stA(t0 + 1, 3); }
      else if (j == 1) { for (int u = 0; u < BU1; ++u) stB(t0 + 1, u); }
      else if (j == 2) { for (int u = BU1; u < BU; ++u) stB(t0 + 1, u); }
      else if (j == 3) { stA(t0 + 2, 0); stA(t0 + 2, 2); }
      else if (j == 4) { stA(t0 + 2, 1); stA(t0 + 2, 3); }
      else if (j == 5) { for (int u = 0; u < BU1; ++u) stB(t0 + 2, u); }
      else if (j == 6) { for (int u = BU1; u < BU; ++u) stB(t0 + 2, u); }
      else             { stA(t0 + 3, 0); stA(t0 + 3, 2); }
      const unsigned short* bA = As[tau & 1];
      const unsigned short* bB = Bs[tau & 1];
      const int rswz = ((kh * 4 + lh) ^ (lg & 7)) * 8;
      bf16x8 af[4], bf[NR];
#pragma unroll
      for (int mi = 0; mi < 4; ++mi)
        af[mi] = *(const bf16x8*)&bA[(wmi * 128 + mh * 64 + mi * 16 + lg) * 64 + rswz];
#pragma unroll
      for (int ni = 0; ni < NR; ++ni)
        bf[ni] = *(const bf16x8*)&bB[(wni * WN + ni * 16 + lg) * 64 + rswz];
      __builtin_amdgcn_s_setprio(1);
#pragma unroll
      for (int mi = 0; mi < 4; ++mi)
#pragma unroll
        for (int ni = 0; ni < NR; ++ni)
          acc[mh * 4 + mi][ni] = __builtin_amdgcn_mfma_f32_16x16x32_bf16(
              af[mi], bf[ni], acc[mh * 4 + mi][ni], 0, 0, 0);
      __builtin_amdgcn_s_setprio(0);
    }
  }

  if (nt & 1) {
    // tail tile nt-1: fully staged by the last iteration; drain and compute
    const int tau = nt - 1;
    asm volatile("s_waitcnt vmcnt(0)" ::: "memory");
    __builtin_amdgcn_s_barrier();
    const unsigned short* bA = As[tau & 1];
    const unsigned short* bB = Bs[tau & 1];
#pragma unroll
    for (int jj = 0; jj < 4; ++jj) {
      const int mh = jj & 1, kh = jj >> 1;
      const int rswz = ((kh * 4 + lh) ^ (lg & 7)) * 8;
      bf16x8 af[4], bf[NR];
#pragma unroll
      for (int mi = 0; mi < 4; ++mi)
        af[mi] = *(const bf16x8*)&bA[(wmi * 128 + mh * 64 + mi * 16 + lg) * 64 + rswz];
#pragma unroll
      for (int ni = 0; ni < NR; ++ni)
        bf[ni] = *(const bf16x8*)&bB[(wni * WN + ni * 16 + lg) * 64 + rswz];
      __builtin_amdgcn_s_setprio(1);
#pragma unroll
      for (int mi = 0; mi < 4; ++mi)
#pragma unroll
        for (int ni = 0; ni < NR; ++ni)
          acc[mh * 4 + mi][ni] = __builtin_amdgcn_mfma_f32_16x16x32_bf16(
              af[mi], bf[ni], acc[mh * 4 + mi][ni], 0, 0, 0);
      __builtin_amdgcn_s_setprio(0);
    }
  }

  const int row0 = bx * BM + wmi * 128;
  const int col0 = by * BN + wni * WN;
  const long coff = (long)zh * sCh + (long)zl * sCl;

  if (MODE == 2) {
#pragma unroll
    for (int mi = 0; mi < 8; ++mi)
#pragma unroll
      for (int r = 0; r < 4; ++r) {
        const int row = row0 + mi * 16 + lh * 4 + r;
        float rs = 0.f;
#pragma unroll
        for (int ni = 0; ni < NR; ++ni) {
          float pv = exp2f(acc[mi][ni][r] * alpha);
          ((unsigned short*)Cv)[coff + (long)row * ldc + col0 + ni * 16 + lg] = bf16r(pv);
          rs += pv;
        }
#pragma unroll
        for (int msk = 1; msk < 16; msk <<= 1) rs += __shfl_xor(rs, msk);
        if (lg == 0) atomicAdd(&laux[(long)z * Mrows + row], rs);
      }
  } else if (MODE == 4) {
#pragma unroll
    for (int mi = 0; mi < 8; ++mi)
#pragma unroll
      for (int r = 0; r < 4; ++r) {
        const int row = row0 + mi * 16 + lh * 4 + r;
        unsigned short* dq = (unsigned short*)Cv +
            (long)(row >> 11) * 6291456 + (long)by * 393216 + (long)(row & 2047) * 192;
#pragma unroll
        for (int ni = 0; ni < NR; ++ni)
          dq[wni * WN + ni * 16 + lg] = bf16r(acc[mi][ni][r] * alpha);
      }
  } else {
#pragma unroll
    for (int mi = 0; mi < 8; ++mi)
#pragma unroll
      for (int r = 0; r < 4; ++r) {
        const int row = row0 + mi * 16 + lh * 4 + r;
#pragma unroll
        for (int ni = 0; ni < NR; ++ni) {
          float v = acc[mi][ni][r] * alpha;
          if (MODE == 0)
            ((float*)Cv)[coff + (long)row * ldc + col0 + ni * 16 + lg] = v;
          else
            ((unsigned short*)Cv)[coff + (long)row * ldc + col0 + ni * 16 + lg] = bf16r(v);
        }
      }
  }
}

// ---------- generic 128x128 bf16 GEMM (m97-class), small/odd shapes ----------
template <int MODE>
__global__ __launch_bounds__(256) void gemm_bt2(
    const unsigned short* __restrict__ A, const unsigned short* __restrict__ B,
    void* __restrict__ Cv, float* __restrict__ laux,
    int M, int Nstore, int K, int lda, int ldb, int ldc, int zs,
    long sAh, long sAl, long sBh, long sBl, long sCh, long sCl, float alpha)
{
  __shared__ unsigned short As[128 * 32];
  __shared__ unsigned short Bs[128 * 32];
  const int tid = threadIdx.x;
  const int w = tid >> 6, l = tid & 63, lg = l & 15, lh = l >> 4;

  const int gx = gridDim.x, gy = gridDim.y;
  const int nwg = gx * gy * gridDim.z;
  int id = blockIdx.x + gx * (blockIdx.y + gy * blockIdx.z);
  if ((nwg & 7) == 0) id = (id & 7) * (nwg >> 3) + (id >> 3);
  const int bx = id % gx;
  const int t1 = id / gx;
  const int by = t1 % gy;
  const int z = t1 / gy;

  const int zh = z >> zs, zl = z & ((1 << zs) - 1);
  const unsigned short* Ab = A + zh * sAh + zl * sAl + (long)(bx * 128) * lda;
  const unsigned short* Bb = B + zh * sBh + zl * sBl + (long)(by * 128) * ldb;
  const int srow = l >> 2;
  const int scol = (((l & 3) ^ ((l >> 3) & 3)) * 8);
  const int wm = (w >> 1) * 64, wn = (w & 1) * 64;
  f32x4 acc[4][4] = {};

  const long ra0 = (long)(w * 16 + srow) * lda + scol;
  const long ra1 = (long)(64 + w * 16 + srow) * lda + scol;
  const long rb0 = (long)(w * 16 + srow) * ldb + scol;
  const long rb1 = (long)(64 + w * 16 + srow) * ldb + scol;
  unsigned short* lA0 = &As[(w * 16) * 32];
  unsigned short* lA1 = &As[(64 + w * 16) * 32];
  unsigned short* lB0 = &Bs[(w * 16) * 32];
  unsigned short* lB1 = &Bs[(64 + w * 16) * 32];

  const int rsw = ((lh ^ ((lg >> 1) & 3)) * 8);

  for (int k0 = 0; k0 < K; k0 += 32) {
    __syncthreads();
    GLOAD16(Ab + ra0 + k0, lA0);
    GLOAD16(Ab + ra1 + k0, lA1);
    GLOAD16(Bb + rb0 + k0, lB0);
    GLOAD16(Bb + rb1 + k0, lB1);
    __syncthreads();
    bf16x8 af[4], bfr[4];
#pragma unroll
    for (int m = 0; m < 4; m++) af[m] = *(const bf16x8*)&As[(wm + m * 16 + lg) * 32 + rsw];
#pragma unroll
    for (int n = 0; n < 4; n++) bfr[n] = *(const bf16x8*)&Bs[(wn + n * 16 + lg) * 32 + rsw];
#pragma unroll
    for (int m = 0; m < 4; m++)
#pragma unroll
      for (int n = 0; n < 4; n++)
        acc[m][n] = __builtin_amdgcn_mfma_f32_16x16x32_bf16(af[m], bfr[n], acc[m][n], 0, 0, 0);
  }

  const int row0 = bx * 128 + wm, col0 = by * 128 + wn;
  long coff = zh * sCh + zl * sCl;

#pragma unroll
  for (int m = 0; m < 4; m++)
#pragma unroll
    for (int r = 0; r < 4; r++) {
      const int row = row0 + m * 16 + lh * 4 + r;
#pragma unroll
      for (int n = 0; n < 4; n++) {
        int col = col0 + n * 16 + lg;
        if (col < Nstore) {
          float v = acc[m][n][r] * alpha;
          if (MODE == 0)
            ((float*)Cv)[coff + (long)row * ldc + col] = v;
          else
            ((unsigned short*)Cv)[coff + (long)row * ldc + col] = bf16r(v);
        }
      }
    }
}

// ---------- kv epilogue: tanh-norm -> kvn bf16; roped k_pe -> kh[...][128:192) x16 heads ----
__global__ void kv_epilogue(const float* __restrict__ kvf, const float* __restrict__ fc,
                            const float* __restrict__ fs, const float* __restrict__ alpha,
                            const float* __restrict__ gamma, const float* __restrict__ beta,
                            unsigned short* __restrict__ kvn, unsigned short* __restrict__ kh) {
  const int n = blockIdx.x;
  const int b = n >> 11, s = n & 2047;
  const int tid = threadIdx.x;
  const float a = alpha[0];
  const float* src = kvf + (long)n * 576;
  unsigned short* dst = kvn + (long)n * 512;
#pragma unroll
  for (int c0 = 0; c0 < 512; c0 += 256) {
    int c = c0 + tid;
    float v = tanhf(a * src[c]) * gamma[c] + beta[c];
    dst[c] = bf16r(v);
  }
  if (tid < 32) {
    int i = tid;
    float re = src[512 + 2 * i], im = src[512 + 2 * i + 1];
    float co = fc[s * 32 + i], si = fs[s * 32 + i];
    ushort2 v;
    v.x = bf16r(re * co - im * si);
    v.y = bf16r(re * si + im * co);
#pragma unroll
    for (int h = 0; h < 16; h++)
      *(ushort2*)&kh[((long)(b * 16 + h) * 2048 + s) * 192 + 128 + 2 * i] = v;
  }
}

// ---------- q rope fixup: in-place rotate q192[...][128:192) (values pre-scaled) ----------
__global__ void q_ropefix(unsigned short* __restrict__ q192, const float* __restrict__ fc,
                          const float* __restrict__ fs) {
  const int n = blockIdx.x;
  const int b = n >> 11, s = n & 2047;
  const int tid = threadIdx.x;
  for (int it = tid; it < 512; it += 256) {
    int h = it >> 5, i = it & 31;
    unsigned short* dd = q192 + ((long)(b * 16 + h) * 2048 + s) * 192 + 128 + 2 * i;
    float re = bf2f(dd[0]), im = bf2f(dd[1]);
    float co = fc[s * 32 + i], si = fs[s * 32 + i];
    ushort2 o;
    o.x = bf16r(re * co - im * si);
    o.y = bf16r(re * si + im * co);
    *(ushort2*)dd = o;
  }
}

// ---------- PV reduce: o_b slice = bf16((o_p[0]+o_p[1]) / l) ----------
__global__ void reduce_pv(const float* __restrict__ op, const float* __restrict__ lsum,
                          unsigned short* __restrict__ ob, int c) {
  const long idx = (long)blockIdx.x * 256 + threadIdx.x;
  const int d4 = (int)(idx & 31);
  const int s = (int)((idx >> 5) & 2047);
  const int hh = (int)(idx >> 16);
  const long base = (long)hh * 262144 + (long)s * 128 + d4 * 4;
  float4 a = *(const float4*)&op[base];
  float4 b = *(const float4*)&op[2097152 + base];
  const float inv = 1.0f / lsum[hh * 2048 + s];
  const long row = (long)(c >> 1) * 2048 + s;
  const int col = ((c & 1) * 8 + hh) * 128 + d4 * 4;
  ushort4 o;
  o.x = bf16r((a.x + b.x) * inv);
  o.y = bf16r((a.y + b.y) * inv);
  o.z = bf16r((a.z + b.z) * inv);
  o.w = bf16r((a.w + b.w) * inv);
  *(ushort4*)&ob[row * 2048 + col] = o;
}

__global__ void zerof(float* __restrict__ p, long n) {
  long i = ((long)blockIdx.x * 256 + threadIdx.x) * 4;
  if (i < n) *(float4*)&p[i] = make_float4(0.f, 0.f, 0.f, 0.f);
}

// ---------- host launcher ----------
extern "C" void kernel_launch(void* const* d_in, const int* in_sizes, int n_in,
                              void* d_out, int out_size, void* d_ws, size_t ws_size,
                              hipStream_t stream) {
  const float* x = (const float*)d_in[0];
  const float* fc = (const float*)d_in[1];
  const float* fs = (const float*)d_in[2];
  const float* wq = (const float*)d_in[3];
  const float* wkva = (const float*)d_in[4];
  const float* wkvb = (const float*)d_in[5];
  const float* wo = (const float*)d_in[6];
  const float* alpha = (const float*)d_in[7];
  const float* gamma = (const float*)d_in[8];
  const float* beta = (const float*)d_in[9];
  float* out = (float*)d_out;

  char* p = (char*)d_ws;
  auto take = [&](size_t bytes) {
    char* r = p;
    p += (bytes + 255) & ~(size_t)255;
    return r;
  };
  unsigned short* wqb   = (unsigned short*)take(6291456ull * 2);    // wq bf16 [3072][2048]
  float*          kvf   = (float*)take(2359296ull * 4);             // kv_full f32 [4096][576]
  unsigned short* xb    = (unsigned short*)take(8388608ull * 2);    // x bf16 [4096][2048]
  unsigned short* wab   = (unsigned short*)take(1310720ull * 2);    // wkv_a bf16 padded [640][2048]
  unsigned short* wbb   = (unsigned short*)take(2097152ull * 2);    // wkv_b bf16 [4096][512]
  unsigned short* wob   = (unsigned short*)take(4194304ull * 2);    // wo bf16 [2048][2048]
  unsigned short* kvn   = (unsigned short*)take(2097152ull * 2);    // [4096][512]
  unsigned short* kh    = (unsigned short*)take(12582912ull * 2);   // [32][2048][192]
  unsigned short* q192  = (unsigned short*)take(12582912ull * 2);   // [32][2048][192]
  unsigned short* vhT   = (unsigned short*)take(8388608ull * 2);    // [32][128][2048]
  float*          lsum  = (float*)take(65536ull * 4);               // [32][2048]
  unsigned short* o_b   = (unsigned short*)take(8388608ull * 2);    // [4096][2048]
  unsigned short* P     = (unsigned short*)take(33554432ull * 2);   // [8][2048][2048] chunk
  float*          o_p   = (float*)take(4194304ull * 4 * 2);         // [2][8][2048][128] f32 partials

  const float scale = 1.0f / sqrtf(192.0f);

  // fused conversions
  conv_all<<<21760, 256, 0, stream>>>(x, wq, wkva, wkvb, wo, xb, wqb, wab, wbb, wob);

  // q192 = scale * (x @ wq^T) scattered head-major -- 8-phase 256x192, grid 256
  gemm8p<192, 4><<<dim3(16, 16, 1), 512, 0, stream>>>(
      xb, wqb, q192, nullptr, 4096, 2048, 2048, 2048, 192, 0, 0, 0, 0, 0, 0, 0, scale);
  // kv_full = x @ wkv_a^T (f32)
  gemm_bt2<0><<<dim3(32, 5, 1), 256, 0, stream>>>(xb, wab, kvf, nullptr, 4096, 576, 2048,
                                                  2048, 2048, 576, 0, 0, 0, 0, 0, 0, 0, 1.0f);
  // kvn (tanh-norm) + roped k_pe broadcast into kh[...][128:192)
  kv_epilogue<<<4096, 256, 0, stream>>>(kvf, fc, fs, alpha, gamma, beta, kvn, kh);
  // k_abs[h] = kvn @ wk_h^T -> kh[:, :, 0:128) -- 8-phase 256x128, grid 256
  gemm8p<128, 1><<<dim3(8, 1, 32), 512, 0, stream>>>(
      kvn, wbb, kh, nullptr, 2048, 512, 512, 512, 192, 4,
      1048576, 0, 0, 131072, 6291456, 393216, 1.0f);
  // rope the pe part of q192 in place
  q_ropefix<<<4096, 256, 0, stream>>>(q192, fc, fs);
  // vhT[g] = wv_h @ kvn_b^T   [128][2048]
  gemm_bt2<1><<<dim3(1, 16, 32), 256, 0, stream>>>(wbb + 128 * 512, kvn, vhT, nullptr,
                                                   128, 2048, 512,
                                                   512, 512, 2048, 4,
                                                   0, 131072,
                                                   1048576, 0,
                                                   4194304, 262144,
                                                   1.0f);
  // zero l
  zerof<<<64, 256, 0, stream>>>(lsum, 65536L);

  // attention: 4 chunks of 8 heads
  for (int c = 0; c < 4; c++) {
    const unsigned short* Aq = q192 + (long)c * 8 * 393216;
    const unsigned short* Bk = kh + (long)c * 8 * 393216;
    float* lc = lsum + (long)c * 8 * 2048;
    // QK: P = exp2(q192 @ kh^T * LOG2E) + row-sum atomics -- 8-phase 256x256 (nt=3 w/ tail)
    gemm8p<256, 2><<<dim3(8, 8, 8), 512, 0, stream>>>(
        Aq, Bk, P, lc, 2048, 192, 192, 192, 2048, 3,
        0, 393216, 0, 393216, 0, 4194304, LOG2E);
    // PV K-split: o_p[khalf][head] = P_half @ vhT_half^T -- 8-phase 256x128, K=1024/split
    const unsigned short* Bv = vhT + (long)c * 8 * 262144;
    gemm8p<128, 0><<<dim3(8, 1, 16), 512, 0, stream>>>(
        P, Bv, o_p, nullptr, 2048, 1024, 2048, 2048, 128, 3,
        1024, 4194304, 1024, 262144, 2097152, 262144, 1.0f);
    // reduce partials / l -> o_b slice
    reduce_pv<<<2048, 256, 0, stream>>>(o_p, lc, o_b, c);
  }

  // out = o_b @ wo^T (f32) -- 8-phase 256x128, grid 256
  gemm8p<128, 0><<<dim3(16, 16, 1), 512, 0, stream>>>(
      o_b, wob, out, nullptr, 4096, 2048, 2048, 2048, 2048, 0, 0, 0, 0, 0, 0, 0, 1.0f);
}

// Round 12
// 508.295 us; speedup vs baseline: 1.0974x; 1.0974x over previous
//
#include <hip/hip_runtime.h>
#include <math.h>

// ---------- common types / helpers ----------
typedef __bf16 bf16x8 __attribute__((ext_vector_type(8)));
typedef float f32x4 __attribute__((ext_vector_type(4)));

#define LOG2E 1.4426950408889634f

__device__ __forceinline__ unsigned short bf16r(float f) {
  unsigned u = __float_as_uint(f);
  u = (u + 0x7fffu + ((u >> 16) & 1u)) >> 16;
  return (unsigned short)u;
}
__device__ __forceinline__ float bf2f(unsigned short h) {
  return __uint_as_float(((unsigned)h) << 16);
}

// async global->LDS, 16B per lane; LDS dest is wave-uniform base + lane*16B (linear)
#define GLOAD16(gsrc, ldst)                                                        \
  __builtin_amdgcn_global_load_lds(                                                \
      (const __attribute__((address_space(1))) void*)(gsrc),                       \
      (__attribute__((address_space(3))) void*)(ldst), 16, 0, 0)

// ---------- fused conversion kernel: all 5 f32->bf16 weight/input converts ----------
__global__ void conv_all(const float* __restrict__ x, const float* __restrict__ wq,
                         const float* __restrict__ wkva, const float* __restrict__ wkvb,
                         const float* __restrict__ wo,
                         unsigned short* __restrict__ xb, unsigned short* __restrict__ wqb,
                         unsigned short* __restrict__ wab, unsigned short* __restrict__ wbb,
                         unsigned short* __restrict__ wob) {
  int bid = blockIdx.x;
  const float* src; unsigned short* dst; long nsrc;
  if (bid < 8192)       {               src = x;    dst = xb;  nsrc = 8388608; }
  else if (bid < 14336) { bid -= 8192;  src = wq;   dst = wqb; nsrc = 6291456; }
  else if (bid < 15616) { bid -= 14336; src = wkva; dst = wab; nsrc = 1179648; } // pad to 640 rows
  else if (bid < 17664) { bid -= 15616; src = wkvb; dst = wbb; nsrc = 2097152; }
  else                  { bid -= 17664; src = wo;   dst = wob; nsrc = 4194304; }
  long i = ((long)bid * 256 + threadIdx.x) * 4;
  ushort4 o;
  if (i < nsrc) {
    float4 v = *(const float4*)&src[i];
    o.x = bf16r(v.x); o.y = bf16r(v.y); o.z = bf16r(v.z); o.w = bf16r(v.w);
  } else {
    o.x = 0; o.y = 0; o.z = 0; o.w = 0;
  }
  *(ushort4*)&dst[i] = o;
}

// =====================================================================
// 8-phase deep-pipelined GEMM (m201-style). BM=256, 8 waves 2Mx4N,
// BK=64, dbuf-2 LDS, 2 K-tiles per iter, 8 phases/iter + odd-nt tail.
// Stage calendar (unit X of tile T+2 staged right after X(T)'s last read):
//   j0: A1,A3(2i+1)  j1: B-first(2i+1)  j2: B-second(2i+1)  j3: A0,A2(2i+2)
//   j4: A1,A3(2i+2)  j5: B-first(2i+2)  j6: B-second(2i+2)  j7: A0,A2(2i+3)
// Waits: vmcnt(2) at each tile start; vmcnt(0) before un-prefetched tiles.
// One barrier/phase. BN<=192 keeps acc registers spill-free (BN=256 spilled).
// MODE: 0 f32*alpha; 1 bf16*alpha; 2 bf16 exp2(acc*alpha)+rowsum atomics;
//       4 scatter into q192 [b*16+by][s][192].
// =====================================================================
template <int BN, int MODE>
__global__ __launch_bounds__(512) void gemm8p(
    const unsigned short* __restrict__ A, const unsigned short* __restrict__ B,
    void* __restrict__ Cv, float* __restrict__ laux,
    int Mrows, int K, int lda, int ldb, int ldc, int zs,
    long sAh, long sAl, long sBh, long sBl, long sCh, long sCl, float alpha)
{
  constexpr int BM = 256;
  constexpr int WN = BN / 4;
  constexpr int NR = WN / 16;
  constexpr int BU = BN / 64;
  constexpr int BU1 = (BU + 1) / 2;

  __shared__ unsigned short As[2][BM * 64];
  __shared__ unsigned short Bs[2][BN * 64];

  const int tid = threadIdx.x;
  const int w = tid >> 6, l = tid & 63, lg = l & 15, lh = l >> 4;
  const int wmi = w >> 2, wni = w & 3;
  const int lrow = l >> 3;
  const int swz8 = ((l & 7) ^ lrow) * 8;

  // XCD-bijective chunked swizzle over linearized grid
  const int gx = gridDim.x, gy = gridDim.y;
  const int nwg = gx * gy * gridDim.z;
  int id = blockIdx.x + gx * (blockIdx.y + gy * blockIdx.z);
  if ((nwg & 7) == 0) id = (id & 7) * (nwg >> 3) + (id >> 3);
  const int bx = id % gx;
  const int t1 = id / gx;
  const int by = t1 % gy;
  const int z = t1 / gy;
  const int zh = z >> zs, zl = z & ((1 << zs) - 1);

  const unsigned short* Ab = A + zh * sAh + zl * sAl + (long)(bx * BM) * lda;
  const unsigned short* Bb = B + zh * sBh + zl * sBl + (long)(by * BN) * ldb;

  const int nt = K >> 6;

  auto stA = [&](int T, int u) {
    if (T >= nt) return;
    const int rr = u * 64 + w * 8;
    GLOAD16(Ab + (long)(rr + lrow) * lda + (T << 6) + swz8, &As[T & 1][rr * 64]);
  };
  auto stB = [&](int T, int u) {
    if (T >= nt) return;
    const int rr = u * 64 + w * 8;
    GLOAD16(Bb + (long)(rr + lrow) * ldb + (T << 6) + swz8, &Bs[T & 1][rr * 64]);
  };

  // prologue: tile 0 fully; tile 1 units A0, A2
  stA(0, 0); stA(0, 1); stA(0, 2); stA(0, 3);
#pragma unroll
  for (int u = 0; u < BU; ++u) stB(0, u);
  stA(1, 0); stA(1, 2);

  f32x4 acc[8][NR] = {};

  const int nit = nt >> 1;
  for (int i = 0; i < nit; ++i) {
    const int t0 = 2 * i;
#pragma unroll
    for (int j = 0; j < 8; ++j) {
      const int tau = t0 + (j >> 2);
      const int jj = j & 3;
      const int mh = jj & 1, kh = jj >> 1;
      if (jj == 0) {
        if (tau + 1 < nt) asm volatile("s_waitcnt vmcnt(2)" ::: "memory");
        else              asm volatile("s_waitcnt vmcnt(0)" ::: "memory");
      } else {
        asm volatile("" ::: "memory");
      }
      __builtin_amdgcn_s_barrier();
      // stage per calendar (targets verified dead regions)
      if (j == 0)      { stA(t0 + 1, 1); stA(t0 + 1, 3); }
      else if (j == 1) { for (int u = 0; u < BU1; ++u) stB(t0 + 1, u); }
      else if (j == 2) { for (int u = BU1; u < BU; ++u) stB(t0 + 1, u); }
      else if (j == 3) { stA(t0 + 2, 0); stA(t0 + 2, 2); }
      else if (j == 4) { stA(t0 + 2, 1); stA(t0 + 2, 3); }
      else if (j == 5) { for (int u = 0; u < BU1; ++u) stB(t0 + 2, u); }
      else if (j == 6) { for (int u = BU1; u < BU; ++u) stB(t0 + 2, u); }
      else             { stA(t0 + 3, 0); stA(t0 + 3, 2); }
      const unsigned short* bA = As[tau & 1];
      const unsigned short* bB = Bs[tau & 1];
      const int rswz = ((kh * 4 + lh) ^ (lg & 7)) * 8;
      bf16x8 af[4], bf[NR];
#pragma unroll
      for (int mi = 0; mi < 4; ++mi)
        af[mi] = *(const bf16x8*)&bA[(wmi * 128 + mh * 64 + mi * 16 + lg) * 64 + rswz];
#pragma unroll
      for (int ni = 0; ni < NR; ++ni)
        bf[ni] = *(const bf16x8*)&bB[(wni * WN + ni * 16 + lg) * 64 + rswz];
      __builtin_amdgcn_s_setprio(1);
#pragma unroll
      for (int mi = 0; mi < 4; ++mi)
#pragma unroll
        for (int ni = 0; ni < NR; ++ni)
          acc[mh * 4 + mi][ni] = __builtin_amdgcn_mfma_f32_16x16x32_bf16(
              af[mi], bf[ni], acc[mh * 4 + mi][ni], 0, 0, 0);
      __builtin_amdgcn_s_setprio(0);
    }
  }

  if (nt & 1) {
    // tail tile nt-1: fully staged by the last iteration; drain and compute
    const int tau = nt - 1;
    asm volatile("s_waitcnt vmcnt(0)" ::: "memory");
    __builtin_amdgcn_s_barrier();
    const unsigned short* bA = As[tau & 1];
    const unsigned short* bB = Bs[tau & 1];
#pragma unroll
    for (int jj = 0; jj < 4; ++jj) {
      const int mh = jj & 1, kh = jj >> 1;
      const int rswz = ((kh * 4 + lh) ^ (lg & 7)) * 8;
      bf16x8 af[4], bf[NR];
#pragma unroll
      for (int mi = 0; mi < 4; ++mi)
        af[mi] = *(const bf16x8*)&bA[(wmi * 128 + mh * 64 + mi * 16 + lg) * 64 + rswz];
#pragma unroll
      for (int ni = 0; ni < NR; ++ni)
        bf[ni] = *(const bf16x8*)&bB[(wni * WN + ni * 16 + lg) * 64 + rswz];
      __builtin_amdgcn_s_setprio(1);
#pragma unroll
      for (int mi = 0; mi < 4; ++mi)
#pragma unroll
        for (int ni = 0; ni < NR; ++ni)
          acc[mh * 4 + mi][ni] = __builtin_amdgcn_mfma_f32_16x16x32_bf16(
              af[mi], bf[ni], acc[mh * 4 + mi][ni], 0, 0, 0);
      __builtin_amdgcn_s_setprio(0);
    }
  }

  const int row0 = bx * BM + wmi * 128;
  const int col0 = by * BN + wni * WN;
  const long coff = (long)zh * sCh + (long)zl * sCl;

  if (MODE == 2) {
#pragma unroll
    for (int mi = 0; mi < 8; ++mi)
#pragma unroll
      for (int r = 0; r < 4; ++r) {
        const int row = row0 + mi * 16 + lh * 4 + r;
        float rs = 0.f;
#pragma unroll
        for (int ni = 0; ni < NR; ++ni) {
          float pv = exp2f(acc[mi][ni][r] * alpha);
          ((unsigned short*)Cv)[coff + (long)row * ldc + col0 + ni * 16 + lg] = bf16r(pv);
          rs += pv;
        }
#pragma unroll
        for (int msk = 1; msk < 16; msk <<= 1) rs += __shfl_xor(rs, msk);
        if (lg == 0) atomicAdd(&laux[(long)z * Mrows + row], rs);
      }
  } else if (MODE == 4) {
#pragma unroll
    for (int mi = 0; mi < 8; ++mi)
#pragma unroll
      for (int r = 0; r < 4; ++r) {
        const int row = row0 + mi * 16 + lh * 4 + r;
        unsigned short* dq = (unsigned short*)Cv +
            (long)(row >> 11) * 6291456 + (long)by * 393216 + (long)(row & 2047) * 192;
#pragma unroll
        for (int ni = 0; ni < NR; ++ni)
          dq[wni * WN + ni * 16 + lg] = bf16r(acc[mi][ni][r] * alpha);
      }
  } else {
#pragma unroll
    for (int mi = 0; mi < 8; ++mi)
#pragma unroll
      for (int r = 0; r < 4; ++r) {
        const int row = row0 + mi * 16 + lh * 4 + r;
#pragma unroll
        for (int ni = 0; ni < NR; ++ni) {
          float v = acc[mi][ni][r] * alpha;
          if (MODE == 0)
            ((float*)Cv)[coff + (long)row * ldc + col0 + ni * 16 + lg] = v;
          else
            ((unsigned short*)Cv)[coff + (long)row * ldc + col0 + ni * 16 + lg] = bf16r(v);
        }
      }
  }
}

// ---------- generic 128x128 bf16 GEMM (m97-class), small/odd shapes ----------
template <int MODE>
__global__ __launch_bounds__(256) void gemm_bt2(
    const unsigned short* __restrict__ A, const unsigned short* __restrict__ B,
    void* __restrict__ Cv, float* __restrict__ laux,
    int M, int Nstore, int K, int lda, int ldb, int ldc, int zs,
    long sAh, long sAl, long sBh, long sBl, long sCh, long sCl, float alpha)
{
  __shared__ unsigned short As[128 * 32];
  __shared__ unsigned short Bs[128 * 32];
  const int tid = threadIdx.x;
  const int w = tid >> 6, l = tid & 63, lg = l & 15, lh = l >> 4;

  const int gx = gridDim.x, gy = gridDim.y;
  const int nwg = gx * gy * gridDim.z;
  int id = blockIdx.x + gx * (blockIdx.y + gy * blockIdx.z);
  if ((nwg & 7) == 0) id = (id & 7) * (nwg >> 3) + (id >> 3);
  const int bx = id % gx;
  const int t1 = id / gx;
  const int by = t1 % gy;
  const int z = t1 / gy;

  const int zh = z >> zs, zl = z & ((1 << zs) - 1);
  const unsigned short* Ab = A + zh * sAh + zl * sAl + (long)(bx * 128) * lda;
  const unsigned short* Bb = B + zh * sBh + zl * sBl + (long)(by * 128) * ldb;
  const int srow = l >> 2;
  const int scol = (((l & 3) ^ ((l >> 3) & 3)) * 8);
  const int wm = (w >> 1) * 64, wn = (w & 1) * 64;
  f32x4 acc[4][4] = {};

  const long ra0 = (long)(w * 16 + srow) * lda + scol;
  const long ra1 = (long)(64 + w * 16 + srow) * lda + scol;
  const long rb0 = (long)(w * 16 + srow) * ldb + scol;
  const long rb1 = (long)(64 + w * 16 + srow) * ldb + scol;
  unsigned short* lA0 = &As[(w * 16) * 32];
  unsigned short* lA1 = &As[(64 + w * 16) * 32];
  unsigned short* lB0 = &Bs[(w * 16) * 32];
  unsigned short* lB1 = &Bs[(64 + w * 16) * 32];

  const int rsw = ((lh ^ ((lg >> 1) & 3)) * 8);

  for (int k0 = 0; k0 < K; k0 += 32) {
    __syncthreads();
    GLOAD16(Ab + ra0 + k0, lA0);
    GLOAD16(Ab + ra1 + k0, lA1);
    GLOAD16(Bb + rb0 + k0, lB0);
    GLOAD16(Bb + rb1 + k0, lB1);
    __syncthreads();
    bf16x8 af[4], bfr[4];
#pragma unroll
    for (int m = 0; m < 4; m++) af[m] = *(const bf16x8*)&As[(wm + m * 16 + lg) * 32 + rsw];
#pragma unroll
    for (int n = 0; n < 4; n++) bfr[n] = *(const bf16x8*)&Bs[(wn + n * 16 + lg) * 32 + rsw];
#pragma unroll
    for (int m = 0; m < 4; m++)
#pragma unroll
      for (int n = 0; n < 4; n++)
        acc[m][n] = __builtin_amdgcn_mfma_f32_16x16x32_bf16(af[m], bfr[n], acc[m][n], 0, 0, 0);
  }

  const int row0 = bx * 128 + wm, col0 = by * 128 + wn;
  long coff = zh * sCh + zl * sCl;

#pragma unroll
  for (int m = 0; m < 4; m++)
#pragma unroll
    for (int r = 0; r < 4; r++) {
      const int row = row0 + m * 16 + lh * 4 + r;
#pragma unroll
      for (int n = 0; n < 4; n++) {
        int col = col0 + n * 16 + lg;
        if (col < Nstore) {
          float v = acc[m][n][r] * alpha;
          if (MODE == 0)
            ((float*)Cv)[coff + (long)row * ldc + col] = v;
          else
            ((unsigned short*)Cv)[coff + (long)row * ldc + col] = bf16r(v);
        }
      }
    }
}

// ---------- kv epilogue: tanh-norm -> kvn bf16; roped k_pe -> kh[...][128:192) x16 heads ----
__global__ void kv_epilogue(const float* __restrict__ kvf, const float* __restrict__ fc,
                            const float* __restrict__ fs, const float* __restrict__ alpha,
                            const float* __restrict__ gamma, const float* __restrict__ beta,
                            unsigned short* __restrict__ kvn, unsigned short* __restrict__ kh) {
  const int n = blockIdx.x;
  const int b = n >> 11, s = n & 2047;
  const int tid = threadIdx.x;
  const float a = alpha[0];
  const float* src = kvf + (long)n * 576;
  unsigned short* dst = kvn + (long)n * 512;
#pragma unroll
  for (int c0 = 0; c0 < 512; c0 += 256) {
    int c = c0 + tid;
    float v = tanhf(a * src[c]) * gamma[c] + beta[c];
    dst[c] = bf16r(v);
  }
  if (tid < 32) {
    int i = tid;
    float re = src[512 + 2 * i], im = src[512 + 2 * i + 1];
    float co = fc[s * 32 + i], si = fs[s * 32 + i];
    ushort2 v;
    v.x = bf16r(re * co - im * si);
    v.y = bf16r(re * si + im * co);
#pragma unroll
    for (int h = 0; h < 16; h++)
      *(ushort2*)&kh[((long)(b * 16 + h) * 2048 + s) * 192 + 128 + 2 * i] = v;
  }
}

// ---------- q rope fixup: in-place rotate q192[...][128:192) (values pre-scaled) ----------
__global__ void q_ropefix(unsigned short* __restrict__ q192, const float* __restrict__ fc,
                          const float* __restrict__ fs) {
  const int n = blockIdx.x;
  const int b = n >> 11, s = n & 2047;
  const int tid = threadIdx.x;
  for (int it = tid; it < 512; it += 256) {
    int h = it >> 5, i = it & 31;
    unsigned short* dd = q192 + ((long)(b * 16 + h) * 2048 + s) * 192 + 128 + 2 * i;
    float re = bf2f(dd[0]), im = bf2f(dd[1]);
    float co = fc[s * 32 + i], si = fs[s * 32 + i];
    ushort2 o;
    o.x = bf16r(re * co - im * si);
    o.y = bf16r(re * si + im * co);
    *(ushort2*)dd = o;
  }
}

// ---------- PV reduce: o_b slice = bf16((o_p[0..3]) / l) ----------
__global__ void reduce_pv(const float* __restrict__ op, const float* __restrict__ lsum,
                          unsigned short* __restrict__ ob, int c) {
  const long idx = (long)blockIdx.x * 256 + threadIdx.x;   // [8][2048][32] float4 units
  const int d4 = (int)(idx & 31);
  const int s = (int)((idx >> 5) & 2047);
  const int hh = (int)(idx >> 16);
  const long base = (long)hh * 262144 + (long)s * 128 + d4 * 4;
  float4 a = *(const float4*)&op[base];
  float4 b = *(const float4*)&op[2097152 + base];
  float4 e = *(const float4*)&op[2 * 2097152 + base];
  float4 d = *(const float4*)&op[3 * 2097152 + base];
  const float inv = 1.0f / lsum[hh * 2048 + s];
  const long row = (long)(c >> 1) * 2048 + s;
  const int col = ((c & 1) * 8 + hh) * 128 + d4 * 4;
  ushort4 o;
  o.x = bf16r((a.x + b.x + e.x + d.x) * inv);
  o.y = bf16r((a.y + b.y + e.y + d.y) * inv);
  o.z = bf16r((a.z + b.z + e.z + d.z) * inv);
  o.w = bf16r((a.w + b.w + e.w + d.w) * inv);
  *(ushort4*)&ob[row * 2048 + col] = o;
}

__global__ void zerof(float* __restrict__ p, long n) {
  long i = ((long)blockIdx.x * 256 + threadIdx.x) * 4;
  if (i < n) *(float4*)&p[i] = make_float4(0.f, 0.f, 0.f, 0.f);
}

// ---------- host launcher ----------
extern "C" void kernel_launch(void* const* d_in, const int* in_sizes, int n_in,
                              void* d_out, int out_size, void* d_ws, size_t ws_size,
                              hipStream_t stream) {
  const float* x = (const float*)d_in[0];
  const float* fc = (const float*)d_in[1];
  const float* fs = (const float*)d_in[2];
  const float* wq = (const float*)d_in[3];
  const float* wkva = (const float*)d_in[4];
  const float* wkvb = (const float*)d_in[5];
  const float* wo = (const float*)d_in[6];
  const float* alpha = (const float*)d_in[7];
  const float* gamma = (const float*)d_in[8];
  const float* beta = (const float*)d_in[9];
  float* out = (float*)d_out;

  char* p = (char*)d_ws;
  auto take = [&](size_t bytes) {
    char* r = p;
    p += (bytes + 255) & ~(size_t)255;
    return r;
  };
  unsigned short* wqb   = (unsigned short*)take(6291456ull * 2);    // wq bf16 [3072][2048]
  float*          kvf   = (float*)take(2359296ull * 4);             // kv_full f32 [4096][576]
  unsigned short* xb    = (unsigned short*)take(8388608ull * 2);    // x bf16 [4096][2048]
  unsigned short* wab   = (unsigned short*)take(1310720ull * 2);    // wkv_a bf16 padded [640][2048]
  unsigned short* wbb   = (unsigned short*)take(2097152ull * 2);    // wkv_b bf16 [4096][512]
  unsigned short* wob   = (unsigned short*)take(4194304ull * 2);    // wo bf16 [2048][2048]
  unsigned short* kvn   = (unsigned short*)take(2097152ull * 2);    // [4096][512]
  unsigned short* kh    = (unsigned short*)take(12582912ull * 2);   // [32][2048][192]
  unsigned short* q192  = (unsigned short*)take(12582912ull * 2);   // [32][2048][192]
  unsigned short* vhT   = (unsigned short*)take(8388608ull * 2);    // [32][128][2048]
  float*          lsum  = (float*)take(65536ull * 4);               // [32][2048]
  unsigned short* o_b   = (unsigned short*)take(8388608ull * 2);    // [4096][2048]
  unsigned short* P     = (unsigned short*)take(33554432ull * 2);   // [8][2048][2048] chunk
  float*          o_p   = (float*)take(8388608ull * 4);             // [4][8][2048][128] f32 partials

  const float scale = 1.0f / sqrtf(192.0f);

  // fused conversions
  conv_all<<<21760, 256, 0, stream>>>(x, wq, wkva, wkvb, wo, xb, wqb, wab, wbb, wob);

  // q192 = scale * (x @ wq^T) scattered head-major -- 8-phase 256x192, grid 256
  gemm8p<192, 4><<<dim3(16, 16, 1), 512, 0, stream>>>(
      xb, wqb, q192, nullptr, 4096, 2048, 2048, 2048, 192, 0, 0, 0, 0, 0, 0, 0, scale);
  // kv_full = x @ wkv_a^T (f32)
  gemm_bt2<0><<<dim3(32, 5, 1), 256, 0, stream>>>(xb, wab, kvf, nullptr, 4096, 576, 2048,
                                                  2048, 2048, 576, 0, 0, 0, 0, 0, 0, 0, 1.0f);
  // kvn (tanh-norm) + roped k_pe broadcast into kh[...][128:192)
  kv_epilogue<<<4096, 256, 0, stream>>>(kvf, fc, fs, alpha, gamma, beta, kvn, kh);
  // k_abs[h] = kvn @ wk_h^T -> kh[:, :, 0:128) -- 8-phase 256x128, grid 256
  gemm8p<128, 1><<<dim3(8, 1, 32), 512, 0, stream>>>(
      kvn, wbb, kh, nullptr, 2048, 512, 512, 512, 192, 4,
      1048576, 0, 0, 131072, 6291456, 393216, 1.0f);
  // rope the pe part of q192 in place
  q_ropefix<<<4096, 256, 0, stream>>>(q192, fc, fs);
  // vhT[g] = wv_h @ kvn_b^T   [128][2048]
  gemm_bt2<1><<<dim3(1, 16, 32), 256, 0, stream>>>(wbb + 128 * 512, kvn, vhT, nullptr,
                                                   128, 2048, 512,
                                                   512, 512, 2048, 4,
                                                   0, 131072,
                                                   1048576, 0,
                                                   4194304, 262144,
                                                   1.0f);
  // zero l
  zerof<<<64, 256, 0, stream>>>(lsum, 65536L);

  // attention: 4 chunks of 8 heads
  for (int c = 0; c < 4; c++) {
    const unsigned short* Aq = q192 + (long)c * 8 * 393216;
    const unsigned short* Bk = kh + (long)c * 8 * 393216;
    float* lc = lsum + (long)c * 8 * 2048;
    // QK: P = exp2(q192 @ kh^T * LOG2E) + row-sum atomics -- 8-phase 256x128, grid 1024
    gemm8p<128, 2><<<dim3(8, 16, 8), 512, 0, stream>>>(
        Aq, Bk, P, lc, 2048, 192, 192, 192, 2048, 3,
        0, 393216, 0, 393216, 0, 4194304, LOG2E);
    // PV 4-way K-split: o_p[kq][head] = P_q @ vhT_q^T -- 8-phase 256x128, grid 256 (nt=8)
    const unsigned short* Bv = vhT + (long)c * 8 * 262144;
    gemm8p<128, 0><<<dim3(8, 1, 32), 512, 0, stream>>>(
        P, Bv, o_p, nullptr, 2048, 512, 2048, 2048, 128, 3,
        512, 4194304, 512, 262144, 2097152, 262144, 1.0f);
    // reduce partials / l -> o_b slice
    reduce_pv<<<2048, 256, 0, stream>>>(o_p, lc, o_b, c);
  }

  // out = o_b @ wo^T (f32) -- 8-phase 256x128, grid 256
  gemm8p<128, 0><<<dim3(16, 16, 1), 512, 0, stream>>>(
      o_b, wob, out, nullptr, 4096, 2048, 2048, 2048, 2048, 0, 0, 0, 0, 0, 0, 0, 1.0f);
}

// Round 13
// 460.264 us; speedup vs baseline: 1.2120x; 1.1044x over previous
//
#include <hip/hip_runtime.h>
#include <math.h>

// ---------- common types / helpers ----------
typedef __bf16 bf16x8 __attribute__((ext_vector_type(8)));
typedef float f32x4 __attribute__((ext_vector_type(4)));

#define LOG2E 1.4426950408889634f

__device__ __forceinline__ unsigned short bf16r(float f) {
  unsigned u = __float_as_uint(f);
  u = (u + 0x7fffu + ((u >> 16) & 1u)) >> 16;
  return (unsigned short)u;
}
__device__ __forceinline__ float bf2f(unsigned short h) {
  return __uint_as_float(((unsigned)h) << 16);
}

// async global->LDS, 16B per lane; LDS dest is wave-uniform base + lane*16B (linear)
#define GLOAD16(gsrc, ldst)                                                        \
  __builtin_amdgcn_global_load_lds(                                                \
      (const __attribute__((address_space(1))) void*)(gsrc),                       \
      (__attribute__((address_space(3))) void*)(ldst), 16, 0, 0)

// ---------- fused conversion kernel: all 5 f32->bf16 weight/input converts ----------
__global__ void conv_all(const float* __restrict__ x, const float* __restrict__ wq,
                         const float* __restrict__ wkva, const float* __restrict__ wkvb,
                         const float* __restrict__ wo,
                         unsigned short* __restrict__ xb, unsigned short* __restrict__ wqb,
                         unsigned short* __restrict__ wab, unsigned short* __restrict__ wbb,
                         unsigned short* __restrict__ wob) {
  int bid = blockIdx.x;
  const float* src; unsigned short* dst; long nsrc;
  if (bid < 8192)       {               src = x;    dst = xb;  nsrc = 8388608; }
  else if (bid < 14336) { bid -= 8192;  src = wq;   dst = wqb; nsrc = 6291456; }
  else if (bid < 15616) { bid -= 14336; src = wkva; dst = wab; nsrc = 1179648; } // pad to 640 rows
  else if (bid < 17664) { bid -= 15616; src = wkvb; dst = wbb; nsrc = 2097152; }
  else                  { bid -= 17664; src = wo;   dst = wob; nsrc = 4194304; }
  long i = ((long)bid * 256 + threadIdx.x) * 4;
  ushort4 o;
  if (i < nsrc) {
    float4 v = *(const float4*)&src[i];
    o.x = bf16r(v.x); o.y = bf16r(v.y); o.z = bf16r(v.z); o.w = bf16r(v.w);
  } else {
    o.x = 0; o.y = 0; o.z = 0; o.w = 0;
  }
  *(ushort4*)&dst[i] = o;
}

// =====================================================================
// 8-phase deep-pipelined GEMM (m201-style). BM=256, 8 waves 2Mx4N,
// BK=64, dbuf-2 LDS, 2 K-tiles per iter + odd-nt tail. (q-proj, out-proj)
// MODE: 0 f32*alpha; 4 scatter into q192 [b*16+by][s][192].
// =====================================================================
template <int BN, int MODE>
__global__ __launch_bounds__(512) void gemm8p(
    const unsigned short* __restrict__ A, const unsigned short* __restrict__ B,
    void* __restrict__ Cv, float* __restrict__ laux,
    int Mrows, int K, int lda, int ldb, int ldc, int zs,
    long sAh, long sAl, long sBh, long sBl, long sCh, long sCl, float alpha)
{
  constexpr int BM = 256;
  constexpr int WN = BN / 4;
  constexpr int NR = WN / 16;
  constexpr int BU = BN / 64;
  constexpr int BU1 = (BU + 1) / 2;

  __shared__ unsigned short As[2][BM * 64];
  __shared__ unsigned short Bs[2][BN * 64];

  const int tid = threadIdx.x;
  const int w = tid >> 6, l = tid & 63, lg = l & 15, lh = l >> 4;
  const int wmi = w >> 2, wni = w & 3;
  const int lrow = l >> 3;
  const int swz8 = ((l & 7) ^ lrow) * 8;

  const int gx = gridDim.x, gy = gridDim.y;
  const int nwg = gx * gy * gridDim.z;
  int id = blockIdx.x + gx * (blockIdx.y + gy * blockIdx.z);
  if ((nwg & 7) == 0) id = (id & 7) * (nwg >> 3) + (id >> 3);
  const int bx = id % gx;
  const int t1 = id / gx;
  const int by = t1 % gy;
  const int z = t1 / gy;
  const int zh = z >> zs, zl = z & ((1 << zs) - 1);

  const unsigned short* Ab = A + zh * sAh + zl * sAl + (long)(bx * BM) * lda;
  const unsigned short* Bb = B + zh * sBh + zl * sBl + (long)(by * BN) * ldb;

  const int nt = K >> 6;

  auto stA = [&](int T, int u) {
    if (T >= nt) return;
    const int rr = u * 64 + w * 8;
    GLOAD16(Ab + (long)(rr + lrow) * lda + (T << 6) + swz8, &As[T & 1][rr * 64]);
  };
  auto stB = [&](int T, int u) {
    if (T >= nt) return;
    const int rr = u * 64 + w * 8;
    GLOAD16(Bb + (long)(rr + lrow) * ldb + (T << 6) + swz8, &Bs[T & 1][rr * 64]);
  };

  stA(0, 0); stA(0, 1); stA(0, 2); stA(0, 3);
#pragma unroll
  for (int u = 0; u < BU; ++u) stB(0, u);
  stA(1, 0); stA(1, 2);

  f32x4 acc[8][NR] = {};

  const int nit = nt >> 1;
  for (int i = 0; i < nit; ++i) {
    const int t0 = 2 * i;
#pragma unroll
    for (int j = 0; j < 8; ++j) {
      const int tau = t0 + (j >> 2);
      const int jj = j & 3;
      const int mh = jj & 1, kh = jj >> 1;
      if (jj == 0) {
        if (tau + 1 < nt) asm volatile("s_waitcnt vmcnt(2)" ::: "memory");
        else              asm volatile("s_waitcnt vmcnt(0)" ::: "memory");
      } else {
        asm volatile("" ::: "memory");
      }
      __builtin_amdgcn_s_barrier();
      if (j == 0)      { stA(t0 + 1, 1); stA(t0 + 1, 3); }
      else if (j == 1) { for (int u = 0; u < BU1; ++u) stB(t0 + 1, u); }
      else if (j == 2) { for (int u = BU1; u < BU; ++u) stB(t0 + 1, u); }
      else if (j == 3) { stA(t0 + 2, 0); stA(t0 + 2, 2); }
      else if (j == 4) { stA(t0 + 2, 1); stA(t0 + 2, 3); }
      else if (j == 5) { for (int u = 0; u < BU1; ++u) stB(t0 + 2, u); }
      else if (j == 6) { for (int u = BU1; u < BU; ++u) stB(t0 + 2, u); }
      else             { stA(t0 + 3, 0); stA(t0 + 3, 2); }
      const unsigned short* bA = As[tau & 1];
      const unsigned short* bB = Bs[tau & 1];
      const int rswz = ((kh * 4 + lh) ^ (lg & 7)) * 8;
      bf16x8 af[4], bf[NR];
#pragma unroll
      for (int mi = 0; mi < 4; ++mi)
        af[mi] = *(const bf16x8*)&bA[(wmi * 128 + mh * 64 + mi * 16 + lg) * 64 + rswz];
#pragma unroll
      for (int ni = 0; ni < NR; ++ni)
        bf[ni] = *(const bf16x8*)&bB[(wni * WN + ni * 16 + lg) * 64 + rswz];
      __builtin_amdgcn_s_setprio(1);
#pragma unroll
      for (int mi = 0; mi < 4; ++mi)
#pragma unroll
        for (int ni = 0; ni < NR; ++ni)
          acc[mh * 4 + mi][ni] = __builtin_amdgcn_mfma_f32_16x16x32_bf16(
              af[mi], bf[ni], acc[mh * 4 + mi][ni], 0, 0, 0);
      __builtin_amdgcn_s_setprio(0);
    }
  }

  if (nt & 1) {
    const int tau = nt - 1;
    asm volatile("s_waitcnt vmcnt(0)" ::: "memory");
    __builtin_amdgcn_s_barrier();
    const unsigned short* bA = As[tau & 1];
    const unsigned short* bB = Bs[tau & 1];
#pragma unroll
    for (int jj = 0; jj < 4; ++jj) {
      const int mh = jj & 1, kh = jj >> 1;
      const int rswz = ((kh * 4 + lh) ^ (lg & 7)) * 8;
      bf16x8 af[4], bf[NR];
#pragma unroll
      for (int mi = 0; mi < 4; ++mi)
        af[mi] = *(const bf16x8*)&bA[(wmi * 128 + mh * 64 + mi * 16 + lg) * 64 + rswz];
#pragma unroll
      for (int ni = 0; ni < NR; ++ni)
        bf[ni] = *(const bf16x8*)&bB[(wni * WN + ni * 16 + lg) * 64 + rswz];
      __builtin_amdgcn_s_setprio(1);
#pragma unroll
      for (int mi = 0; mi < 4; ++mi)
#pragma unroll
        for (int ni = 0; ni < NR; ++ni)
          acc[mh * 4 + mi][ni] = __builtin_amdgcn_mfma_f32_16x16x32_bf16(
              af[mi], bf[ni], acc[mh * 4 + mi][ni], 0, 0, 0);
      __builtin_amdgcn_s_setprio(0);
    }
  }

  const int row0 = bx * BM + wmi * 128;
  const int col0 = by * BN + wni * WN;
  const long coff = (long)zh * sCh + (long)zl * sCl;

  if (MODE == 4) {
#pragma unroll
    for (int mi = 0; mi < 8; ++mi)
#pragma unroll
      for (int r = 0; r < 4; ++r) {
        const int row = row0 + mi * 16 + lh * 4 + r;
        unsigned short* dq = (unsigned short*)Cv +
            (long)(row >> 11) * 6291456 + (long)by * 393216 + (long)(row & 2047) * 192;
#pragma unroll
        for (int ni = 0; ni < NR; ++ni)
          dq[wni * WN + ni * 16 + lg] = bf16r(acc[mi][ni][r] * alpha);
      }
  } else {
#pragma unroll
    for (int mi = 0; mi < 8; ++mi)
#pragma unroll
      for (int r = 0; r < 4; ++r) {
        const int row = row0 + mi * 16 + lh * 4 + r;
#pragma unroll
        for (int ni = 0; ni < NR; ++ni) {
          float v = acc[mi][ni][r] * alpha;
          if (MODE == 0)
            ((float*)Cv)[coff + (long)row * ldc + col0 + ni * 16 + lg] = v;
          else
            ((unsigned short*)Cv)[coff + (long)row * ldc + col0 + ni * 16 + lg] = bf16r(v);
        }
      }
  }
}

// =====================================================================
// 4-wave co-resident GEMM: 256 threads (2Mx2N waves, 64xWN wave tiles),
// BM=128, BK=64, dbuf-2, 64KB LDS -> 2 blocks/CU. One barrier + vmcnt(0)
// per K-tile; freerun interior; block-boundary prologue/drain overlaps
// the co-resident block's compute. (QK / PV / kabs / vhT)
// MODE: 0 f32*alpha; 1 bf16*alpha; 2 bf16 exp2(acc*alpha)+rowsum atomics.
// =====================================================================
template <int MODE>
__global__ __launch_bounds__(256) void gemm4w(
    const unsigned short* __restrict__ A, const unsigned short* __restrict__ B,
    void* __restrict__ Cv, float* __restrict__ laux,
    int Mrows, int K, int lda, int ldb, int ldc, int zs,
    long sAh, long sAl, long sBh, long sBl, long sCh, long sCl, float alpha)
{
  constexpr int BM = 128, BN = 128, WN = 64, NR = 4;

  __shared__ unsigned short As[2][BM * 64];
  __shared__ unsigned short Bs[2][BN * 64];

  const int tid = threadIdx.x;
  const int w = tid >> 6, l = tid & 63, lg = l & 15, lh = l >> 4;
  const int wmi = w >> 1, wni = w & 1;
  const int lrow = l >> 3;
  const int swz8 = ((l & 7) ^ lrow) * 8;

  const int gx = gridDim.x, gy = gridDim.y;
  const int nwg = gx * gy * gridDim.z;
  int id = blockIdx.x + gx * (blockIdx.y + gy * blockIdx.z);
  if ((nwg & 7) == 0) id = (id & 7) * (nwg >> 3) + (id >> 3);
  const int bx = id % gx;
  const int t1 = id / gx;
  const int by = t1 % gy;
  const int z = t1 / gy;
  const int zh = z >> zs, zl = z & ((1 << zs) - 1);

  const unsigned short* Ab = A + zh * sAh + zl * sAl + (long)(bx * BM) * lda;
  const unsigned short* Bb = B + zh * sBh + zl * sBl + (long)(by * BN) * ldb;

  const int nt = K >> 6;

  // stage: unit = 32 rows x 64 cols; wave w covers rows [u*32 + w*8, +8)
  auto stage = [&](int T) {
    const int k0 = T << 6;
    const int d = T & 1;
#pragma unroll
    for (int u = 0; u < 4; ++u) {
      const int rr = u * 32 + w * 8;
      GLOAD16(Ab + (long)(rr + lrow) * lda + k0 + swz8, &As[d][rr * 64]);
    }
#pragma unroll
    for (int u = 0; u < 4; ++u) {
      const int rr = u * 32 + w * 8;
      GLOAD16(Bb + (long)(rr + lrow) * ldb + k0 + swz8, &Bs[d][rr * 64]);
    }
  };

  f32x4 acc[4][NR] = {};

  stage(0);
  for (int t = 0; t < nt; ++t) {
    asm volatile("s_waitcnt vmcnt(0)" ::: "memory");
    __builtin_amdgcn_s_barrier();          // only barrier per tile
    if (t + 1 < nt) stage(t + 1);          // fire-and-forget into buf^1
    const unsigned short* bA = As[t & 1];
    const unsigned short* bB = Bs[t & 1];
#pragma unroll
    for (int kh = 0; kh < 2; ++kh) {
      const int rswz = ((kh * 4 + lh) ^ (lg & 7)) * 8;
      bf16x8 af[4], bf[NR];
#pragma unroll
      for (int mi = 0; mi < 4; ++mi)
        af[mi] = *(const bf16x8*)&bA[(wmi * 64 + mi * 16 + lg) * 64 + rswz];
#pragma unroll
      for (int ni = 0; ni < NR; ++ni)
        bf[ni] = *(const bf16x8*)&bB[(wni * WN + ni * 16 + lg) * 64 + rswz];
      __builtin_amdgcn_s_setprio(1);
#pragma unroll
      for (int mi = 0; mi < 4; ++mi)
#pragma unroll
        for (int ni = 0; ni < NR; ++ni)
          acc[mi][ni] = __builtin_amdgcn_mfma_f32_16x16x32_bf16(
              af[mi], bf[ni], acc[mi][ni], 0, 0, 0);
      __builtin_amdgcn_s_setprio(0);
    }
  }

  const int row0 = bx * BM + wmi * 64;
  const int col0 = by * BN + wni * WN;
  const long coff = (long)zh * sCh + (long)zl * sCl;

  if (MODE == 2) {
#pragma unroll
    for (int mi = 0; mi < 4; ++mi)
#pragma unroll
      for (int r = 0; r < 4; ++r) {
        const int row = row0 + mi * 16 + lh * 4 + r;
        float rs = 0.f;
#pragma unroll
        for (int ni = 0; ni < NR; ++ni) {
          float pv = exp2f(acc[mi][ni][r] * alpha);
          ((unsigned short*)Cv)[coff + (long)row * ldc + col0 + ni * 16 + lg] = bf16r(pv);
          rs += pv;
        }
#pragma unroll
        for (int msk = 1; msk < 16; msk <<= 1) rs += __shfl_xor(rs, msk);
        if (lg == 0) atomicAdd(&laux[(long)z * Mrows + row], rs);
      }
  } else {
#pragma unroll
    for (int mi = 0; mi < 4; ++mi)
#pragma unroll
      for (int r = 0; r < 4; ++r) {
        const int row = row0 + mi * 16 + lh * 4 + r;
#pragma unroll
        for (int ni = 0; ni < NR; ++ni) {
          float v = acc[mi][ni][r] * alpha;
          if (MODE == 0)
            ((float*)Cv)[coff + (long)row * ldc + col0 + ni * 16 + lg] = v;
          else
            ((unsigned short*)Cv)[coff + (long)row * ldc + col0 + ni * 16 + lg] = bf16r(v);
        }
      }
  }
}

// ---------- generic 128x128 bf16 GEMM (m97-class), odd shapes (kv_full) ----------
template <int MODE>
__global__ __launch_bounds__(256) void gemm_bt2(
    const unsigned short* __restrict__ A, const unsigned short* __restrict__ B,
    void* __restrict__ Cv, float* __restrict__ laux,
    int M, int Nstore, int K, int lda, int ldb, int ldc, int zs,
    long sAh, long sAl, long sBh, long sBl, long sCh, long sCl, float alpha)
{
  __shared__ unsigned short As[128 * 32];
  __shared__ unsigned short Bs[128 * 32];
  const int tid = threadIdx.x;
  const int w = tid >> 6, l = tid & 63, lg = l & 15, lh = l >> 4;

  const int gx = gridDim.x, gy = gridDim.y;
  const int nwg = gx * gy * gridDim.z;
  int id = blockIdx.x + gx * (blockIdx.y + gy * blockIdx.z);
  if ((nwg & 7) == 0) id = (id & 7) * (nwg >> 3) + (id >> 3);
  const int bx = id % gx;
  const int t1 = id / gx;
  const int by = t1 % gy;
  const int z = t1 / gy;

  const int zh = z >> zs, zl = z & ((1 << zs) - 1);
  const unsigned short* Ab = A + zh * sAh + zl * sAl + (long)(bx * 128) * lda;
  const unsigned short* Bb = B + zh * sBh + zl * sBl + (long)(by * 128) * ldb;
  const int srow = l >> 2;
  const int scol = (((l & 3) ^ ((l >> 3) & 3)) * 8);
  const int wm = (w >> 1) * 64, wn = (w & 1) * 64;
  f32x4 acc[4][4] = {};

  const long ra0 = (long)(w * 16 + srow) * lda + scol;
  const long ra1 = (long)(64 + w * 16 + srow) * lda + scol;
  const long rb0 = (long)(w * 16 + srow) * ldb + scol;
  const long rb1 = (long)(64 + w * 16 + srow) * ldb + scol;
  unsigned short* lA0 = &As[(w * 16) * 32];
  unsigned short* lA1 = &As[(64 + w * 16) * 32];
  unsigned short* lB0 = &Bs[(w * 16) * 32];
  unsigned short* lB1 = &Bs[(64 + w * 16) * 32];

  const int rsw = ((lh ^ ((lg >> 1) & 3)) * 8);

  for (int k0 = 0; k0 < K; k0 += 32) {
    __syncthreads();
    GLOAD16(Ab + ra0 + k0, lA0);
    GLOAD16(Ab + ra1 + k0, lA1);
    GLOAD16(Bb + rb0 + k0, lB0);
    GLOAD16(Bb + rb1 + k0, lB1);
    __syncthreads();
    bf16x8 af[4], bfr[4];
#pragma unroll
    for (int m = 0; m < 4; m++) af[m] = *(const bf16x8*)&As[(wm + m * 16 + lg) * 32 + rsw];
#pragma unroll
    for (int n = 0; n < 4; n++) bfr[n] = *(const bf16x8*)&Bs[(wn + n * 16 + lg) * 32 + rsw];
#pragma unroll
    for (int m = 0; m < 4; m++)
#pragma unroll
      for (int n = 0; n < 4; n++)
        acc[m][n] = __builtin_amdgcn_mfma_f32_16x16x32_bf16(af[m], bfr[n], acc[m][n], 0, 0, 0);
  }

  const int row0 = bx * 128 + wm, col0 = by * 128 + wn;
  long coff = zh * sCh + zl * sCl;

#pragma unroll
  for (int m = 0; m < 4; m++)
#pragma unroll
    for (int r = 0; r < 4; r++) {
      const int row = row0 + m * 16 + lh * 4 + r;
#pragma unroll
      for (int n = 0; n < 4; n++) {
        int col = col0 + n * 16 + lg;
        if (col < Nstore) {
          float v = acc[m][n][r] * alpha;
          if (MODE == 0)
            ((float*)Cv)[coff + (long)row * ldc + col] = v;
          else
            ((unsigned short*)Cv)[coff + (long)row * ldc + col] = bf16r(v);
        }
      }
    }
}

// ---------- kv epilogue: tanh-norm -> kvn bf16; roped k_pe -> kh[...][128:192) x16 heads ----
__global__ void kv_epilogue(const float* __restrict__ kvf, const float* __restrict__ fc,
                            const float* __restrict__ fs, const float* __restrict__ alpha,
                            const float* __restrict__ gamma, const float* __restrict__ beta,
                            unsigned short* __restrict__ kvn, unsigned short* __restrict__ kh) {
  const int n = blockIdx.x;
  const int b = n >> 11, s = n & 2047;
  const int tid = threadIdx.x;
  const float a = alpha[0];
  const float* src = kvf + (long)n * 576;
  unsigned short* dst = kvn + (long)n * 512;
#pragma unroll
  for (int c0 = 0; c0 < 512; c0 += 256) {
    int c = c0 + tid;
    float v = tanhf(a * src[c]) * gamma[c] + beta[c];
    dst[c] = bf16r(v);
  }
  if (tid < 32) {
    int i = tid;
    float re = src[512 + 2 * i], im = src[512 + 2 * i + 1];
    float co = fc[s * 32 + i], si = fs[s * 32 + i];
    ushort2 v;
    v.x = bf16r(re * co - im * si);
    v.y = bf16r(re * si + im * co);
#pragma unroll
    for (int h = 0; h < 16; h++)
      *(ushort2*)&kh[((long)(b * 16 + h) * 2048 + s) * 192 + 128 + 2 * i] = v;
  }
}

// ---------- q rope fixup: in-place rotate q192[...][128:192) (values pre-scaled) ----------
__global__ void q_ropefix(unsigned short* __restrict__ q192, const float* __restrict__ fc,
                          const float* __restrict__ fs) {
  const int n = blockIdx.x;
  const int b = n >> 11, s = n & 2047;
  const int tid = threadIdx.x;
  for (int it = tid; it < 512; it += 256) {
    int h = it >> 5, i = it & 31;
    unsigned short* dd = q192 + ((long)(b * 16 + h) * 2048 + s) * 192 + 128 + 2 * i;
    float re = bf2f(dd[0]), im = bf2f(dd[1]);
    float co = fc[s * 32 + i], si = fs[s * 32 + i];
    ushort2 o;
    o.x = bf16r(re * co - im * si);
    o.y = bf16r(re * si + im * co);
    *(ushort2*)dd = o;
  }
}

// ---------- PV reduce: o_b slice = bf16((o_p[0..3]) / l) ----------
__global__ void reduce_pv(const float* __restrict__ op, const float* __restrict__ lsum,
                          unsigned short* __restrict__ ob, int c) {
  const long idx = (long)blockIdx.x * 256 + threadIdx.x;   // [8][2048][32] float4 units
  const int d4 = (int)(idx & 31);
  const int s = (int)((idx >> 5) & 2047);
  const int hh = (int)(idx >> 16);
  const long base = (long)hh * 262144 + (long)s * 128 + d4 * 4;
  float4 a = *(const float4*)&op[base];
  float4 b = *(const float4*)&op[2097152 + base];
  float4 e = *(const float4*)&op[2 * 2097152 + base];
  float4 d = *(const float4*)&op[3 * 2097152 + base];
  const float inv = 1.0f / lsum[hh * 2048 + s];
  const long row = (long)(c >> 1) * 2048 + s;
  const int col = ((c & 1) * 8 + hh) * 128 + d4 * 4;
  ushort4 o;
  o.x = bf16r((a.x + b.x + e.x + d.x) * inv);
  o.y = bf16r((a.y + b.y + e.y + d.y) * inv);
  o.z = bf16r((a.z + b.z + e.z + d.z) * inv);
  o.w = bf16r((a.w + b.w + e.w + d.w) * inv);
  *(ushort4*)&ob[row * 2048 + col] = o;
}

__global__ void zerof(float* __restrict__ p, long n) {
  long i = ((long)blockIdx.x * 256 + threadIdx.x) * 4;
  if (i < n) *(float4*)&p[i] = make_float4(0.f, 0.f, 0.f, 0.f);
}

// ---------- host launcher ----------
extern "C" void kernel_launch(void* const* d_in, const int* in_sizes, int n_in,
                              void* d_out, int out_size, void* d_ws, size_t ws_size,
                              hipStream_t stream) {
  const float* x = (const float*)d_in[0];
  const float* fc = (const float*)d_in[1];
  const float* fs = (const float*)d_in[2];
  const float* wq = (const float*)d_in[3];
  const float* wkva = (const float*)d_in[4];
  const float* wkvb = (const float*)d_in[5];
  const float* wo = (const float*)d_in[6];
  const float* alpha = (const float*)d_in[7];
  const float* gamma = (const float*)d_in[8];
  const float* beta = (const float*)d_in[9];
  float* out = (float*)d_out;

  char* p = (char*)d_ws;
  auto take = [&](size_t bytes) {
    char* r = p;
    p += (bytes + 255) & ~(size_t)255;
    return r;
  };
  unsigned short* wqb   = (unsigned short*)take(6291456ull * 2);    // wq bf16 [3072][2048]
  float*          kvf   = (float*)take(2359296ull * 4);             // kv_full f32 [4096][576]
  unsigned short* xb    = (unsigned short*)take(8388608ull * 2);    // x bf16 [4096][2048]
  unsigned short* wab   = (unsigned short*)take(1310720ull * 2);    // wkv_a bf16 padded [640][2048]
  unsigned short* wbb   = (unsigned short*)take(2097152ull * 2);    // wkv_b bf16 [4096][512]
  unsigned short* wob   = (unsigned short*)take(4194304ull * 2);    // wo bf16 [2048][2048]
  unsigned short* kvn   = (unsigned short*)take(2097152ull * 2);    // [4096][512]
  unsigned short* kh    = (unsigned short*)take(12582912ull * 2);   // [32][2048][192]
  unsigned short* q192  = (unsigned short*)take(12582912ull * 2);   // [32][2048][192]
  unsigned short* vhT   = (unsigned short*)take(8388608ull * 2);    // [32][128][2048]
  float*          lsum  = (float*)take(65536ull * 4);               // [32][2048]
  unsigned short* o_b   = (unsigned short*)take(8388608ull * 2);    // [4096][2048]
  unsigned short* P     = (unsigned short*)take(33554432ull * 2);   // [8][2048][2048] chunk
  float*          o_p   = (float*)take(8388608ull * 4);             // [4][8][2048][128] f32 partials

  const float scale = 1.0f / sqrtf(192.0f);

  // fused conversions
  conv_all<<<21760, 256, 0, stream>>>(x, wq, wkva, wkvb, wo, xb, wqb, wab, wbb, wob);

  // q192 = scale * (x @ wq^T) scattered head-major -- 8-phase 256x192, grid 256
  gemm8p<192, 4><<<dim3(16, 16, 1), 512, 0, stream>>>(
      xb, wqb, q192, nullptr, 4096, 2048, 2048, 2048, 192, 0, 0, 0, 0, 0, 0, 0, scale);
  // kv_full = x @ wkv_a^T (f32)
  gemm_bt2<0><<<dim3(32, 5, 1), 256, 0, stream>>>(xb, wab, kvf, nullptr, 4096, 576, 2048,
                                                  2048, 2048, 576, 0, 0, 0, 0, 0, 0, 0, 1.0f);
  // kvn (tanh-norm) + roped k_pe broadcast into kh[...][128:192)
  kv_epilogue<<<4096, 256, 0, stream>>>(kvf, fc, fs, alpha, gamma, beta, kvn, kh);
  // k_abs[h] = kvn @ wk_h^T -> kh[:, :, 0:128) -- 4-wave 128x128, grid 512, 2/CU
  gemm4w<1><<<dim3(16, 1, 32), 256, 0, stream>>>(
      kvn, wbb, kh, nullptr, 2048, 512, 512, 512, 192, 4,
      1048576, 0, 0, 131072, 6291456, 393216, 1.0f);
  // rope the pe part of q192 in place
  q_ropefix<<<4096, 256, 0, stream>>>(q192, fc, fs);
  // vhT[g] = wv_h @ kvn_b^T [128][2048] -- 4-wave, grid 512
  gemm4w<1><<<dim3(1, 16, 32), 256, 0, stream>>>(
      wbb + 128 * 512, kvn, vhT, nullptr, 128, 512, 512, 512, 2048, 4,
      0, 131072, 1048576, 0, 4194304, 262144, 1.0f);
  // zero l
  zerof<<<64, 256, 0, stream>>>(lsum, 65536L);

  // attention: 4 chunks of 8 heads
  for (int c = 0; c < 4; c++) {
    const unsigned short* Aq = q192 + (long)c * 8 * 393216;
    const unsigned short* Bk = kh + (long)c * 8 * 393216;
    float* lc = lsum + (long)c * 8 * 2048;
    // QK: P = exp2(q192 @ kh^T * LOG2E) + row-sum atomics -- 4-wave, grid 2048, 2/CU
    gemm4w<2><<<dim3(16, 16, 8), 256, 0, stream>>>(
        Aq, Bk, P, lc, 2048, 192, 192, 192, 2048, 3,
        0, 393216, 0, 393216, 0, 4194304, LOG2E);
    // PV 4-way K-split: o_p[kq][head] = P_q @ vhT_q^T -- 4-wave, grid 512
    const unsigned short* Bv = vhT + (long)c * 8 * 262144;
    gemm4w<0><<<dim3(16, 1, 32), 256, 0, stream>>>(
        P, Bv, o_p, nullptr, 2048, 512, 2048, 2048, 128, 3,
        512, 4194304, 512, 262144, 2097152, 262144, 1.0f);
    // reduce partials / l -> o_b slice
    reduce_pv<<<2048, 256, 0, stream>>>(o_p, lc, o_b, c);
  }

  // out = o_b @ wo^T (f32) -- 8-phase 256x128, grid 256
  gemm8p<128, 0><<<dim3(16, 16, 1), 512, 0, stream>>>(
      o_b, wob, out, nullptr, 4096, 2048, 2048, 2048, 2048, 0, 0, 0, 0, 0, 0, 0, 1.0f);
}

// Round 14
// 459.406 us; speedup vs baseline: 1.2142x; 1.0019x over previous
//
#include <hip/hip_runtime.h>
#include <math.h>

// ---------- common types / helpers ----------
typedef __bf16 bf16x8 __attribute__((ext_vector_type(8)));
typedef float f32x4 __attribute__((ext_vector_type(4)));

#define LOG2E 1.4426950408889634f

__device__ __forceinline__ unsigned short bf16r(float f) {
  unsigned u = __float_as_uint(f);
  u = (u + 0x7fffu + ((u >> 16) & 1u)) >> 16;
  return (unsigned short)u;
}
__device__ __forceinline__ float bf2f(unsigned short h) {
  return __uint_as_float(((unsigned)h) << 16);
}

// async global->LDS, 16B per lane; LDS dest is wave-uniform base + lane*16B (linear)
#define GLOAD16(gsrc, ldst)                                                        \
  __builtin_amdgcn_global_load_lds(                                                \
      (const __attribute__((address_space(1))) void*)(gsrc),                       \
      (__attribute__((address_space(3))) void*)(ldst), 16, 0, 0)

// Block mapping: XCD-aware. For gz==1 grids, each XCD owns a (gx/4)x(gy/2)
// rectangle of (bx,by) -> A/B panel footprint per XCD-L2 drops ~2x (L2-rect).
// For batched grids, chunked swizzle (per-XCD z locality). Bijective in both.
__device__ __forceinline__ void map_block(int& bx, int& by, int& z) {
  const int gx = gridDim.x, gy = gridDim.y;
  const int nwg = gx * gy * gridDim.z;
  int id = blockIdx.x + gx * (blockIdx.y + gy * blockIdx.z);
  if (gridDim.z == 1 && (gx & 3) == 0 && (gy & 1) == 0 && (nwg & 7) == 0) {
    const int xcd = id & 7, k = id >> 3;
    const int rx = gx >> 2, ry = gy >> 1;
    bx = (xcd & 3) * rx + (k % rx);
    by = (xcd >> 2) * ry + (k / rx);
    z = 0;
  } else {
    if ((nwg & 7) == 0) id = (id & 7) * (nwg >> 3) + (id >> 3);
    bx = id % gx;
    const int t1 = id / gx;
    by = t1 % gy;
    z = t1 / gy;
  }
}

// ---------- fused conversion kernel: 5 f32->bf16 converts + lsum zero ----------
__global__ void conv_all(const float* __restrict__ x, const float* __restrict__ wq,
                         const float* __restrict__ wkva, const float* __restrict__ wkvb,
                         const float* __restrict__ wo,
                         unsigned short* __restrict__ xb, unsigned short* __restrict__ wqb,
                         unsigned short* __restrict__ wab, unsigned short* __restrict__ wbb,
                         unsigned short* __restrict__ wob, float* __restrict__ lsum) {
  int bid = blockIdx.x;
  if (bid >= 21760) {                     // last 64 blocks: zero lsum [32][2048]
    long i = ((long)(bid - 21760) * 256 + threadIdx.x) * 4;
    *(float4*)&lsum[i] = make_float4(0.f, 0.f, 0.f, 0.f);
    return;
  }
  const float* src; unsigned short* dst; long nsrc;
  if (bid < 8192)       {               src = x;    dst = xb;  nsrc = 8388608; }
  else if (bid < 14336) { bid -= 8192;  src = wq;   dst = wqb; nsrc = 6291456; }
  else if (bid < 15616) { bid -= 14336; src = wkva; dst = wab; nsrc = 1179648; } // pad to 640 rows
  else if (bid < 17664) { bid -= 15616; src = wkvb; dst = wbb; nsrc = 2097152; }
  else                  { bid -= 17664; src = wo;   dst = wob; nsrc = 4194304; }
  long i = ((long)bid * 256 + threadIdx.x) * 4;
  ushort4 o;
  if (i < nsrc) {
    float4 v = *(const float4*)&src[i];
    o.x = bf16r(v.x); o.y = bf16r(v.y); o.z = bf16r(v.z); o.w = bf16r(v.w);
  } else {
    o.x = 0; o.y = 0; o.z = 0; o.w = 0;
  }
  *(ushort4*)&dst[i] = o;
}

// =====================================================================
// 8-phase deep-pipelined GEMM (m201-style). BM=256, 8 waves 2Mx4N,
// BK=64, dbuf-2 LDS, 2 K-tiles per iter + odd-nt tail. (q-proj)
// MODE: 0 f32*alpha; 4 scatter into q192 [b*16+by][s][192].
// =====================================================================
template <int BN, int MODE>
__global__ __launch_bounds__(512) void gemm8p(
    const unsigned short* __restrict__ A, const unsigned short* __restrict__ B,
    void* __restrict__ Cv, float* __restrict__ laux,
    int Mrows, int K, int lda, int ldb, int ldc, int zs,
    long sAh, long sAl, long sBh, long sBl, long sCh, long sCl, float alpha)
{
  constexpr int BM = 256;
  constexpr int WN = BN / 4;
  constexpr int NR = WN / 16;
  constexpr int BU = BN / 64;
  constexpr int BU1 = (BU + 1) / 2;

  __shared__ unsigned short As[2][BM * 64];
  __shared__ unsigned short Bs[2][BN * 64];

  const int tid = threadIdx.x;
  const int w = tid >> 6, l = tid & 63, lg = l & 15, lh = l >> 4;
  const int wmi = w >> 2, wni = w & 3;
  const int lrow = l >> 3;
  const int swz8 = ((l & 7) ^ lrow) * 8;

  int bx, by, z;
  map_block(bx, by, z);
  const int zh = z >> zs, zl = z & ((1 << zs) - 1);

  const unsigned short* Ab = A + zh * sAh + zl * sAl + (long)(bx * BM) * lda;
  const unsigned short* Bb = B + zh * sBh + zl * sBl + (long)(by * BN) * ldb;

  const int nt = K >> 6;

  auto stA = [&](int T, int u) {
    if (T >= nt) return;
    const int rr = u * 64 + w * 8;
    GLOAD16(Ab + (long)(rr + lrow) * lda + (T << 6) + swz8, &As[T & 1][rr * 64]);
  };
  auto stB = [&](int T, int u) {
    if (T >= nt) return;
    const int rr = u * 64 + w * 8;
    GLOAD16(Bb + (long)(rr + lrow) * ldb + (T << 6) + swz8, &Bs[T & 1][rr * 64]);
  };

  stA(0, 0); stA(0, 1); stA(0, 2); stA(0, 3);
#pragma unroll
  for (int u = 0; u < BU; ++u) stB(0, u);
  stA(1, 0); stA(1, 2);

  f32x4 acc[8][NR] = {};

  const int nit = nt >> 1;
  for (int i = 0; i < nit; ++i) {
    const int t0 = 2 * i;
#pragma unroll
    for (int j = 0; j < 8; ++j) {
      const int tau = t0 + (j >> 2);
      const int jj = j & 3;
      const int mh = jj & 1, kh = jj >> 1;
      if (jj == 0) {
        if (tau + 1 < nt) asm volatile("s_waitcnt vmcnt(2)" ::: "memory");
        else              asm volatile("s_waitcnt vmcnt(0)" ::: "memory");
      } else {
        asm volatile("" ::: "memory");
      }
      __builtin_amdgcn_s_barrier();
      if (j == 0)      { stA(t0 + 1, 1); stA(t0 + 1, 3); }
      else if (j == 1) { for (int u = 0; u < BU1; ++u) stB(t0 + 1, u); }
      else if (j == 2) { for (int u = BU1; u < BU; ++u) stB(t0 + 1, u); }
      else if (j == 3) { stA(t0 + 2, 0); stA(t0 + 2, 2); }
      else if (j == 4) { stA(t0 + 2, 1); stA(t0 + 2, 3); }
      else if (j == 5) { for (int u = 0; u < BU1; ++u) stB(t0 + 2, u); }
      else if (j == 6) { for (int u = BU1; u < BU; ++u) stB(t0 + 2, u); }
      else             { stA(t0 + 3, 0); stA(t0 + 3, 2); }
      const unsigned short* bA = As[tau & 1];
      const unsigned short* bB = Bs[tau & 1];
      const int rswz = ((kh * 4 + lh) ^ (lg & 7)) * 8;
      bf16x8 af[4], bf[NR];
#pragma unroll
      for (int mi = 0; mi < 4; ++mi)
        af[mi] = *(const bf16x8*)&bA[(wmi * 128 + mh * 64 + mi * 16 + lg) * 64 + rswz];
#pragma unroll
      for (int ni = 0; ni < NR; ++ni)
        bf[ni] = *(const bf16x8*)&bB[(wni * WN + ni * 16 + lg) * 64 + rswz];
      __builtin_amdgcn_s_setprio(1);
#pragma unroll
      for (int mi = 0; mi < 4; ++mi)
#pragma unroll
        for (int ni = 0; ni < NR; ++ni)
          acc[mh * 4 + mi][ni] = __builtin_amdgcn_mfma_f32_16x16x32_bf16(
              af[mi], bf[ni], acc[mh * 4 + mi][ni], 0, 0, 0);
      __builtin_amdgcn_s_setprio(0);
    }
  }

  if (nt & 1) {
    const int tau = nt - 1;
    asm volatile("s_waitcnt vmcnt(0)" ::: "memory");
    __builtin_amdgcn_s_barrier();
    const unsigned short* bA = As[tau & 1];
    const unsigned short* bB = Bs[tau & 1];
#pragma unroll
    for (int jj = 0; jj < 4; ++jj) {
      const int mh = jj & 1, kh = jj >> 1;
      const int rswz = ((kh * 4 + lh) ^ (lg & 7)) * 8;
      bf16x8 af[4], bf[NR];
#pragma unroll
      for (int mi = 0; mi < 4; ++mi)
        af[mi] = *(const bf16x8*)&bA[(wmi * 128 + mh * 64 + mi * 16 + lg) * 64 + rswz];
#pragma unroll
      for (int ni = 0; ni < NR; ++ni)
        bf[ni] = *(const bf16x8*)&bB[(wni * WN + ni * 16 + lg) * 64 + rswz];
      __builtin_amdgcn_s_setprio(1);
#pragma unroll
      for (int mi = 0; mi < 4; ++mi)
#pragma unroll
        for (int ni = 0; ni < NR; ++ni)
          acc[mh * 4 + mi][ni] = __builtin_amdgcn_mfma_f32_16x16x32_bf16(
              af[mi], bf[ni], acc[mh * 4 + mi][ni], 0, 0, 0);
      __builtin_amdgcn_s_setprio(0);
    }
  }

  const int row0 = bx * BM + wmi * 128;
  const int col0 = by * BN + wni * WN;
  const long coff = (long)zh * sCh + (long)zl * sCl;

  if (MODE == 4) {
#pragma unroll
    for (int mi = 0; mi < 8; ++mi)
#pragma unroll
      for (int r = 0; r < 4; ++r) {
        const int row = row0 + mi * 16 + lh * 4 + r;
        unsigned short* dq = (unsigned short*)Cv +
            (long)(row >> 11) * 6291456 + (long)by * 393216 + (long)(row & 2047) * 192;
#pragma unroll
        for (int ni = 0; ni < NR; ++ni)
          dq[wni * WN + ni * 16 + lg] = bf16r(acc[mi][ni][r] * alpha);
      }
  } else {
#pragma unroll
    for (int mi = 0; mi < 8; ++mi)
#pragma unroll
      for (int r = 0; r < 4; ++r) {
        const int row = row0 + mi * 16 + lh * 4 + r;
#pragma unroll
        for (int ni = 0; ni < NR; ++ni) {
          float v = acc[mi][ni][r] * alpha;
          if (MODE == 0)
            ((float*)Cv)[coff + (long)row * ldc + col0 + ni * 16 + lg] = v;
          else
            ((unsigned short*)Cv)[coff + (long)row * ldc + col0 + ni * 16 + lg] = bf16r(v);
        }
      }
  }
}

// =====================================================================
// 4-wave co-resident GEMM: 256 threads (2Mx2N waves), BM=BN=128, BK=64,
// dbuf-2, 64KB LDS -> 2 blocks/CU. One barrier + vmcnt(0) per K-tile;
// freerun interior. (QK / PV / kabs / vhT / out-proj)
// MODE: 0 f32*alpha; 1 bf16*alpha; 2 bf16 exp2(acc*alpha)+rowsum atomics.
// =====================================================================
template <int MODE>
__global__ __launch_bounds__(256) void gemm4w(
    const unsigned short* __restrict__ A, const unsigned short* __restrict__ B,
    void* __restrict__ Cv, float* __restrict__ laux,
    int Mrows, int K, int lda, int ldb, int ldc, int zs,
    long sAh, long sAl, long sBh, long sBl, long sCh, long sCl, float alpha)
{
  constexpr int BM = 128, BN = 128, WN = 64, NR = 4;

  __shared__ unsigned short As[2][BM * 64];
  __shared__ unsigned short Bs[2][BN * 64];

  const int tid = threadIdx.x;
  const int w = tid >> 6, l = tid & 63, lg = l & 15, lh = l >> 4;
  const int wmi = w >> 1, wni = w & 1;
  const int lrow = l >> 3;
  const int swz8 = ((l & 7) ^ lrow) * 8;

  int bx, by, z;
  map_block(bx, by, z);
  const int zh = z >> zs, zl = z & ((1 << zs) - 1);

  const unsigned short* Ab = A + zh * sAh + zl * sAl + (long)(bx * BM) * lda;
  const unsigned short* Bb = B + zh * sBh + zl * sBl + (long)(by * BN) * ldb;

  const int nt = K >> 6;

  auto stage = [&](int T) {
    const int k0 = T << 6;
    const int d = T & 1;
#pragma unroll
    for (int u = 0; u < 4; ++u) {
      const int rr = u * 32 + w * 8;
      GLOAD16(Ab + (long)(rr + lrow) * lda + k0 + swz8, &As[d][rr * 64]);
    }
#pragma unroll
    for (int u = 0; u < 4; ++u) {
      const int rr = u * 32 + w * 8;
      GLOAD16(Bb + (long)(rr + lrow) * ldb + k0 + swz8, &Bs[d][rr * 64]);
    }
  };

  f32x4 acc[4][NR] = {};

  stage(0);
  for (int t = 0; t < nt; ++t) {
    asm volatile("s_waitcnt vmcnt(0)" ::: "memory");
    __builtin_amdgcn_s_barrier();          // only barrier per tile
    if (t + 1 < nt) stage(t + 1);          // fire-and-forget into buf^1
    const unsigned short* bA = As[t & 1];
    const unsigned short* bB = Bs[t & 1];
#pragma unroll
    for (int kh = 0; kh < 2; ++kh) {
      const int rswz = ((kh * 4 + lh) ^ (lg & 7)) * 8;
      bf16x8 af[4], bf[NR];
#pragma unroll
      for (int mi = 0; mi < 4; ++mi)
        af[mi] = *(const bf16x8*)&bA[(wmi * 64 + mi * 16 + lg) * 64 + rswz];
#pragma unroll
      for (int ni = 0; ni < NR; ++ni)
        bf[ni] = *(const bf16x8*)&bB[(wni * WN + ni * 16 + lg) * 64 + rswz];
      __builtin_amdgcn_s_setprio(1);
#pragma unroll
      for (int mi = 0; mi < 4; ++mi)
#pragma unroll
        for (int ni = 0; ni < NR; ++ni)
          acc[mi][ni] = __builtin_amdgcn_mfma_f32_16x16x32_bf16(
              af[mi], bf[ni], acc[mi][ni], 0, 0, 0);
      __builtin_amdgcn_s_setprio(0);
    }
  }

  const int row0 = bx * BM + wmi * 64;
  const int col0 = by * BN + wni * WN;
  const long coff = (long)zh * sCh + (long)zl * sCl;

  if (MODE == 2) {
#pragma unroll
    for (int mi = 0; mi < 4; ++mi)
#pragma unroll
      for (int r = 0; r < 4; ++r) {
        const int row = row0 + mi * 16 + lh * 4 + r;
        float rs = 0.f;
#pragma unroll
        for (int ni = 0; ni < NR; ++ni) {
          float pv = exp2f(acc[mi][ni][r] * alpha);
          ((unsigned short*)Cv)[coff + (long)row * ldc + col0 + ni * 16 + lg] = bf16r(pv);
          rs += pv;
        }
#pragma unroll
        for (int msk = 1; msk < 16; msk <<= 1) rs += __shfl_xor(rs, msk);
        if (lg == 0) atomicAdd(&laux[(long)z * Mrows + row], rs);
      }
  } else {
#pragma unroll
    for (int mi = 0; mi < 4; ++mi)
#pragma unroll
      for (int r = 0; r < 4; ++r) {
        const int row = row0 + mi * 16 + lh * 4 + r;
#pragma unroll
        for (int ni = 0; ni < NR; ++ni) {
          float v = acc[mi][ni][r] * alpha;
          if (MODE == 0)
            ((float*)Cv)[coff + (long)row * ldc + col0 + ni * 16 + lg] = v;
          else
            ((unsigned short*)Cv)[coff + (long)row * ldc + col0 + ni * 16 + lg] = bf16r(v);
        }
      }
  }
}

// ---------- generic 128x128 bf16 GEMM (m97-class), odd shapes (kv_full) ----------
template <int MODE>
__global__ __launch_bounds__(256) void gemm_bt2(
    const unsigned short* __restrict__ A, const unsigned short* __restrict__ B,
    void* __restrict__ Cv, float* __restrict__ laux,
    int M, int Nstore, int K, int lda, int ldb, int ldc, int zs,
    long sAh, long sAl, long sBh, long sBl, long sCh, long sCl, float alpha)
{
  __shared__ unsigned short As[128 * 32];
  __shared__ unsigned short Bs[128 * 32];
  const int tid = threadIdx.x;
  const int w = tid >> 6, l = tid & 63, lg = l & 15, lh = l >> 4;

  int bx, by, z;
  map_block(bx, by, z);

  const int zh = z >> zs, zl = z & ((1 << zs) - 1);
  const unsigned short* Ab = A + zh * sAh + zl * sAl + (long)(bx * 128) * lda;
  const unsigned short* Bb = B + zh * sBh + zl * sBl + (long)(by * 128) * ldb;
  const int srow = l >> 2;
  const int scol = (((l & 3) ^ ((l >> 3) & 3)) * 8);
  const int wm = (w >> 1) * 64, wn = (w & 1) * 64;
  f32x4 acc[4][4] = {};

  const long ra0 = (long)(w * 16 + srow) * lda + scol;
  const long ra1 = (long)(64 + w * 16 + srow) * lda + scol;
  const long rb0 = (long)(w * 16 + srow) * ldb + scol;
  const long rb1 = (long)(64 + w * 16 + srow) * ldb + scol;
  unsigned short* lA0 = &As[(w * 16) * 32];
  unsigned short* lA1 = &As[(64 + w * 16) * 32];
  unsigned short* lB0 = &Bs[(w * 16) * 32];
  unsigned short* lB1 = &Bs[(64 + w * 16) * 32];

  const int rsw = ((lh ^ ((lg >> 1) & 3)) * 8);

  for (int k0 = 0; k0 < K; k0 += 32) {
    __syncthreads();
    GLOAD16(Ab + ra0 + k0, lA0);
    GLOAD16(Ab + ra1 + k0, lA1);
    GLOAD16(Bb + rb0 + k0, lB0);
    GLOAD16(Bb + rb1 + k0, lB1);
    __syncthreads();
    bf16x8 af[4], bfr[4];
#pragma unroll
    for (int m = 0; m < 4; m++) af[m] = *(const bf16x8*)&As[(wm + m * 16 + lg) * 32 + rsw];
#pragma unroll
    for (int n = 0; n < 4; n++) bfr[n] = *(const bf16x8*)&Bs[(wn + n * 16 + lg) * 32 + rsw];
#pragma unroll
    for (int m = 0; m < 4; m++)
#pragma unroll
      for (int n = 0; n < 4; n++)
        acc[m][n] = __builtin_amdgcn_mfma_f32_16x16x32_bf16(af[m], bfr[n], acc[m][n], 0, 0, 0);
  }

  const int row0 = bx * 128 + wm, col0 = by * 128 + wn;
  long coff = zh * sCh + zl * sCl;

#pragma unroll
  for (int m = 0; m < 4; m++)
#pragma unroll
    for (int r = 0; r < 4; r++) {
      const int row = row0 + m * 16 + lh * 4 + r;
#pragma unroll
      for (int n = 0; n < 4; n++) {
        int col = col0 + n * 16 + lg;
        if (col < Nstore) {
          float v = acc[m][n][r] * alpha;
          if (MODE == 0)
            ((float*)Cv)[coff + (long)row * ldc + col] = v;
          else
            ((unsigned short*)Cv)[coff + (long)row * ldc + col] = bf16r(v);
        }
      }
    }
}

// ---------- kv epilogue: tanh-norm -> kvn bf16; roped k_pe -> kh[...][128:192) x16 heads ----
__global__ void kv_epilogue(const float* __restrict__ kvf, const float* __restrict__ fc,
                            const float* __restrict__ fs, const float* __restrict__ alpha,
                            const float* __restrict__ gamma, const float* __restrict__ beta,
                            unsigned short* __restrict__ kvn, unsigned short* __restrict__ kh) {
  const int n = blockIdx.x;
  const int b = n >> 11, s = n & 2047;
  const int tid = threadIdx.x;
  const float a = alpha[0];
  const float* src = kvf + (long)n * 576;
  unsigned short* dst = kvn + (long)n * 512;
#pragma unroll
  for (int c0 = 0; c0 < 512; c0 += 256) {
    int c = c0 + tid;
    float v = tanhf(a * src[c]) * gamma[c] + beta[c];
    dst[c] = bf16r(v);
  }
  if (tid < 32) {
    int i = tid;
    float re = src[512 + 2 * i], im = src[512 + 2 * i + 1];
    float co = fc[s * 32 + i], si = fs[s * 32 + i];
    ushort2 v;
    v.x = bf16r(re * co - im * si);
    v.y = bf16r(re * si + im * co);
#pragma unroll
    for (int h = 0; h < 16; h++)
      *(ushort2*)&kh[((long)(b * 16 + h) * 2048 + s) * 192 + 128 + 2 * i] = v;
  }
}

// ---------- q rope fixup: in-place rotate q192[...][128:192) (values pre-scaled) ----------
__global__ void q_ropefix(unsigned short* __restrict__ q192, const float* __restrict__ fc,
                          const float* __restrict__ fs) {
  const int n = blockIdx.x;
  const int b = n >> 11, s = n & 2047;
  const int tid = threadIdx.x;
  for (int it = tid; it < 512; it += 256) {
    int h = it >> 5, i = it & 31;
    unsigned short* dd = q192 + ((long)(b * 16 + h) * 2048 + s) * 192 + 128 + 2 * i;
    float re = bf2f(dd[0]), im = bf2f(dd[1]);
    float co = fc[s * 32 + i], si = fs[s * 32 + i];
    ushort2 o;
    o.x = bf16r(re * co - im * si);
    o.y = bf16r(re * si + im * co);
    *(ushort2*)dd = o;
  }
}

// ---------- PV reduce: o_b slice = bf16((o_p[0..3]) / l) ----------
__global__ void reduce_pv(const float* __restrict__ op, const float* __restrict__ lsum,
                          unsigned short* __restrict__ ob, int c) {
  const long idx = (long)blockIdx.x * 256 + threadIdx.x;   // [8][2048][32] float4 units
  const int d4 = (int)(idx & 31);
  const int s = (int)((idx >> 5) & 2047);
  const int hh = (int)(idx >> 16);
  const long base = (long)hh * 262144 + (long)s * 128 + d4 * 4;
  float4 a = *(const float4*)&op[base];
  float4 b = *(const float4*)&op[2097152 + base];
  float4 e = *(const float4*)&op[2 * 2097152 + base];
  float4 d = *(const float4*)&op[3 * 2097152 + base];
  const float inv = 1.0f / lsum[hh * 2048 + s];
  const long row = (long)(c >> 1) * 2048 + s;
  const int col = ((c & 1) * 8 + hh) * 128 + d4 * 4;
  ushort4 o;
  o.x = bf16r((a.x + b.x + e.x + d.x) * inv);
  o.y = bf16r((a.y + b.y + e.y + d.y) * inv);
  o.z = bf16r((a.z + b.z + e.z + d.z) * inv);
  o.w = bf16r((a.w + b.w + e.w + d.w) * inv);
  *(ushort4*)&ob[row * 2048 + col] = o;
}

// ---------- host launcher ----------
extern "C" void kernel_launch(void* const* d_in, const int* in_sizes, int n_in,
                              void* d_out, int out_size, void* d_ws, size_t ws_size,
                              hipStream_t stream) {
  const float* x = (const float*)d_in[0];
  const float* fc = (const float*)d_in[1];
  const float* fs = (const float*)d_in[2];
  const float* wq = (const float*)d_in[3];
  const float* wkva = (const float*)d_in[4];
  const float* wkvb = (const float*)d_in[5];
  const float* wo = (const float*)d_in[6];
  const float* alpha = (const float*)d_in[7];
  const float* gamma = (const float*)d_in[8];
  const float* beta = (const float*)d_in[9];
  float* out = (float*)d_out;

  char* p = (char*)d_ws;
  auto take = [&](size_t bytes) {
    char* r = p;
    p += (bytes + 255) & ~(size_t)255;
    return r;
  };
  unsigned short* wqb   = (unsigned short*)take(6291456ull * 2);    // wq bf16 [3072][2048]
  float*          kvf   = (float*)take(2359296ull * 4);             // kv_full f32 [4096][576]
  unsigned short* xb    = (unsigned short*)take(8388608ull * 2);    // x bf16 [4096][2048]
  unsigned short* wab   = (unsigned short*)take(1310720ull * 2);    // wkv_a bf16 padded [640][2048]
  unsigned short* wbb   = (unsigned short*)take(2097152ull * 2);    // wkv_b bf16 [4096][512]
  unsigned short* wob   = (unsigned short*)take(4194304ull * 2);    // wo bf16 [2048][2048]
  unsigned short* kvn   = (unsigned short*)take(2097152ull * 2);    // [4096][512]
  unsigned short* kh    = (unsigned short*)take(12582912ull * 2);   // [32][2048][192]
  unsigned short* q192  = (unsigned short*)take(12582912ull * 2);   // [32][2048][192]
  unsigned short* vhT   = (unsigned short*)take(8388608ull * 2);    // [32][128][2048]
  float*          lsum  = (float*)take(65536ull * 4);               // [32][2048]
  unsigned short* o_b   = (unsigned short*)take(8388608ull * 2);    // [4096][2048]
  unsigned short* P     = (unsigned short*)take(33554432ull * 2);   // [8][2048][2048] chunk
  float*          o_p   = (float*)take(8388608ull * 4);             // [4][8][2048][128] f32 partials

  const float scale = 1.0f / sqrtf(192.0f);

  // fused conversions + lsum zero
  conv_all<<<21824, 256, 0, stream>>>(x, wq, wkva, wkvb, wo, xb, wqb, wab, wbb, wob, lsum);

  // q192 = scale * (x @ wq^T) scattered head-major -- 8-phase 256x192, L2-rect
  gemm8p<192, 4><<<dim3(16, 16, 1), 512, 0, stream>>>(
      xb, wqb, q192, nullptr, 4096, 2048, 2048, 2048, 192, 0, 0, 0, 0, 0, 0, 0, scale);
  // kv_full = x @ wkv_a^T (f32)
  gemm_bt2<0><<<dim3(32, 5, 1), 256, 0, stream>>>(xb, wab, kvf, nullptr, 4096, 576, 2048,
                                                  2048, 2048, 576, 0, 0, 0, 0, 0, 0, 0, 1.0f);
  // kvn (tanh-norm) + roped k_pe broadcast into kh[...][128:192)
  kv_epilogue<<<4096, 256, 0, stream>>>(kvf, fc, fs, alpha, gamma, beta, kvn, kh);
  // k_abs[h] = kvn @ wk_h^T -> kh[:, :, 0:128) -- 4-wave, grid 512, 2/CU
  gemm4w<1><<<dim3(16, 1, 32), 256, 0, stream>>>(
      kvn, wbb, kh, nullptr, 2048, 512, 512, 512, 192, 4,
      1048576, 0, 0, 131072, 6291456, 393216, 1.0f);
  // rope the pe part of q192 in place
  q_ropefix<<<4096, 256, 0, stream>>>(q192, fc, fs);
  // vhT[g] = wv_h @ kvn_b^T [128][2048] -- 4-wave, grid 512
  gemm4w<1><<<dim3(1, 16, 32), 256, 0, stream>>>(
      wbb + 128 * 512, kvn, vhT, nullptr, 128, 512, 512, 512, 2048, 4,
      0, 131072, 1048576, 0, 4194304, 262144, 1.0f);

  // attention: 4 chunks of 8 heads
  for (int c = 0; c < 4; c++) {
    const unsigned short* Aq = q192 + (long)c * 8 * 393216;
    const unsigned short* Bk = kh + (long)c * 8 * 393216;
    float* lc = lsum + (long)c * 8 * 2048;
    // QK: P = exp2(q192 @ kh^T * LOG2E) + row-sum atomics -- 4-wave, grid 2048, 2/CU
    gemm4w<2><<<dim3(16, 16, 8), 256, 0, stream>>>(
        Aq, Bk, P, lc, 2048, 192, 192, 192, 2048, 3,
        0, 393216, 0, 393216, 0, 4194304, LOG2E);
    // PV 4-way K-split: o_p[kq][head] = P_q @ vhT_q^T -- 4-wave, grid 512
    const unsigned short* Bv = vhT + (long)c * 8 * 262144;
    gemm4w<0><<<dim3(16, 1, 32), 256, 0, stream>>>(
        P, Bv, o_p, nullptr, 2048, 512, 2048, 2048, 128, 3,
        512, 4194304, 512, 262144, 2097152, 262144, 1.0f);
    // reduce partials / l -> o_b slice
    reduce_pv<<<2048, 256, 0, stream>>>(o_p, lc, o_b, c);
  }

  // out = o_b @ wo^T (f32) -- 4-wave co-resident, grid 512, L2-rect
  gemm4w<0><<<dim3(32, 16, 1), 256, 0, stream>>>(
      o_b, wob, out, nullptr, 4096, 2048, 2048, 2048, 2048, 0,
      0, 0, 0, 0, 0, 0, 1.0f);
}

// Round 15
// 389.203 us; speedup vs baseline: 1.4332x; 1.1804x over previous
//
#include <hip/hip_runtime.h>
#include <math.h>

// ---------- common types / helpers ----------
typedef __bf16 bf16x8 __attribute__((ext_vector_type(8)));
typedef float f32x4 __attribute__((ext_vector_type(4)));

#define LOG2E 1.4426950408889634f

__device__ __forceinline__ unsigned short bf16r(float f) {
  unsigned u = __float_as_uint(f);
  u = (u + 0x7fffu + ((u >> 16) & 1u)) >> 16;
  return (unsigned short)u;
}
__device__ __forceinline__ float bf2f(unsigned short h) {
  return __uint_as_float(((unsigned)h) << 16);
}

// async global->LDS, 16B per lane; LDS dest is wave-uniform base + lane*16B (linear)
#define GLOAD16(gsrc, ldst)                                                        \
  __builtin_amdgcn_global_load_lds(                                                \
      (const __attribute__((address_space(1))) void*)(gsrc),                       \
      (__attribute__((address_space(3))) void*)(ldst), 16, 0, 0)

// Block mapping: XCD-aware. gz==1 grids: L2-rect; batched: chunked z-locality.
__device__ __forceinline__ void map_block(int& bx, int& by, int& z) {
  const int gx = gridDim.x, gy = gridDim.y;
  const int nwg = gx * gy * gridDim.z;
  int id = blockIdx.x + gx * (blockIdx.y + gy * blockIdx.z);
  if (gridDim.z == 1 && (gx & 3) == 0 && (gy & 1) == 0 && (nwg & 7) == 0) {
    const int xcd = id & 7, k = id >> 3;
    const int rx = gx >> 2, ry = gy >> 1;
    bx = (xcd & 3) * rx + (k % rx);
    by = (xcd >> 2) * ry + (k / rx);
    z = 0;
  } else {
    if ((nwg & 7) == 0) id = (id & 7) * (nwg >> 3) + (id >> 3);
    bx = id % gx;
    const int t1 = id / gx;
    by = t1 % gy;
    z = t1 / gy;
  }
}

// ---------- fused conversion kernel: all 5 f32->bf16 weight/input converts ----------
__global__ void conv_all(const float* __restrict__ x, const float* __restrict__ wq,
                         const float* __restrict__ wkva, const float* __restrict__ wkvb,
                         const float* __restrict__ wo,
                         unsigned short* __restrict__ xb, unsigned short* __restrict__ wqb,
                         unsigned short* __restrict__ wab, unsigned short* __restrict__ wbb,
                         unsigned short* __restrict__ wob) {
  int bid = blockIdx.x;
  const float* src; unsigned short* dst; long nsrc;
  if (bid < 8192)       {               src = x;    dst = xb;  nsrc = 8388608; }
  else if (bid < 14336) { bid -= 8192;  src = wq;   dst = wqb; nsrc = 6291456; }
  else if (bid < 15616) { bid -= 14336; src = wkva; dst = wab; nsrc = 1179648; } // pad to 640 rows
  else if (bid < 17664) { bid -= 15616; src = wkvb; dst = wbb; nsrc = 2097152; }
  else                  { bid -= 17664; src = wo;   dst = wob; nsrc = 4194304; }
  long i = ((long)bid * 256 + threadIdx.x) * 4;
  ushort4 o;
  if (i < nsrc) {
    float4 v = *(const float4*)&src[i];
    o.x = bf16r(v.x); o.y = bf16r(v.y); o.z = bf16r(v.z); o.w = bf16r(v.w);
  } else {
    o.x = 0; o.y = 0; o.z = 0; o.w = 0;
  }
  *(ushort4*)&dst[i] = o;
}

// =====================================================================
// 8-phase deep-pipelined GEMM (m201-style). BM=256, 8 waves 2Mx4N,
// BK=64, dbuf-2 LDS, 2 K-tiles per iter + odd-nt tail. (q-proj)
// MODE: 0 f32*alpha; 4 scatter into q192 [b*16+by][s][192].
// =====================================================================
template <int BN, int MODE>
__global__ __launch_bounds__(512) void gemm8p(
    const unsigned short* __restrict__ A, const unsigned short* __restrict__ B,
    void* __restrict__ Cv, float* __restrict__ laux,
    int Mrows, int K, int lda, int ldb, int ldc, int zs,
    long sAh, long sAl, long sBh, long sBl, long sCh, long sCl, float alpha)
{
  constexpr int BM = 256;
  constexpr int WN = BN / 4;
  constexpr int NR = WN / 16;
  constexpr int BU = BN / 64;
  constexpr int BU1 = (BU + 1) / 2;

  __shared__ unsigned short As[2][BM * 64];
  __shared__ unsigned short Bs[2][BN * 64];

  const int tid = threadIdx.x;
  const int w = tid >> 6, l = tid & 63, lg = l & 15, lh = l >> 4;
  const int wmi = w >> 2, wni = w & 3;
  const int lrow = l >> 3;
  const int swz8 = ((l & 7) ^ lrow) * 8;

  int bx, by, z;
  map_block(bx, by, z);
  const int zh = z >> zs, zl = z & ((1 << zs) - 1);

  const unsigned short* Ab = A + zh * sAh + zl * sAl + (long)(bx * BM) * lda;
  const unsigned short* Bb = B + zh * sBh + zl * sBl + (long)(by * BN) * ldb;

  const int nt = K >> 6;

  auto stA = [&](int T, int u) {
    if (T >= nt) return;
    const int rr = u * 64 + w * 8;
    GLOAD16(Ab + (long)(rr + lrow) * lda + (T << 6) + swz8, &As[T & 1][rr * 64]);
  };
  auto stB = [&](int T, int u) {
    if (T >= nt) return;
    const int rr = u * 64 + w * 8;
    GLOAD16(Bb + (long)(rr + lrow) * ldb + (T << 6) + swz8, &Bs[T & 1][rr * 64]);
  };

  stA(0, 0); stA(0, 1); stA(0, 2); stA(0, 3);
#pragma unroll
  for (int u = 0; u < BU; ++u) stB(0, u);
  stA(1, 0); stA(1, 2);

  f32x4 acc[8][NR] = {};

  const int nit = nt >> 1;
  for (int i = 0; i < nit; ++i) {
    const int t0 = 2 * i;
#pragma unroll
    for (int j = 0; j < 8; ++j) {
      const int tau = t0 + (j >> 2);
      const int jj = j & 3;
      const int mh = jj & 1, kh = jj >> 1;
      if (jj == 0) {
        if (tau + 1 < nt) asm volatile("s_waitcnt vmcnt(2)" ::: "memory");
        else              asm volatile("s_waitcnt vmcnt(0)" ::: "memory");
      } else {
        asm volatile("" ::: "memory");
      }
      __builtin_amdgcn_s_barrier();
      if (j == 0)      { stA(t0 + 1, 1); stA(t0 + 1, 3); }
      else if (j == 1) { for (int u = 0; u < BU1; ++u) stB(t0 + 1, u); }
      else if (j == 2) { for (int u = BU1; u < BU; ++u) stB(t0 + 1, u); }
      else if (j == 3) { stA(t0 + 2, 0); stA(t0 + 2, 2); }
      else if (j == 4) { stA(t0 + 2, 1); stA(t0 + 2, 3); }
      else if (j == 5) { for (int u = 0; u < BU1; ++u) stB(t0 + 2, u); }
      else if (j == 6) { for (int u = BU1; u < BU; ++u) stB(t0 + 2, u); }
      else             { stA(t0 + 3, 0); stA(t0 + 3, 2); }
      const unsigned short* bA = As[tau & 1];
      const unsigned short* bB = Bs[tau & 1];
      const int rswz = ((kh * 4 + lh) ^ (lg & 7)) * 8;
      bf16x8 af[4], bf[NR];
#pragma unroll
      for (int mi = 0; mi < 4; ++mi)
        af[mi] = *(const bf16x8*)&bA[(wmi * 128 + mh * 64 + mi * 16 + lg) * 64 + rswz];
#pragma unroll
      for (int ni = 0; ni < NR; ++ni)
        bf[ni] = *(const bf16x8*)&bB[(wni * WN + ni * 16 + lg) * 64 + rswz];
      __builtin_amdgcn_s_setprio(1);
#pragma unroll
      for (int mi = 0; mi < 4; ++mi)
#pragma unroll
        for (int ni = 0; ni < NR; ++ni)
          acc[mh * 4 + mi][ni] = __builtin_amdgcn_mfma_f32_16x16x32_bf16(
              af[mi], bf[ni], acc[mh * 4 + mi][ni], 0, 0, 0);
      __builtin_amdgcn_s_setprio(0);
    }
  }

  if (nt & 1) {
    const int tau = nt - 1;
    asm volatile("s_waitcnt vmcnt(0)" ::: "memory");
    __builtin_amdgcn_s_barrier();
    const unsigned short* bA = As[tau & 1];
    const unsigned short* bB = Bs[tau & 1];
#pragma unroll
    for (int jj = 0; jj < 4; ++jj) {
      const int mh = jj & 1, kh = jj >> 1;
      const int rswz = ((kh * 4 + lh) ^ (lg & 7)) * 8;
      bf16x8 af[4], bf[NR];
#pragma unroll
      for (int mi = 0; mi < 4; ++mi)
        af[mi] = *(const bf16x8*)&bA[(wmi * 128 + mh * 64 + mi * 16 + lg) * 64 + rswz];
#pragma unroll
      for (int ni = 0; ni < NR; ++ni)
        bf[ni] = *(const bf16x8*)&bB[(wni * WN + ni * 16 + lg) * 64 + rswz];
      __builtin_amdgcn_s_setprio(1);
#pragma unroll
      for (int mi = 0; mi < 4; ++mi)
#pragma unroll
        for (int ni = 0; ni < NR; ++ni)
          acc[mh * 4 + mi][ni] = __builtin_amdgcn_mfma_f32_16x16x32_bf16(
              af[mi], bf[ni], acc[mh * 4 + mi][ni], 0, 0, 0);
      __builtin_amdgcn_s_setprio(0);
    }
  }

  const int row0 = bx * BM + wmi * 128;
  const int col0 = by * BN + wni * WN;
  const long coff = (long)zh * sCh + (long)zl * sCl;

  if (MODE == 4) {
#pragma unroll
    for (int mi = 0; mi < 8; ++mi)
#pragma unroll
      for (int r = 0; r < 4; ++r) {
        const int row = row0 + mi * 16 + lh * 4 + r;
        unsigned short* dq = (unsigned short*)Cv +
            (long)(row >> 11) * 6291456 + (long)by * 393216 + (long)(row & 2047) * 192;
#pragma unroll
        for (int ni = 0; ni < NR; ++ni)
          dq[wni * WN + ni * 16 + lg] = bf16r(acc[mi][ni][r] * alpha);
      }
  } else {
#pragma unroll
    for (int mi = 0; mi < 8; ++mi)
#pragma unroll
      for (int r = 0; r < 4; ++r) {
        const int row = row0 + mi * 16 + lh * 4 + r;
#pragma unroll
        for (int ni = 0; ni < NR; ++ni) {
          float v = acc[mi][ni][r] * alpha;
          if (MODE == 0)
            ((float*)Cv)[coff + (long)row * ldc + col0 + ni * 16 + lg] = v;
          else
            ((unsigned short*)Cv)[coff + (long)row * ldc + col0 + ni * 16 + lg] = bf16r(v);
        }
      }
  }
}

// =====================================================================
// 4-wave co-resident GEMM: 256 threads (2Mx2N waves), BM=BN=128, BK=64,
// dbuf-2, 64KB LDS -> 2 blocks/CU. (kabs / vhT / out-proj)
// MODE: 0 f32*alpha; 1 bf16*alpha.
// =====================================================================
template <int MODE>
__global__ __launch_bounds__(256) void gemm4w(
    const unsigned short* __restrict__ A, const unsigned short* __restrict__ B,
    void* __restrict__ Cv, float* __restrict__ laux,
    int Mrows, int K, int lda, int ldb, int ldc, int zs,
    long sAh, long sAl, long sBh, long sBl, long sCh, long sCl, float alpha)
{
  constexpr int BM = 128, BN = 128, WN = 64, NR = 4;

  __shared__ unsigned short As[2][BM * 64];
  __shared__ unsigned short Bs[2][BN * 64];

  const int tid = threadIdx.x;
  const int w = tid >> 6, l = tid & 63, lg = l & 15, lh = l >> 4;
  const int wmi = w >> 1, wni = w & 1;
  const int lrow = l >> 3;
  const int swz8 = ((l & 7) ^ lrow) * 8;

  int bx, by, z;
  map_block(bx, by, z);
  const int zh = z >> zs, zl = z & ((1 << zs) - 1);

  const unsigned short* Ab = A + zh * sAh + zl * sAl + (long)(bx * BM) * lda;
  const unsigned short* Bb = B + zh * sBh + zl * sBl + (long)(by * BN) * ldb;

  const int nt = K >> 6;

  auto stage = [&](int T) {
    const int k0 = T << 6;
    const int d = T & 1;
#pragma unroll
    for (int u = 0; u < 4; ++u) {
      const int rr = u * 32 + w * 8;
      GLOAD16(Ab + (long)(rr + lrow) * lda + k0 + swz8, &As[d][rr * 64]);
    }
#pragma unroll
    for (int u = 0; u < 4; ++u) {
      const int rr = u * 32 + w * 8;
      GLOAD16(Bb + (long)(rr + lrow) * ldb + k0 + swz8, &Bs[d][rr * 64]);
    }
  };

  f32x4 acc[4][NR] = {};

  stage(0);
  for (int t = 0; t < nt; ++t) {
    asm volatile("s_waitcnt vmcnt(0)" ::: "memory");
    __builtin_amdgcn_s_barrier();
    if (t + 1 < nt) stage(t + 1);
    const unsigned short* bA = As[t & 1];
    const unsigned short* bB = Bs[t & 1];
#pragma unroll
    for (int kh = 0; kh < 2; ++kh) {
      const int rswz = ((kh * 4 + lh) ^ (lg & 7)) * 8;
      bf16x8 af[4], bf[NR];
#pragma unroll
      for (int mi = 0; mi < 4; ++mi)
        af[mi] = *(const bf16x8*)&bA[(wmi * 64 + mi * 16 + lg) * 64 + rswz];
#pragma unroll
      for (int ni = 0; ni < NR; ++ni)
        bf[ni] = *(const bf16x8*)&bB[(wni * WN + ni * 16 + lg) * 64 + rswz];
      __builtin_amdgcn_s_setprio(1);
#pragma unroll
      for (int mi = 0; mi < 4; ++mi)
#pragma unroll
        for (int ni = 0; ni < NR; ++ni)
          acc[mi][ni] = __builtin_amdgcn_mfma_f32_16x16x32_bf16(
              af[mi], bf[ni], acc[mi][ni], 0, 0, 0);
      __builtin_amdgcn_s_setprio(0);
    }
  }

  const int row0 = bx * BM + wmi * 64;
  const int col0 = by * BN + wni * WN;
  const long coff = (long)zh * sCh + (long)zl * sCl;

#pragma unroll
  for (int mi = 0; mi < 4; ++mi)
#pragma unroll
    for (int r = 0; r < 4; ++r) {
      const int row = row0 + mi * 16 + lh * 4 + r;
#pragma unroll
      for (int ni = 0; ni < NR; ++ni) {
        float v = acc[mi][ni][r] * alpha;
        if (MODE == 0)
          ((float*)Cv)[coff + (long)row * ldc + col0 + ni * 16 + lg] = v;
        else
          ((unsigned short*)Cv)[coff + (long)row * ldc + col0 + ni * 16 + lg] = bf16r(v);
      }
    }
}

// =====================================================================
// Fused flash attention over absorbed latent heads.
// Per block: 64 q-rows x one z (b*16+h). 4 waves 2Mx2N. Q frags in VGPRs
// (K=192 fixed), K tiles in LDS dbuf (proven stage/swizzle), P in LDS
// (fixed-max softmax, LOG2E pre-folded into q192), V frags direct from
// L2-resident vhT, row-sums l via ones-MFMA. O = acc/l -> o_b bf16.
// LDS 57KB -> 2 blocks/CU. grid 1024 (32 row-blocks x 32 z), z-chunked XCD.
// =====================================================================
__global__ __launch_bounds__(256) void attn_fused(
    const unsigned short* __restrict__ q192, const unsigned short* __restrict__ kh,
    const unsigned short* __restrict__ vhT, unsigned short* __restrict__ o_b)
{
  __shared__ unsigned short Ks[2][3 * 64 * 64];   // 3 units [64 keys][64 d]
  __shared__ unsigned short Ps[64 * 72];          // [row][key], padded

  const int tid = threadIdx.x;
  const int w = tid >> 6, l = tid & 63, lg = l & 15, lh = l >> 4;
  const int wmi = w >> 1, wni = w & 1;
  const int lrow = l >> 3;
  const int swz8 = ((l & 7) ^ lrow) * 8;

  int id = blockIdx.x;                            // 1024 blocks
  id = (id & 7) * 128 + (id >> 3);                // chunked: 4 z per XCD
  const int bx = id & 31;
  const int z = id >> 5;
  const int b = z >> 4, hh = z & 15;

  const unsigned short* Qg = q192 + (long)z * 393216 + (long)(bx * 64) * 192;
  const unsigned short* Kg = kh + (long)z * 393216;
  const unsigned short* Vg = vhT + (long)z * 262144;

  // Q fragments in registers: rows wmi*32 + mi*16 + lg, k = s*32 + lh*8
  bf16x8 qf[2][6];
#pragma unroll
  for (int mi = 0; mi < 2; ++mi)
#pragma unroll
    for (int s = 0; s < 6; ++s)
      qf[mi][s] = *(const bf16x8*)&Qg[(wmi * 32 + mi * 16 + lg) * 192 + s * 32 + lh * 8];

  bf16x8 ones;
#pragma unroll
  for (int j = 0; j < 8; ++j) ((unsigned short*)&ones)[j] = 0x3F80;

  auto stageK = [&](int T) {
    if (T >= 32) return;
    const unsigned short* src = Kg + (long)(T * 64) * 192;
    unsigned short* dst = Ks[T & 1];
#pragma unroll
    for (int u = 0; u < 3; ++u)
#pragma unroll
      for (int i = 0; i < 2; ++i) {
        const int rr = w * 16 + i * 8;            // key rows staged by this wave
        GLOAD16(src + (long)(rr + lrow) * 192 + u * 64 + swz8, &dst[u * 4096 + rr * 64]);
      }
  };

  f32x4 acc_o[2][4] = {};
  f32x4 accl[2] = {};

  stageK(0);
  for (int t = 0; t < 32; ++t) {
    asm volatile("s_waitcnt vmcnt(0)" ::: "memory");
    __builtin_amdgcn_s_barrier();                 // K(t) staged; P(t-1) consumed
    stageK(t + 1);                                // fire-and-forget into buf^1
    const unsigned short* bK = Ks[t & 1];

    // ---- QK: S[64 rows][64 keys]; wave = rows wmi*32, keys wni*32 ----
    f32x4 acc_s[2][2] = {};
#pragma unroll
    for (int s = 0; s < 6; ++s) {
      const int u = s >> 1, half = s & 1;
      const int rswz = ((half * 4 + lh) ^ (lg & 7)) * 8;
      bf16x8 kf[2];
#pragma unroll
      for (int n = 0; n < 2; ++n)
        kf[n] = *(const bf16x8*)&bK[u * 4096 + (wni * 32 + n * 16 + lg) * 64 + rswz];
      __builtin_amdgcn_s_setprio(1);
#pragma unroll
      for (int mi = 0; mi < 2; ++mi)
#pragma unroll
        for (int n = 0; n < 2; ++n)
          acc_s[mi][n] = __builtin_amdgcn_mfma_f32_16x16x32_bf16(
              qf[mi][s], kf[n], acc_s[mi][n], 0, 0, 0);
      __builtin_amdgcn_s_setprio(0);
    }
    // ---- P = exp2(S) (fixed-max; LOG2E folded into q192) ----
#pragma unroll
    for (int mi = 0; mi < 2; ++mi)
#pragma unroll
      for (int n = 0; n < 2; ++n)
#pragma unroll
        for (int r = 0; r < 4; ++r)
          Ps[(wmi * 32 + mi * 16 + lh * 4 + r) * 72 + wni * 32 + n * 16 + lg] =
              bf16r(exp2f(acc_s[mi][n][r]));
    __builtin_amdgcn_s_barrier();                 // P complete (K reads also done)

    // ---- PV: O[64][128] += P[64][64] @ vhT_tile^T; l += P @ ones ----
#pragma unroll
    for (int k2 = 0; k2 < 2; ++k2) {
      bf16x8 pf[2], vf[4];
#pragma unroll
      for (int mi = 0; mi < 2; ++mi)
        pf[mi] = *(const bf16x8*)&Ps[(wmi * 32 + mi * 16 + lg) * 72 + k2 * 32 + lh * 8];
#pragma unroll
      for (int n = 0; n < 4; ++n)
        vf[n] = *(const bf16x8*)&Vg[(long)(wni * 64 + n * 16 + lg) * 2048 +
                                    t * 64 + k2 * 32 + lh * 8];
      __builtin_amdgcn_s_setprio(1);
#pragma unroll
      for (int mi = 0; mi < 2; ++mi) {
        accl[mi] = __builtin_amdgcn_mfma_f32_16x16x32_bf16(pf[mi], ones, accl[mi], 0, 0, 0);
#pragma unroll
        for (int n = 0; n < 4; ++n)
          acc_o[mi][n] = __builtin_amdgcn_mfma_f32_16x16x32_bf16(
              pf[mi], vf[n], acc_o[mi][n], 0, 0, 0);
      }
      __builtin_amdgcn_s_setprio(0);
    }
  }

  // ---- epilogue: O / l -> o_b[b*2048 + row][h*128 + d] ----
#pragma unroll
  for (int mi = 0; mi < 2; ++mi)
#pragma unroll
    for (int r = 0; r < 4; ++r) {
      const int row = bx * 64 + wmi * 32 + mi * 16 + lh * 4 + r;
      const float inv = 1.0f / accl[mi][r];
      unsigned short* dst = o_b + (long)(b * 2048 + row) * 2048 + hh * 128 + wni * 64;
#pragma unroll
      for (int n = 0; n < 4; ++n)
        dst[n * 16 + lg] = bf16r(acc_o[mi][n][r] * inv);
    }
}

// ---------- generic 128x128 bf16 GEMM (m97-class), odd shapes (kv_full) ----------
template <int MODE>
__global__ __launch_bounds__(256) void gemm_bt2(
    const unsigned short* __restrict__ A, const unsigned short* __restrict__ B,
    void* __restrict__ Cv, float* __restrict__ laux,
    int M, int Nstore, int K, int lda, int ldb, int ldc, int zs,
    long sAh, long sAl, long sBh, long sBl, long sCh, long sCl, float alpha)
{
  __shared__ unsigned short As[128 * 32];
  __shared__ unsigned short Bs[128 * 32];
  const int tid = threadIdx.x;
  const int w = tid >> 6, l = tid & 63, lg = l & 15, lh = l >> 4;

  int bx, by, z;
  map_block(bx, by, z);

  const int zh = z >> zs, zl = z & ((1 << zs) - 1);
  const unsigned short* Ab = A + zh * sAh + zl * sAl + (long)(bx * 128) * lda;
  const unsigned short* Bb = B + zh * sBh + zl * sBl + (long)(by * 128) * ldb;
  const int srow = l >> 2;
  const int scol = (((l & 3) ^ ((l >> 3) & 3)) * 8);
  const int wm = (w >> 1) * 64, wn = (w & 1) * 64;
  f32x4 acc[4][4] = {};

  const long ra0 = (long)(w * 16 + srow) * lda + scol;
  const long ra1 = (long)(64 + w * 16 + srow) * lda + scol;
  const long rb0 = (long)(w * 16 + srow) * ldb + scol;
  const long rb1 = (long)(64 + w * 16 + srow) * ldb + scol;
  unsigned short* lA0 = &As[(w * 16) * 32];
  unsigned short* lA1 = &As[(64 + w * 16) * 32];
  unsigned short* lB0 = &Bs[(w * 16) * 32];
  unsigned short* lB1 = &Bs[(64 + w * 16) * 32];

  const int rsw = ((lh ^ ((lg >> 1) & 3)) * 8);

  for (int k0 = 0; k0 < K; k0 += 32) {
    __syncthreads();
    GLOAD16(Ab + ra0 + k0, lA0);
    GLOAD16(Ab + ra1 + k0, lA1);
    GLOAD16(Bb + rb0 + k0, lB0);
    GLOAD16(Bb + rb1 + k0, lB1);
    __syncthreads();
    bf16x8 af[4], bfr[4];
#pragma unroll
    for (int m = 0; m < 4; m++) af[m] = *(const bf16x8*)&As[(wm + m * 16 + lg) * 32 + rsw];
#pragma unroll
    for (int n = 0; n < 4; n++) bfr[n] = *(const bf16x8*)&Bs[(wn + n * 16 + lg) * 32 + rsw];
#pragma unroll
    for (int m = 0; m < 4; m++)
#pragma unroll
      for (int n = 0; n < 4; n++)
        acc[m][n] = __builtin_amdgcn_mfma_f32_16x16x32_bf16(af[m], bfr[n], acc[m][n], 0, 0, 0);
  }

  const int row0 = bx * 128 + wm, col0 = by * 128 + wn;
  long coff = zh * sCh + zl * sCl;

#pragma unroll
  for (int m = 0; m < 4; m++)
#pragma unroll
    for (int r = 0; r < 4; r++) {
      const int row = row0 + m * 16 + lh * 4 + r;
#pragma unroll
      for (int n = 0; n < 4; n++) {
        int col = col0 + n * 16 + lg;
        if (col < Nstore) {
          float v = acc[m][n][r] * alpha;
          if (MODE == 0)
            ((float*)Cv)[coff + (long)row * ldc + col] = v;
          else
            ((unsigned short*)Cv)[coff + (long)row * ldc + col] = bf16r(v);
        }
      }
    }
}

// ---------- kv epilogue: tanh-norm -> kvn bf16; roped k_pe -> kh[...][128:192) x16 heads ----
__global__ void kv_epilogue(const float* __restrict__ kvf, const float* __restrict__ fc,
                            const float* __restrict__ fs, const float* __restrict__ alpha,
                            const float* __restrict__ gamma, const float* __restrict__ beta,
                            unsigned short* __restrict__ kvn, unsigned short* __restrict__ kh) {
  const int n = blockIdx.x;
  const int b = n >> 11, s = n & 2047;
  const int tid = threadIdx.x;
  const float a = alpha[0];
  const float* src = kvf + (long)n * 576;
  unsigned short* dst = kvn + (long)n * 512;
#pragma unroll
  for (int c0 = 0; c0 < 512; c0 += 256) {
    int c = c0 + tid;
    float v = tanhf(a * src[c]) * gamma[c] + beta[c];
    dst[c] = bf16r(v);
  }
  if (tid < 32) {
    int i = tid;
    float re = src[512 + 2 * i], im = src[512 + 2 * i + 1];
    float co = fc[s * 32 + i], si = fs[s * 32 + i];
    ushort2 v;
    v.x = bf16r(re * co - im * si);
    v.y = bf16r(re * si + im * co);
#pragma unroll
    for (int h = 0; h < 16; h++)
      *(ushort2*)&kh[((long)(b * 16 + h) * 2048 + s) * 192 + 128 + 2 * i] = v;
  }
}

// ---------- q rope fixup: in-place rotate q192[...][128:192) (values pre-scaled) ----------
__global__ void q_ropefix(unsigned short* __restrict__ q192, const float* __restrict__ fc,
                          const float* __restrict__ fs) {
  const int n = blockIdx.x;
  const int b = n >> 11, s = n & 2047;
  const int tid = threadIdx.x;
  for (int it = tid; it < 512; it += 256) {
    int h = it >> 5, i = it & 31;
    unsigned short* dd = q192 + ((long)(b * 16 + h) * 2048 + s) * 192 + 128 + 2 * i;
    float re = bf2f(dd[0]), im = bf2f(dd[1]);
    float co = fc[s * 32 + i], si = fs[s * 32 + i];
    ushort2 o;
    o.x = bf16r(re * co - im * si);
    o.y = bf16r(re * si + im * co);
    *(ushort2*)dd = o;
  }
}

// ---------- host launcher ----------
extern "C" void kernel_launch(void* const* d_in, const int* in_sizes, int n_in,
                              void* d_out, int out_size, void* d_ws, size_t ws_size,
                              hipStream_t stream) {
  const float* x = (const float*)d_in[0];
  const float* fc = (const float*)d_in[1];
  const float* fs = (const float*)d_in[2];
  const float* wq = (const float*)d_in[3];
  const float* wkva = (const float*)d_in[4];
  const float* wkvb = (const float*)d_in[5];
  const float* wo = (const float*)d_in[6];
  const float* alpha = (const float*)d_in[7];
  const float* gamma = (const float*)d_in[8];
  const float* beta = (const float*)d_in[9];
  float* out = (float*)d_out;

  char* p = (char*)d_ws;
  auto take = [&](size_t bytes) {
    char* r = p;
    p += (bytes + 255) & ~(size_t)255;
    return r;
  };
  unsigned short* wqb   = (unsigned short*)take(6291456ull * 2);    // wq bf16 [3072][2048]
  float*          kvf   = (float*)take(2359296ull * 4);             // kv_full f32 [4096][576]
  unsigned short* xb    = (unsigned short*)take(8388608ull * 2);    // x bf16 [4096][2048]
  unsigned short* wab   = (unsigned short*)take(1310720ull * 2);    // wkv_a bf16 padded [640][2048]
  unsigned short* wbb   = (unsigned short*)take(2097152ull * 2);    // wkv_b bf16 [4096][512]
  unsigned short* wob   = (unsigned short*)take(4194304ull * 2);    // wo bf16 [2048][2048]
  unsigned short* kvn   = (unsigned short*)take(2097152ull * 2);    // [4096][512]
  unsigned short* kh    = (unsigned short*)take(12582912ull * 2);   // [32][2048][192]
  unsigned short* q192  = (unsigned short*)take(12582912ull * 2);   // [32][2048][192]
  unsigned short* vhT   = (unsigned short*)take(8388608ull * 2);    // [32][128][2048]
  unsigned short* o_b   = (unsigned short*)take(8388608ull * 2);    // [4096][2048]

  const float scale = 1.0f / sqrtf(192.0f);
  const float scaleL = scale * LOG2E;     // fold LOG2E into q so attn uses bare exp2

  // fused conversions
  conv_all<<<21760, 256, 0, stream>>>(x, wq, wkva, wkvb, wo, xb, wqb, wab, wbb, wob);

  // q192 = (scale*LOG2E) * (x @ wq^T) scattered head-major -- 8-phase 256x192
  gemm8p<192, 4><<<dim3(16, 16, 1), 512, 0, stream>>>(
      xb, wqb, q192, nullptr, 4096, 2048, 2048, 2048, 192, 0, 0, 0, 0, 0, 0, 0, scaleL);
  // kv_full = x @ wkv_a^T (f32)
  gemm_bt2<0><<<dim3(32, 5, 1), 256, 0, stream>>>(xb, wab, kvf, nullptr, 4096, 576, 2048,
                                                  2048, 2048, 576, 0, 0, 0, 0, 0, 0, 0, 1.0f);
  // kvn (tanh-norm) + roped k_pe broadcast into kh[...][128:192)
  kv_epilogue<<<4096, 256, 0, stream>>>(kvf, fc, fs, alpha, gamma, beta, kvn, kh);
  // k_abs[h] = kvn @ wk_h^T -> kh[:, :, 0:128) -- 4-wave, grid 512, 2/CU
  gemm4w<1><<<dim3(16, 1, 32), 256, 0, stream>>>(
      kvn, wbb, kh, nullptr, 2048, 512, 512, 512, 192, 4,
      1048576, 0, 0, 131072, 6291456, 393216, 1.0f);
  // rope the pe part of q192 in place (linear; LOG2E factor commutes)
  q_ropefix<<<4096, 256, 0, stream>>>(q192, fc, fs);
  // vhT[g] = wv_h @ kvn_b^T [128][2048] -- 4-wave, grid 512
  gemm4w<1><<<dim3(1, 16, 32), 256, 0, stream>>>(
      wbb + 128 * 512, kvn, vhT, nullptr, 128, 512, 512, 512, 2048, 4,
      0, 131072, 1048576, 0, 4194304, 262144, 1.0f);

  // fused flash attention: o_b[b][s][h*128+d] in one dispatch
  attn_fused<<<1024, 256, 0, stream>>>(q192, kh, vhT, o_b);

  // out = o_b @ wo^T (f32) -- 4-wave co-resident, grid 512, L2-rect
  gemm4w<0><<<dim3(32, 16, 1), 256, 0, stream>>>(
      o_b, wob, out, nullptr, 4096, 2048, 2048, 2048, 2048, 0,
      0, 0, 0, 0, 0, 0, 1.0f);
}

// Round 16
// 369.075 us; speedup vs baseline: 1.5114x; 1.0545x over previous
//
#include <hip/hip_runtime.h>
#include <math.h>

// ---------- common types / helpers ----------
typedef __bf16 bf16x8 __attribute__((ext_vector_type(8)));
typedef float f32x4 __attribute__((ext_vector_type(4)));

#define LOG2E 1.4426950408889634f

__device__ __forceinline__ unsigned short bf16r(float f) {
  unsigned u = __float_as_uint(f);
  u = (u + 0x7fffu + ((u >> 16) & 1u)) >> 16;
  return (unsigned short)u;
}
__device__ __forceinline__ unsigned short bfc(float f) {
  __bf16 h = (__bf16)f;                      // HW RNE convert
  return __builtin_bit_cast(unsigned short, h);
}
__device__ __forceinline__ float bf2f(unsigned short h) {
  return __uint_as_float(((unsigned)h) << 16);
}

// async global->LDS, 16B per lane; LDS dest is wave-uniform base + lane*16B (linear)
#define GLOAD16(gsrc, ldst)                                                        \
  __builtin_amdgcn_global_load_lds(                                                \
      (const __attribute__((address_space(1))) void*)(gsrc),                       \
      (__attribute__((address_space(3))) void*)(ldst), 16, 0, 0)

// Block mapping: XCD-aware. gz==1 grids: L2-rect; batched: chunked z-locality.
__device__ __forceinline__ void map_block(int& bx, int& by, int& z) {
  const int gx = gridDim.x, gy = gridDim.y;
  const int nwg = gx * gy * gridDim.z;
  int id = blockIdx.x + gx * (blockIdx.y + gy * blockIdx.z);
  if (gridDim.z == 1 && (gx & 3) == 0 && (gy & 1) == 0 && (nwg & 7) == 0) {
    const int xcd = id & 7, k = id >> 3;
    const int rx = gx >> 2, ry = gy >> 1;
    bx = (xcd & 3) * rx + (k % rx);
    by = (xcd >> 2) * ry + (k / rx);
    z = 0;
  } else {
    if ((nwg & 7) == 0) id = (id & 7) * (nwg >> 3) + (id >> 3);
    bx = id % gx;
    const int t1 = id / gx;
    by = t1 % gy;
    z = t1 / gy;
  }
}

// ---------- fused conversion kernel: all 5 f32->bf16 weight/input converts ----------
__global__ void conv_all(const float* __restrict__ x, const float* __restrict__ wq,
                         const float* __restrict__ wkva, const float* __restrict__ wkvb,
                         const float* __restrict__ wo,
                         unsigned short* __restrict__ xb, unsigned short* __restrict__ wqb,
                         unsigned short* __restrict__ wab, unsigned short* __restrict__ wbb,
                         unsigned short* __restrict__ wob) {
  int bid = blockIdx.x;
  const float* src; unsigned short* dst; long nsrc;
  if (bid < 8192)       {               src = x;    dst = xb;  nsrc = 8388608; }
  else if (bid < 14336) { bid -= 8192;  src = wq;   dst = wqb; nsrc = 6291456; }
  else if (bid < 15616) { bid -= 14336; src = wkva; dst = wab; nsrc = 1179648; } // pad to 640 rows
  else if (bid < 17664) { bid -= 15616; src = wkvb; dst = wbb; nsrc = 2097152; }
  else                  { bid -= 17664; src = wo;   dst = wob; nsrc = 4194304; }
  long i = ((long)bid * 256 + threadIdx.x) * 4;
  ushort4 o;
  if (i < nsrc) {
    float4 v = *(const float4*)&src[i];
    o.x = bf16r(v.x); o.y = bf16r(v.y); o.z = bf16r(v.z); o.w = bf16r(v.w);
  } else {
    o.x = 0; o.y = 0; o.z = 0; o.w = 0;
  }
  *(ushort4*)&dst[i] = o;
}

// =====================================================================
// 8-phase deep-pipelined GEMM (m201-style). BM=256, 8 waves 2Mx4N,
// BK=64, dbuf-2 LDS, 2 K-tiles per iter + odd-nt tail. (q-proj)
// MODE: 0 f32*alpha; 4 scatter into q192 [b*16+by][s][192].
// =====================================================================
template <int BN, int MODE>
__global__ __launch_bounds__(512) void gemm8p(
    const unsigned short* __restrict__ A, const unsigned short* __restrict__ B,
    void* __restrict__ Cv, float* __restrict__ laux,
    int Mrows, int K, int lda, int ldb, int ldc, int zs,
    long sAh, long sAl, long sBh, long sBl, long sCh, long sCl, float alpha)
{
  constexpr int BM = 256;
  constexpr int WN = BN / 4;
  constexpr int NR = WN / 16;
  constexpr int BU = BN / 64;
  constexpr int BU1 = (BU + 1) / 2;

  __shared__ unsigned short As[2][BM * 64];
  __shared__ unsigned short Bs[2][BN * 64];

  const int tid = threadIdx.x;
  const int w = tid >> 6, l = tid & 63, lg = l & 15, lh = l >> 4;
  const int wmi = w >> 2, wni = w & 3;
  const int lrow = l >> 3;
  const int swz8 = ((l & 7) ^ lrow) * 8;

  int bx, by, z;
  map_block(bx, by, z);
  const int zh = z >> zs, zl = z & ((1 << zs) - 1);

  const unsigned short* Ab = A + zh * sAh + zl * sAl + (long)(bx * BM) * lda;
  const unsigned short* Bb = B + zh * sBh + zl * sBl + (long)(by * BN) * ldb;

  const int nt = K >> 6;

  auto stA = [&](int T, int u) {
    if (T >= nt) return;
    const int rr = u * 64 + w * 8;
    GLOAD16(Ab + (long)(rr + lrow) * lda + (T << 6) + swz8, &As[T & 1][rr * 64]);
  };
  auto stB = [&](int T, int u) {
    if (T >= nt) return;
    const int rr = u * 64 + w * 8;
    GLOAD16(Bb + (long)(rr + lrow) * ldb + (T << 6) + swz8, &Bs[T & 1][rr * 64]);
  };

  stA(0, 0); stA(0, 1); stA(0, 2); stA(0, 3);
#pragma unroll
  for (int u = 0; u < BU; ++u) stB(0, u);
  stA(1, 0); stA(1, 2);

  f32x4 acc[8][NR] = {};

  const int nit = nt >> 1;
  for (int i = 0; i < nit; ++i) {
    const int t0 = 2 * i;
#pragma unroll
    for (int j = 0; j < 8; ++j) {
      const int tau = t0 + (j >> 2);
      const int jj = j & 3;
      const int mh = jj & 1, kh = jj >> 1;
      if (jj == 0) {
        if (tau + 1 < nt) asm volatile("s_waitcnt vmcnt(2)" ::: "memory");
        else              asm volatile("s_waitcnt vmcnt(0)" ::: "memory");
      } else {
        asm volatile("" ::: "memory");
      }
      __builtin_amdgcn_s_barrier();
      if (j == 0)      { stA(t0 + 1, 1); stA(t0 + 1, 3); }
      else if (j == 1) { for (int u = 0; u < BU1; ++u) stB(t0 + 1, u); }
      else if (j == 2) { for (int u = BU1; u < BU; ++u) stB(t0 + 1, u); }
      else if (j == 3) { stA(t0 + 2, 0); stA(t0 + 2, 2); }
      else if (j == 4) { stA(t0 + 2, 1); stA(t0 + 2, 3); }
      else if (j == 5) { for (int u = 0; u < BU1; ++u) stB(t0 + 2, u); }
      else if (j == 6) { for (int u = BU1; u < BU; ++u) stB(t0 + 2, u); }
      else             { stA(t0 + 3, 0); stA(t0 + 3, 2); }
      const unsigned short* bA = As[tau & 1];
      const unsigned short* bB = Bs[tau & 1];
      const int rswz = ((kh * 4 + lh) ^ (lg & 7)) * 8;
      bf16x8 af[4], bf[NR];
#pragma unroll
      for (int mi = 0; mi < 4; ++mi)
        af[mi] = *(const bf16x8*)&bA[(wmi * 128 + mh * 64 + mi * 16 + lg) * 64 + rswz];
#pragma unroll
      for (int ni = 0; ni < NR; ++ni)
        bf[ni] = *(const bf16x8*)&bB[(wni * WN + ni * 16 + lg) * 64 + rswz];
      __builtin_amdgcn_s_setprio(1);
#pragma unroll
      for (int mi = 0; mi < 4; ++mi)
#pragma unroll
        for (int ni = 0; ni < NR; ++ni)
          acc[mh * 4 + mi][ni] = __builtin_amdgcn_mfma_f32_16x16x32_bf16(
              af[mi], bf[ni], acc[mh * 4 + mi][ni], 0, 0, 0);
      __builtin_amdgcn_s_setprio(0);
    }
  }

  if (nt & 1) {
    const int tau = nt - 1;
    asm volatile("s_waitcnt vmcnt(0)" ::: "memory");
    __builtin_amdgcn_s_barrier();
    const unsigned short* bA = As[tau & 1];
    const unsigned short* bB = Bs[tau & 1];
#pragma unroll
    for (int jj = 0; jj < 4; ++jj) {
      const int mh = jj & 1, kh = jj >> 1;
      const int rswz = ((kh * 4 + lh) ^ (lg & 7)) * 8;
      bf16x8 af[4], bf[NR];
#pragma unroll
      for (int mi = 0; mi < 4; ++mi)
        af[mi] = *(const bf16x8*)&bA[(wmi * 128 + mh * 64 + mi * 16 + lg) * 64 + rswz];
#pragma unroll
      for (int ni = 0; ni < NR; ++ni)
        bf[ni] = *(const bf16x8*)&bB[(wni * WN + ni * 16 + lg) * 64 + rswz];
      __builtin_amdgcn_s_setprio(1);
#pragma unroll
      for (int mi = 0; mi < 4; ++mi)
#pragma unroll
        for (int ni = 0; ni < NR; ++ni)
          acc[mh * 4 + mi][ni] = __builtin_amdgcn_mfma_f32_16x16x32_bf16(
              af[mi], bf[ni], acc[mh * 4 + mi][ni], 0, 0, 0);
      __builtin_amdgcn_s_setprio(0);
    }
  }

  const int row0 = bx * BM + wmi * 128;
  const int col0 = by * BN + wni * WN;
  const long coff = (long)zh * sCh + (long)zl * sCl;

  if (MODE == 4) {
#pragma unroll
    for (int mi = 0; mi < 8; ++mi)
#pragma unroll
      for (int r = 0; r < 4; ++r) {
        const int row = row0 + mi * 16 + lh * 4 + r;
        unsigned short* dq = (unsigned short*)Cv +
            (long)(row >> 11) * 6291456 + (long)by * 393216 + (long)(row & 2047) * 192;
#pragma unroll
        for (int ni = 0; ni < NR; ++ni)
          dq[wni * WN + ni * 16 + lg] = bf16r(acc[mi][ni][r] * alpha);
      }
  } else {
#pragma unroll
    for (int mi = 0; mi < 8; ++mi)
#pragma unroll
      for (int r = 0; r < 4; ++r) {
        const int row = row0 + mi * 16 + lh * 4 + r;
#pragma unroll
        for (int ni = 0; ni < NR; ++ni) {
          float v = acc[mi][ni][r] * alpha;
          if (MODE == 0)
            ((float*)Cv)[coff + (long)row * ldc + col0 + ni * 16 + lg] = v;
          else
            ((unsigned short*)Cv)[coff + (long)row * ldc + col0 + ni * 16 + lg] = bf16r(v);
        }
      }
  }
}

// =====================================================================
// 4-wave co-resident GEMM: 256 threads (2Mx2N waves), BM=BN=128, BK=64,
// dbuf-2, 64KB LDS -> 2 blocks/CU. (kabs / vhT / out-proj)
// MODE: 0 f32*alpha; 1 bf16*alpha.
// =====================================================================
template <int MODE>
__global__ __launch_bounds__(256) void gemm4w(
    const unsigned short* __restrict__ A, const unsigned short* __restrict__ B,
    void* __restrict__ Cv, float* __restrict__ laux,
    int Mrows, int K, int lda, int ldb, int ldc, int zs,
    long sAh, long sAl, long sBh, long sBl, long sCh, long sCl, float alpha)
{
  constexpr int BM = 128, BN = 128, WN = 64, NR = 4;

  __shared__ unsigned short As[2][BM * 64];
  __shared__ unsigned short Bs[2][BN * 64];

  const int tid = threadIdx.x;
  const int w = tid >> 6, l = tid & 63, lg = l & 15, lh = l >> 4;
  const int wmi = w >> 1, wni = w & 1;
  const int lrow = l >> 3;
  const int swz8 = ((l & 7) ^ lrow) * 8;

  int bx, by, z;
  map_block(bx, by, z);
  const int zh = z >> zs, zl = z & ((1 << zs) - 1);

  const unsigned short* Ab = A + zh * sAh + zl * sAl + (long)(bx * BM) * lda;
  const unsigned short* Bb = B + zh * sBh + zl * sBl + (long)(by * BN) * ldb;

  const int nt = K >> 6;

  auto stage = [&](int T) {
    const int k0 = T << 6;
    const int d = T & 1;
#pragma unroll
    for (int u = 0; u < 4; ++u) {
      const int rr = u * 32 + w * 8;
      GLOAD16(Ab + (long)(rr + lrow) * lda + k0 + swz8, &As[d][rr * 64]);
    }
#pragma unroll
    for (int u = 0; u < 4; ++u) {
      const int rr = u * 32 + w * 8;
      GLOAD16(Bb + (long)(rr + lrow) * ldb + k0 + swz8, &Bs[d][rr * 64]);
    }
  };

  f32x4 acc[4][NR] = {};

  stage(0);
  for (int t = 0; t < nt; ++t) {
    asm volatile("s_waitcnt vmcnt(0)" ::: "memory");
    __builtin_amdgcn_s_barrier();
    if (t + 1 < nt) stage(t + 1);
    const unsigned short* bA = As[t & 1];
    const unsigned short* bB = Bs[t & 1];
#pragma unroll
    for (int kh = 0; kh < 2; ++kh) {
      const int rswz = ((kh * 4 + lh) ^ (lg & 7)) * 8;
      bf16x8 af[4], bf[NR];
#pragma unroll
      for (int mi = 0; mi < 4; ++mi)
        af[mi] = *(const bf16x8*)&bA[(wmi * 64 + mi * 16 + lg) * 64 + rswz];
#pragma unroll
      for (int ni = 0; ni < NR; ++ni)
        bf[ni] = *(const bf16x8*)&bB[(wni * WN + ni * 16 + lg) * 64 + rswz];
      __builtin_amdgcn_s_setprio(1);
#pragma unroll
      for (int mi = 0; mi < 4; ++mi)
#pragma unroll
        for (int ni = 0; ni < NR; ++ni)
          acc[mi][ni] = __builtin_amdgcn_mfma_f32_16x16x32_bf16(
              af[mi], bf[ni], acc[mi][ni], 0, 0, 0);
      __builtin_amdgcn_s_setprio(0);
    }
  }

  const int row0 = bx * BM + wmi * 64;
  const int col0 = by * BN + wni * WN;
  const long coff = (long)zh * sCh + (long)zl * sCl;

#pragma unroll
  for (int mi = 0; mi < 4; ++mi)
#pragma unroll
    for (int r = 0; r < 4; ++r) {
      const int row = row0 + mi * 16 + lh * 4 + r;
#pragma unroll
      for (int ni = 0; ni < NR; ++ni) {
        float v = acc[mi][ni][r] * alpha;
        if (MODE == 0)
          ((float*)Cv)[coff + (long)row * ldc + col0 + ni * 16 + lg] = v;
        else
          ((unsigned short*)Cv)[coff + (long)row * ldc + col0 + ni * 16 + lg] = bf16r(v);
      }
    }
}

// =====================================================================
// Fused flash attention v2 over absorbed latent heads.
// Per block: 64 q-rows x one z. 4 waves 2Mx2N. Q frags in VGPRs; K in LDS
// dbuf (full-tile prefetch cover); V frags REGISTER double-buffered with
// full-tile cover (vfA/vfB ping-pong, loads issued at tile top); P in LDS
// (fixed-max softmax, exp2(s*LOG2E) in-kernel for precision); row-sums l
// via ones-MFMA. LDS 57KB -> 2 blocks/CU; launch_bounds(256,2) caps VGPR.
// =====================================================================
__global__ __launch_bounds__(256, 2) void attn_fused(
    const unsigned short* __restrict__ q192, const unsigned short* __restrict__ kh,
    const unsigned short* __restrict__ vhT, unsigned short* __restrict__ o_b)
{
  __shared__ unsigned short Ks[2][3 * 64 * 64];   // 3 units [64 keys][64 d]
  __shared__ unsigned short Ps[64 * 72];          // [row][key], padded

  const int tid = threadIdx.x;
  const int w = tid >> 6, l = tid & 63, lg = l & 15, lh = l >> 4;
  const int wmi = w >> 1, wni = w & 1;
  const int lrow = l >> 3;
  const int swz8 = ((l & 7) ^ lrow) * 8;

  int id = blockIdx.x;                            // 1024 blocks
  id = (id & 7) * 128 + (id >> 3);                // chunked: 4 z per XCD
  const int bx = id & 31;
  const int z = id >> 5;
  const int b = z >> 4, hh = z & 15;

  const unsigned short* Qg = q192 + (long)z * 393216 + (long)(bx * 64) * 192;
  const unsigned short* Kg = kh + (long)z * 393216;
  const unsigned short* Vg = vhT + (long)z * 262144;

  // Q fragments in registers: rows wmi*32 + mi*16 + lg, k = s*32 + lh*8
  bf16x8 qf[2][6];
#pragma unroll
  for (int mi = 0; mi < 2; ++mi)
#pragma unroll
    for (int s = 0; s < 6; ++s)
      qf[mi][s] = *(const bf16x8*)&Qg[(wmi * 32 + mi * 16 + lg) * 192 + s * 32 + lh * 8];

  bf16x8 ones;
#pragma unroll
  for (int j = 0; j < 8; ++j) ((unsigned short*)&ones)[j] = 0x3F80;

  auto stageK = [&](int T) {
    if (T >= 32) return;
    const unsigned short* src = Kg + (long)(T * 64) * 192;
    unsigned short* dst = Ks[T & 1];
#pragma unroll
    for (int u = 0; u < 3; ++u)
#pragma unroll
      for (int i = 0; i < 2; ++i) {
        const int rr = w * 16 + i * 8;            // key rows staged by this wave
        GLOAD16(src + (long)(rr + lrow) * 192 + u * 64 + swz8, &dst[u * 4096 + rr * 64]);
      }
  };
  // V fragments for tile T into registers (j = k2*4 + n)
  auto loadV = [&](int T, bf16x8 (&vf)[8]) {
    if (T >= 32) return;
#pragma unroll
    for (int j = 0; j < 8; ++j)
      vf[j] = *(const bf16x8*)&Vg[(long)(wni * 64 + (j & 3) * 16 + lg) * 2048 +
                                  T * 64 + (j >> 2) * 32 + lh * 8];
  };

  f32x4 acc_o[2][4] = {};
  f32x4 accl[2] = {};
  bf16x8 vfA[8], vfB[8];

  stageK(0);
  loadV(0, vfA);

  auto tile = [&](int t, bf16x8 (&vcur)[8], bf16x8 (&vnext)[8]) {
    asm volatile("s_waitcnt vmcnt(0)" ::: "memory");
    __builtin_amdgcn_s_barrier();                 // K(t)+V(t) ready; P(t-1) consumed
    stageK(t + 1);                                // fire-and-forget -> Ks[(t+1)&1]
    loadV(t + 1, vnext);                          // full-tile cover for V(t+1)
    const unsigned short* bK = Ks[t & 1];

    // ---- QK: S[64 rows][64 keys]; 3 u-blocks of {4 ds_read, 8 MFMA} ----
    f32x4 acc_s[2][2] = {};
#pragma unroll
    for (int u = 0; u < 3; ++u) {
      bf16x8 kf[4];
#pragma unroll
      for (int half = 0; half < 2; ++half) {
        const int rswz = ((half * 4 + lh) ^ (lg & 7)) * 8;
#pragma unroll
        for (int n = 0; n < 2; ++n)
          kf[half * 2 + n] =
              *(const bf16x8*)&bK[u * 4096 + (wni * 32 + n * 16 + lg) * 64 + rswz];
      }
      __builtin_amdgcn_s_setprio(1);
#pragma unroll
      for (int half = 0; half < 2; ++half)
#pragma unroll
        for (int mi = 0; mi < 2; ++mi)
#pragma unroll
          for (int n = 0; n < 2; ++n)
            acc_s[mi][n] = __builtin_amdgcn_mfma_f32_16x16x32_bf16(
                qf[mi][u * 2 + half], kf[half * 2 + n], acc_s[mi][n], 0, 0, 0);
      __builtin_amdgcn_s_setprio(0);
    }
    // ---- P = exp2(S*LOG2E) (fixed-max), native bf16 convert ----
#pragma unroll
    for (int mi = 0; mi < 2; ++mi)
#pragma unroll
      for (int n = 0; n < 2; ++n)
#pragma unroll
        for (int r = 0; r < 4; ++r)
          Ps[(wmi * 32 + mi * 16 + lh * 4 + r) * 72 + wni * 32 + n * 16 + lg] =
              bfc(exp2f(acc_s[mi][n][r] * LOG2E));
    __builtin_amdgcn_s_barrier();                 // P complete (K reads also done)

    // ---- PV: O[64][128] += P[64][64] @ V^T (regs); l += P @ ones ----
#pragma unroll
    for (int k2 = 0; k2 < 2; ++k2) {
      bf16x8 pf[2];
#pragma unroll
      for (int mi = 0; mi < 2; ++mi)
        pf[mi] = *(const bf16x8*)&Ps[(wmi * 32 + mi * 16 + lg) * 72 + k2 * 32 + lh * 8];
      __builtin_amdgcn_s_setprio(1);
#pragma unroll
      for (int mi = 0; mi < 2; ++mi) {
        accl[mi] = __builtin_amdgcn_mfma_f32_16x16x32_bf16(pf[mi], ones, accl[mi], 0, 0, 0);
#pragma unroll
        for (int n = 0; n < 4; ++n)
          acc_o[mi][n] = __builtin_amdgcn_mfma_f32_16x16x32_bf16(
              pf[mi], vcur[k2 * 4 + n], acc_o[mi][n], 0, 0, 0);
      }
      __builtin_amdgcn_s_setprio(0);
    }
  };

  for (int tt = 0; tt < 16; ++tt) {
    tile(2 * tt, vfA, vfB);
    tile(2 * tt + 1, vfB, vfA);
  }

  // ---- epilogue: O / l -> o_b[b*2048 + row][h*128 + d] ----
#pragma unroll
  for (int mi = 0; mi < 2; ++mi)
#pragma unroll
    for (int r = 0; r < 4; ++r) {
      const int row = bx * 64 + wmi * 32 + mi * 16 + lh * 4 + r;
      const float inv = 1.0f / accl[mi][r];
      unsigned short* dst = o_b + (long)(b * 2048 + row) * 2048 + hh * 128 + wni * 64;
#pragma unroll
      for (int n = 0; n < 4; ++n)
        dst[n * 16 + lg] = bfc(acc_o[mi][n][r] * inv);
    }
}

// ---------- generic 128x128 bf16 GEMM (m97-class), odd shapes (kv_full) ----------
template <int MODE>
__global__ __launch_bounds__(256) void gemm_bt2(
    const unsigned short* __restrict__ A, const unsigned short* __restrict__ B,
    void* __restrict__ Cv, float* __restrict__ laux,
    int M, int Nstore, int K, int lda, int ldb, int ldc, int zs,
    long sAh, long sAl, long sBh, long sBl, long sCh, long sCl, float alpha)
{
  __shared__ unsigned short As[128 * 32];
  __shared__ unsigned short Bs[128 * 32];
  const int tid = threadIdx.x;
  const int w = tid >> 6, l = tid & 63, lg = l & 15, lh = l >> 4;

  int bx, by, z;
  map_block(bx, by, z);

  const int zh = z >> zs, zl = z & ((1 << zs) - 1);
  const unsigned short* Ab = A + zh * sAh + zl * sAl + (long)(bx * 128) * lda;
  const unsigned short* Bb = B + zh * sBh + zl * sBl + (long)(by * 128) * ldb;
  const int srow = l >> 2;
  const int scol = (((l & 3) ^ ((l >> 3) & 3)) * 8);
  const int wm = (w >> 1) * 64, wn = (w & 1) * 64;
  f32x4 acc[4][4] = {};

  const long ra0 = (long)(w * 16 + srow) * lda + scol;
  const long ra1 = (long)(64 + w * 16 + srow) * lda + scol;
  const long rb0 = (long)(w * 16 + srow) * ldb + scol;
  const long rb1 = (long)(64 + w * 16 + srow) * ldb + scol;
  unsigned short* lA0 = &As[(w * 16) * 32];
  unsigned short* lA1 = &As[(64 + w * 16) * 32];
  unsigned short* lB0 = &Bs[(w * 16) * 32];
  unsigned short* lB1 = &Bs[(64 + w * 16) * 32];

  const int rsw = ((lh ^ ((lg >> 1) & 3)) * 8);

  for (int k0 = 0; k0 < K; k0 += 32) {
    __syncthreads();
    GLOAD16(Ab + ra0 + k0, lA0);
    GLOAD16(Ab + ra1 + k0, lA1);
    GLOAD16(Bb + rb0 + k0, lB0);
    GLOAD16(Bb + rb1 + k0, lB1);
    __syncthreads();
    bf16x8 af[4], bfr[4];
#pragma unroll
    for (int m = 0; m < 4; m++) af[m] = *(const bf16x8*)&As[(wm + m * 16 + lg) * 32 + rsw];
#pragma unroll
    for (int n = 0; n < 4; n++) bfr[n] = *(const bf16x8*)&Bs[(wn + n * 16 + lg) * 32 + rsw];
#pragma unroll
    for (int m = 0; m < 4; m++)
#pragma unroll
      for (int n = 0; n < 4; n++)
        acc[m][n] = __builtin_amdgcn_mfma_f32_16x16x32_bf16(af[m], bfr[n], acc[m][n], 0, 0, 0);
  }

  const int row0 = bx * 128 + wm, col0 = by * 128 + wn;
  long coff = zh * sCh + zl * sCl;

#pragma unroll
  for (int m = 0; m < 4; m++)
#pragma unroll
    for (int r = 0; r < 4; r++) {
      const int row = row0 + m * 16 + lh * 4 + r;
#pragma unroll
      for (int n = 0; n < 4; n++) {
        int col = col0 + n * 16 + lg;
        if (col < Nstore) {
          float v = acc[m][n][r] * alpha;
          if (MODE == 0)
            ((float*)Cv)[coff + (long)row * ldc + col] = v;
          else
            ((unsigned short*)Cv)[coff + (long)row * ldc + col] = bf16r(v);
        }
      }
    }
}

// ---------- kv epilogue: tanh-norm -> kvn bf16; roped k_pe -> kh[...][128:192) x16 heads ----
__global__ void kv_epilogue(const float* __restrict__ kvf, const float* __restrict__ fc,
                            const float* __restrict__ fs, const float* __restrict__ alpha,
                            const float* __restrict__ gamma, const float* __restrict__ beta,
                            unsigned short* __restrict__ kvn, unsigned short* __restrict__ kh) {
  const int n = blockIdx.x;
  const int b = n >> 11, s = n & 2047;
  const int tid = threadIdx.x;
  const float a = alpha[0];
  const float* src = kvf + (long)n * 576;
  unsigned short* dst = kvn + (long)n * 512;
#pragma unroll
  for (int c0 = 0; c0 < 512; c0 += 256) {
    int c = c0 + tid;
    float v = tanhf(a * src[c]) * gamma[c] + beta[c];
    dst[c] = bf16r(v);
  }
  if (tid < 32) {
    int i = tid;
    float re = src[512 + 2 * i], im = src[512 + 2 * i + 1];
    float co = fc[s * 32 + i], si = fs[s * 32 + i];
    ushort2 v;
    v.x = bf16r(re * co - im * si);
    v.y = bf16r(re * si + im * co);
#pragma unroll
    for (int h = 0; h < 16; h++)
      *(ushort2*)&kh[((long)(b * 16 + h) * 2048 + s) * 192 + 128 + 2 * i] = v;
  }
}

// ---------- q rope fixup: in-place rotate q192[...][128:192) (values pre-scaled) ----------
__global__ void q_ropefix(unsigned short* __restrict__ q192, const float* __restrict__ fc,
                          const float* __restrict__ fs) {
  const int n = blockIdx.x;
  const int b = n >> 11, s = n & 2047;
  const int tid = threadIdx.x;
  for (int it = tid; it < 512; it += 256) {
    int h = it >> 5, i = it & 31;
    unsigned short* dd = q192 + ((long)(b * 16 + h) * 2048 + s) * 192 + 128 + 2 * i;
    float re = bf2f(dd[0]), im = bf2f(dd[1]);
    float co = fc[s * 32 + i], si = fs[s * 32 + i];
    ushort2 o;
    o.x = bf16r(re * co - im * si);
    o.y = bf16r(re * si + im * co);
    *(ushort2*)dd = o;
  }
}

// ---------- host launcher ----------
extern "C" void kernel_launch(void* const* d_in, const int* in_sizes, int n_in,
                              void* d_out, int out_size, void* d_ws, size_t ws_size,
                              hipStream_t stream) {
  const float* x = (const float*)d_in[0];
  const float* fc = (const float*)d_in[1];
  const float* fs = (const float*)d_in[2];
  const float* wq = (const float*)d_in[3];
  const float* wkva = (const float*)d_in[4];
  const float* wkvb = (const float*)d_in[5];
  const float* wo = (const float*)d_in[6];
  const float* alpha = (const float*)d_in[7];
  const float* gamma = (const float*)d_in[8];
  const float* beta = (const float*)d_in[9];
  float* out = (float*)d_out;

  char* p = (char*)d_ws;
  auto take = [&](size_t bytes) {
    char* r = p;
    p += (bytes + 255) & ~(size_t)255;
    return r;
  };
  unsigned short* wqb   = (unsigned short*)take(6291456ull * 2);    // wq bf16 [3072][2048]
  float*          kvf   = (float*)take(2359296ull * 4);             // kv_full f32 [4096][576]
  unsigned short* xb    = (unsigned short*)take(8388608ull * 2);    // x bf16 [4096][2048]
  unsigned short* wab   = (unsigned short*)take(1310720ull * 2);    // wkv_a bf16 padded [640][2048]
  unsigned short* wbb   = (unsigned short*)take(2097152ull * 2);    // wkv_b bf16 [4096][512]
  unsigned short* wob   = (unsigned short*)take(4194304ull * 2);    // wo bf16 [2048][2048]
  unsigned short* kvn   = (unsigned short*)take(2097152ull * 2);    // [4096][512]
  unsigned short* kh    = (unsigned short*)take(12582912ull * 2);   // [32][2048][192]
  unsigned short* q192  = (unsigned short*)take(12582912ull * 2);   // [32][2048][192]
  unsigned short* vhT   = (unsigned short*)take(8388608ull * 2);    // [32][128][2048]
  unsigned short* o_b   = (unsigned short*)take(8388608ull * 2);    // [4096][2048]

  const float scale = 1.0f / sqrtf(192.0f);

  // fused conversions
  conv_all<<<21760, 256, 0, stream>>>(x, wq, wkva, wkvb, wo, xb, wqb, wab, wbb, wob);

  // q192 = scale * (x @ wq^T) scattered head-major -- 8-phase 256x192
  gemm8p<192, 4><<<dim3(16, 16, 1), 512, 0, stream>>>(
      xb, wqb, q192, nullptr, 4096, 2048, 2048, 2048, 192, 0, 0, 0, 0, 0, 0, 0, scale);
  // kv_full = x @ wkv_a^T (f32)
  gemm_bt2<0><<<dim3(32, 5, 1), 256, 0, stream>>>(xb, wab, kvf, nullptr, 4096, 576, 2048,
                                                  2048, 2048, 576, 0, 0, 0, 0, 0, 0, 0, 1.0f);
  // kvn (tanh-norm) + roped k_pe broadcast into kh[...][128:192)
  kv_epilogue<<<4096, 256, 0, stream>>>(kvf, fc, fs, alpha, gamma, beta, kvn, kh);
  // k_abs[h] = kvn @ wk_h^T -> kh[:, :, 0:128) -- 4-wave, grid 512, 2/CU
  gemm4w<1><<<dim3(16, 1, 32), 256, 0, stream>>>(
      kvn, wbb, kh, nullptr, 2048, 512, 512, 512, 192, 4,
      1048576, 0, 0, 131072, 6291456, 393216, 1.0f);
  // rope the pe part of q192 in place
  q_ropefix<<<4096, 256, 0, stream>>>(q192, fc, fs);
  // vhT[g] = wv_h @ kvn_b^T [128][2048] -- 4-wave, grid 512
  gemm4w<1><<<dim3(1, 16, 32), 256, 0, stream>>>(
      wbb + 128 * 512, kvn, vhT, nullptr, 128, 512, 512, 512, 2048, 4,
      0, 131072, 1048576, 0, 4194304, 262144, 1.0f);

  // fused flash attention v2: o_b[b][s][h*128+d] in one dispatch
  attn_fused<<<1024, 256, 0, stream>>>(q192, kh, vhT, o_b);

  // out = o_b @ wo^T (f32) -- 4-wave co-resident, grid 512, L2-rect
  gemm4w<0><<<dim3(32, 16, 1), 256, 0, stream>>>(
      o_b, wob, out, nullptr, 4096, 2048, 2048, 2048, 2048, 0,
      0, 0, 0, 0, 0, 0, 1.0f);
}

// Round 17
// 355.014 us; speedup vs baseline: 1.5713x; 1.0396x over previous
//
#include <hip/hip_runtime.h>
#include <math.h>

// ---------- common types / helpers ----------
typedef __bf16 bf16x8 __attribute__((ext_vector_type(8)));
typedef float f32x4 __attribute__((ext_vector_type(4)));

#define LOG2E 1.4426950408889634f

__device__ __forceinline__ unsigned short bf16r(float f) {
  unsigned u = __float_as_uint(f);
  u = (u + 0x7fffu + ((u >> 16) & 1u)) >> 16;
  return (unsigned short)u;
}
__device__ __forceinline__ unsigned short bfc(float f) {
  __bf16 h = (__bf16)f;                      // HW RNE convert
  return __builtin_bit_cast(unsigned short, h);
}
__device__ __forceinline__ float bf2f(unsigned short h) {
  return __uint_as_float(((unsigned)h) << 16);
}

// async global->LDS, 16B per lane; LDS dest is wave-uniform base + lane*16B (linear)
#define GLOAD16(gsrc, ldst)                                                        \
  __builtin_amdgcn_global_load_lds(                                                \
      (const __attribute__((address_space(1))) void*)(gsrc),                       \
      (__attribute__((address_space(3))) void*)(ldst), 16, 0, 0)

// Block mapping: XCD-aware. gz==1 grids: L2-rect; batched: chunked z-locality.
__device__ __forceinline__ void map_block(int& bx, int& by, int& z) {
  const int gx = gridDim.x, gy = gridDim.y;
  const int nwg = gx * gy * gridDim.z;
  int id = blockIdx.x + gx * (blockIdx.y + gy * blockIdx.z);
  if (gridDim.z == 1 && (gx & 3) == 0 && (gy & 1) == 0 && (nwg & 7) == 0) {
    const int xcd = id & 7, k = id >> 3;
    const int rx = gx >> 2, ry = gy >> 1;
    bx = (xcd & 3) * rx + (k % rx);
    by = (xcd >> 2) * ry + (k / rx);
    z = 0;
  } else {
    if ((nwg & 7) == 0) id = (id & 7) * (nwg >> 3) + (id >> 3);
    bx = id % gx;
    const int t1 = id / gx;
    by = t1 % gy;
    z = t1 / gy;
  }
}

// ---------- fused conversion kernel: all 5 f32->bf16 weight/input converts ----------
__global__ void conv_all(const float* __restrict__ x, const float* __restrict__ wq,
                         const float* __restrict__ wkva, const float* __restrict__ wkvb,
                         const float* __restrict__ wo,
                         unsigned short* __restrict__ xb, unsigned short* __restrict__ wqb,
                         unsigned short* __restrict__ wab, unsigned short* __restrict__ wbb,
                         unsigned short* __restrict__ wob) {
  int bid = blockIdx.x;
  const float* src; unsigned short* dst; long nsrc;
  if (bid < 8192)       {               src = x;    dst = xb;  nsrc = 8388608; }
  else if (bid < 14336) { bid -= 8192;  src = wq;   dst = wqb; nsrc = 6291456; }
  else if (bid < 15616) { bid -= 14336; src = wkva; dst = wab; nsrc = 1179648; } // pad to 640 rows
  else if (bid < 17664) { bid -= 15616; src = wkvb; dst = wbb; nsrc = 2097152; }
  else                  { bid -= 17664; src = wo;   dst = wob; nsrc = 4194304; }
  long i = ((long)bid * 256 + threadIdx.x) * 4;
  ushort4 o;
  if (i < nsrc) {
    float4 v = *(const float4*)&src[i];
    o.x = bf16r(v.x); o.y = bf16r(v.y); o.z = bf16r(v.z); o.w = bf16r(v.w);
  } else {
    o.x = 0; o.y = 0; o.z = 0; o.w = 0;
  }
  *(ushort4*)&dst[i] = o;
}

// =====================================================================
// 8-phase deep-pipelined GEMM (m201-style). BM=256, 8 waves 2Mx4N,
// BK=64, dbuf-2 LDS, 2 K-tiles per iter + odd-nt tail. (q-proj)
// MODE: 0 f32*alpha; 4 scatter into q192 [b*16+by][s][192].
// =====================================================================
template <int BN, int MODE>
__global__ __launch_bounds__(512) void gemm8p(
    const unsigned short* __restrict__ A, const unsigned short* __restrict__ B,
    void* __restrict__ Cv, float* __restrict__ laux,
    int Mrows, int K, int lda, int ldb, int ldc, int zs,
    long sAh, long sAl, long sBh, long sBl, long sCh, long sCl, float alpha)
{
  constexpr int BM = 256;
  constexpr int WN = BN / 4;
  constexpr int NR = WN / 16;
  constexpr int BU = BN / 64;
  constexpr int BU1 = (BU + 1) / 2;

  __shared__ unsigned short As[2][BM * 64];
  __shared__ unsigned short Bs[2][BN * 64];

  const int tid = threadIdx.x;
  const int w = tid >> 6, l = tid & 63, lg = l & 15, lh = l >> 4;
  const int wmi = w >> 2, wni = w & 3;
  const int lrow = l >> 3;
  const int swz8 = ((l & 7) ^ lrow) * 8;

  int bx, by, z;
  map_block(bx, by, z);
  const int zh = z >> zs, zl = z & ((1 << zs) - 1);

  const unsigned short* Ab = A + zh * sAh + zl * sAl + (long)(bx * BM) * lda;
  const unsigned short* Bb = B + zh * sBh + zl * sBl + (long)(by * BN) * ldb;

  const int nt = K >> 6;

  auto stA = [&](int T, int u) {
    if (T >= nt) return;
    const int rr = u * 64 + w * 8;
    GLOAD16(Ab + (long)(rr + lrow) * lda + (T << 6) + swz8, &As[T & 1][rr * 64]);
  };
  auto stB = [&](int T, int u) {
    if (T >= nt) return;
    const int rr = u * 64 + w * 8;
    GLOAD16(Bb + (long)(rr + lrow) * ldb + (T << 6) + swz8, &Bs[T & 1][rr * 64]);
  };

  stA(0, 0); stA(0, 1); stA(0, 2); stA(0, 3);
#pragma unroll
  for (int u = 0; u < BU; ++u) stB(0, u);
  stA(1, 0); stA(1, 2);

  f32x4 acc[8][NR] = {};

  const int nit = nt >> 1;
  for (int i = 0; i < nit; ++i) {
    const int t0 = 2 * i;
#pragma unroll
    for (int j = 0; j < 8; ++j) {
      const int tau = t0 + (j >> 2);
      const int jj = j & 3;
      const int mh = jj & 1, kh = jj >> 1;
      if (jj == 0) {
        if (tau + 1 < nt) asm volatile("s_waitcnt vmcnt(2)" ::: "memory");
        else              asm volatile("s_waitcnt vmcnt(0)" ::: "memory");
      } else {
        asm volatile("" ::: "memory");
      }
      __builtin_amdgcn_s_barrier();
      if (j == 0)      { stA(t0 + 1, 1); stA(t0 + 1, 3); }
      else if (j == 1) { for (int u = 0; u < BU1; ++u) stB(t0 + 1, u); }
      else if (j == 2) { for (int u = BU1; u < BU; ++u) stB(t0 + 1, u); }
      else if (j == 3) { stA(t0 + 2, 0); stA(t0 + 2, 2); }
      else if (j == 4) { stA(t0 + 2, 1); stA(t0 + 2, 3); }
      else if (j == 5) { for (int u = 0; u < BU1; ++u) stB(t0 + 2, u); }
      else if (j == 6) { for (int u = BU1; u < BU; ++u) stB(t0 + 2, u); }
      else             { stA(t0 + 3, 0); stA(t0 + 3, 2); }
      const unsigned short* bA = As[tau & 1];
      const unsigned short* bB = Bs[tau & 1];
      const int rswz = ((kh * 4 + lh) ^ (lg & 7)) * 8;
      bf16x8 af[4], bf[NR];
#pragma unroll
      for (int mi = 0; mi < 4; ++mi)
        af[mi] = *(const bf16x8*)&bA[(wmi * 128 + mh * 64 + mi * 16 + lg) * 64 + rswz];
#pragma unroll
      for (int ni = 0; ni < NR; ++ni)
        bf[ni] = *(const bf16x8*)&bB[(wni * WN + ni * 16 + lg) * 64 + rswz];
      __builtin_amdgcn_s_setprio(1);
#pragma unroll
      for (int mi = 0; mi < 4; ++mi)
#pragma unroll
        for (int ni = 0; ni < NR; ++ni)
          acc[mh * 4 + mi][ni] = __builtin_amdgcn_mfma_f32_16x16x32_bf16(
              af[mi], bf[ni], acc[mh * 4 + mi][ni], 0, 0, 0);
      __builtin_amdgcn_s_setprio(0);
    }
  }

  if (nt & 1) {
    const int tau = nt - 1;
    asm volatile("s_waitcnt vmcnt(0)" ::: "memory");
    __builtin_amdgcn_s_barrier();
    const unsigned short* bA = As[tau & 1];
    const unsigned short* bB = Bs[tau & 1];
#pragma unroll
    for (int jj = 0; jj < 4; ++jj) {
      const int mh = jj & 1, kh = jj >> 1;
      const int rswz = ((kh * 4 + lh) ^ (lg & 7)) * 8;
      bf16x8 af[4], bf[NR];
#pragma unroll
      for (int mi = 0; mi < 4; ++mi)
        af[mi] = *(const bf16x8*)&bA[(wmi * 128 + mh * 64 + mi * 16 + lg) * 64 + rswz];
#pragma unroll
      for (int ni = 0; ni < NR; ++ni)
        bf[ni] = *(const bf16x8*)&bB[(wni * WN + ni * 16 + lg) * 64 + rswz];
      __builtin_amdgcn_s_setprio(1);
#pragma unroll
      for (int mi = 0; mi < 4; ++mi)
#pragma unroll
        for (int ni = 0; ni < NR; ++ni)
          acc[mh * 4 + mi][ni] = __builtin_amdgcn_mfma_f32_16x16x32_bf16(
              af[mi], bf[ni], acc[mh * 4 + mi][ni], 0, 0, 0);
      __builtin_amdgcn_s_setprio(0);
    }
  }

  const int row0 = bx * BM + wmi * 128;
  const int col0 = by * BN + wni * WN;
  const long coff = (long)zh * sCh + (long)zl * sCl;

  if (MODE == 4) {
#pragma unroll
    for (int mi = 0; mi < 8; ++mi)
#pragma unroll
      for (int r = 0; r < 4; ++r) {
        const int row = row0 + mi * 16 + lh * 4 + r;
        unsigned short* dq = (unsigned short*)Cv +
            (long)(row >> 11) * 6291456 + (long)by * 393216 + (long)(row & 2047) * 192;
#pragma unroll
        for (int ni = 0; ni < NR; ++ni)
          dq[wni * WN + ni * 16 + lg] = bf16r(acc[mi][ni][r] * alpha);
      }
  } else {
#pragma unroll
    for (int mi = 0; mi < 8; ++mi)
#pragma unroll
      for (int r = 0; r < 4; ++r) {
        const int row = row0 + mi * 16 + lh * 4 + r;
#pragma unroll
        for (int ni = 0; ni < NR; ++ni) {
          float v = acc[mi][ni][r] * alpha;
          if (MODE == 0)
            ((float*)Cv)[coff + (long)row * ldc + col0 + ni * 16 + lg] = v;
          else
            ((unsigned short*)Cv)[coff + (long)row * ldc + col0 + ni * 16 + lg] = bf16r(v);
        }
      }
  }
}

// =====================================================================
// 4-wave co-resident GEMM: 256 threads (2Mx2N waves), BM=BN=128, BK=64,
// dbuf-2, 64KB LDS -> 2 blocks/CU. (kabs / vhT / out-proj)
// MODE: 0 f32*alpha; 1 bf16*alpha.
// =====================================================================
template <int MODE>
__global__ __launch_bounds__(256) void gemm4w(
    const unsigned short* __restrict__ A, const unsigned short* __restrict__ B,
    void* __restrict__ Cv, float* __restrict__ laux,
    int Mrows, int K, int lda, int ldb, int ldc, int zs,
    long sAh, long sAl, long sBh, long sBl, long sCh, long sCl, float alpha)
{
  constexpr int BM = 128, BN = 128, WN = 64, NR = 4;

  __shared__ unsigned short As[2][BM * 64];
  __shared__ unsigned short Bs[2][BN * 64];

  const int tid = threadIdx.x;
  const int w = tid >> 6, l = tid & 63, lg = l & 15, lh = l >> 4;
  const int wmi = w >> 1, wni = w & 1;
  const int lrow = l >> 3;
  const int swz8 = ((l & 7) ^ lrow) * 8;

  int bx, by, z;
  map_block(bx, by, z);
  const int zh = z >> zs, zl = z & ((1 << zs) - 1);

  const unsigned short* Ab = A + zh * sAh + zl * sAl + (long)(bx * BM) * lda;
  const unsigned short* Bb = B + zh * sBh + zl * sBl + (long)(by * BN) * ldb;

  const int nt = K >> 6;

  auto stage = [&](int T) {
    const int k0 = T << 6;
    const int d = T & 1;
#pragma unroll
    for (int u = 0; u < 4; ++u) {
      const int rr = u * 32 + w * 8;
      GLOAD16(Ab + (long)(rr + lrow) * lda + k0 + swz8, &As[d][rr * 64]);
    }
#pragma unroll
    for (int u = 0; u < 4; ++u) {
      const int rr = u * 32 + w * 8;
      GLOAD16(Bb + (long)(rr + lrow) * ldb + k0 + swz8, &Bs[d][rr * 64]);
    }
  };

  f32x4 acc[4][NR] = {};

  stage(0);
  for (int t = 0; t < nt; ++t) {
    asm volatile("s_waitcnt vmcnt(0)" ::: "memory");
    __builtin_amdgcn_s_barrier();
    if (t + 1 < nt) stage(t + 1);
    const unsigned short* bA = As[t & 1];
    const unsigned short* bB = Bs[t & 1];
#pragma unroll
    for (int kh = 0; kh < 2; ++kh) {
      const int rswz = ((kh * 4 + lh) ^ (lg & 7)) * 8;
      bf16x8 af[4], bf[NR];
#pragma unroll
      for (int mi = 0; mi < 4; ++mi)
        af[mi] = *(const bf16x8*)&bA[(wmi * 64 + mi * 16 + lg) * 64 + rswz];
#pragma unroll
      for (int ni = 0; ni < NR; ++ni)
        bf[ni] = *(const bf16x8*)&bB[(wni * WN + ni * 16 + lg) * 64 + rswz];
      __builtin_amdgcn_s_setprio(1);
#pragma unroll
      for (int mi = 0; mi < 4; ++mi)
#pragma unroll
        for (int ni = 0; ni < NR; ++ni)
          acc[mi][ni] = __builtin_amdgcn_mfma_f32_16x16x32_bf16(
              af[mi], bf[ni], acc[mi][ni], 0, 0, 0);
      __builtin_amdgcn_s_setprio(0);
    }
  }

  const int row0 = bx * BM + wmi * 64;
  const int col0 = by * BN + wni * WN;
  const long coff = (long)zh * sCh + (long)zl * sCl;

#pragma unroll
  for (int mi = 0; mi < 4; ++mi)
#pragma unroll
    for (int r = 0; r < 4; ++r) {
      const int row = row0 + mi * 16 + lh * 4 + r;
#pragma unroll
      for (int ni = 0; ni < NR; ++ni) {
        float v = acc[mi][ni][r] * alpha;
        if (MODE == 0)
          ((float*)Cv)[coff + (long)row * ldc + col0 + ni * 16 + lg] = v;
        else
          ((unsigned short*)Cv)[coff + (long)row * ldc + col0 + ni * 16 + lg] = bf16r(v);
      }
    }
}

// =====================================================================
// Fused flash attention v3: 512 threads / 8 waves (2M x 4N), 64 q-rows x
// one z per block -> 16 waves/CU (4/SIMD) for TLP. Q frags in VGPRs;
// K in LDS dbuf (3 gloads/wave/tile); V single-buffered regs issued at
// tile top (consumed after QK+softmax; issued before stageK so the vf
// wait leaves K-stage in flight); P in LDS (fixed-max softmax);
// row-sums l via ones-MFMA. LDS 57KB -> 2 blocks/CU.
// =====================================================================
__global__ __launch_bounds__(512, 4) void attn_fused(
    const unsigned short* __restrict__ q192, const unsigned short* __restrict__ kh,
    const unsigned short* __restrict__ vhT, unsigned short* __restrict__ o_b)
{
  __shared__ unsigned short Ks[2][3 * 64 * 64];   // 3 units [64 keys][64 d]
  __shared__ unsigned short Ps[64 * 72];          // [row][key], padded

  const int tid = threadIdx.x;
  const int w = tid >> 6, l = tid & 63, lg = l & 15, lh = l >> 4;
  const int wmi = w >> 2, wni = w & 3;            // 2 M-waves x 4 N-waves
  const int lrow = l >> 3;
  const int swz8 = ((l & 7) ^ lrow) * 8;

  int id = blockIdx.x;                            // 1024 blocks
  id = (id & 7) * 128 + (id >> 3);                // chunked: 4 z per XCD
  const int bx = id & 31;
  const int z = id >> 5;
  const int b = z >> 4, hh = z & 15;

  const unsigned short* Qg = q192 + (long)z * 393216 + (long)(bx * 64) * 192;
  const unsigned short* Kg = kh + (long)z * 393216;
  const unsigned short* Vg = vhT + (long)z * 262144;

  // Q fragments in registers: rows wmi*32 + mi*16 + lg, k = s*32 + lh*8
  bf16x8 qf[2][6];
#pragma unroll
  for (int mi = 0; mi < 2; ++mi)
#pragma unroll
    for (int s = 0; s < 6; ++s)
      qf[mi][s] = *(const bf16x8*)&Qg[(wmi * 32 + mi * 16 + lg) * 192 + s * 32 + lh * 8];

  bf16x8 ones;
#pragma unroll
  for (int j = 0; j < 8; ++j) ((unsigned short*)&ones)[j] = 0x3F80;

  // stage K tile T: 3 units of [64 keys][64 d]; 8 waves x 8 rows each
  auto stageK = [&](int T) {
    if (T >= 32) return;
    const unsigned short* src = Kg + (long)(T * 64) * 192;
    unsigned short* dst = Ks[T & 1];
#pragma unroll
    for (int u = 0; u < 3; ++u) {
      const int rr = w * 8;
      GLOAD16(src + (long)(rr + lrow) * 192 + u * 64 + swz8, &dst[u * 4096 + rr * 64]);
    }
  };

  f32x4 acc_o[2][2] = {};
  f32x4 accl[2] = {};

  stageK(0);
  for (int t = 0; t < 32; ++t) {
    asm volatile("s_waitcnt vmcnt(0)" ::: "memory");
    __builtin_amdgcn_s_barrier();                 // K(t) staged; P(t-1) consumed
    // V frags for THIS tile (wave's O cols = wni*32..+32), issued early:
    // consumed after QK+softmax (~300cyc cover). Issued BEFORE stageK(t+1)
    // so the auto vf-wait leaves the K-stage loads in flight.
    bf16x8 vf[4];                                 // j = k2*2 + n
#pragma unroll
    for (int j = 0; j < 4; ++j)
      vf[j] = *(const bf16x8*)&Vg[(long)(wni * 32 + (j & 1) * 16 + lg) * 2048 +
                                  t * 64 + (j >> 1) * 32 + lh * 8];
    stageK(t + 1);                                // fire-and-forget -> Ks[(t+1)&1]
    const unsigned short* bK = Ks[t & 1];

    // ---- QK: S[64 rows][64 keys]; wave = rows wmi*32, keys wni*16 ----
    f32x4 acc_s[2] = {};
#pragma unroll
    for (int u = 0; u < 3; ++u) {
      bf16x8 kf[2];
#pragma unroll
      for (int half = 0; half < 2; ++half) {
        const int rswz = ((half * 4 + lh) ^ (lg & 7)) * 8;
        kf[half] = *(const bf16x8*)&bK[u * 4096 + (wni * 16 + lg) * 64 + rswz];
      }
      __builtin_amdgcn_s_setprio(1);
#pragma unroll
      for (int half = 0; half < 2; ++half)
#pragma unroll
        for (int mi = 0; mi < 2; ++mi)
          acc_s[mi] = __builtin_amdgcn_mfma_f32_16x16x32_bf16(
              qf[mi][u * 2 + half], kf[half], acc_s[mi], 0, 0, 0);
      __builtin_amdgcn_s_setprio(0);
    }
    // ---- P = exp2(S*LOG2E) (fixed-max), native bf16 convert ----
#pragma unroll
    for (int mi = 0; mi < 2; ++mi)
#pragma unroll
      for (int r = 0; r < 4; ++r)
        Ps[(wmi * 32 + mi * 16 + lh * 4 + r) * 72 + wni * 16 + lg] =
            bfc(exp2f(acc_s[mi][r] * LOG2E));
    __builtin_amdgcn_s_barrier();                 // P complete (K reads also done)

    // ---- PV: O[64][128] += P[64][64] @ V^T (regs); l += P @ ones ----
#pragma unroll
    for (int k2 = 0; k2 < 2; ++k2) {
      bf16x8 pf[2];
#pragma unroll
      for (int mi = 0; mi < 2; ++mi)
        pf[mi] = *(const bf16x8*)&Ps[(wmi * 32 + mi * 16 + lg) * 72 + k2 * 32 + lh * 8];
      __builtin_amdgcn_s_setprio(1);
#pragma unroll
      for (int mi = 0; mi < 2; ++mi) {
        accl[mi] = __builtin_amdgcn_mfma_f32_16x16x32_bf16(pf[mi], ones, accl[mi], 0, 0, 0);
#pragma unroll
        for (int n = 0; n < 2; ++n)
          acc_o[mi][n] = __builtin_amdgcn_mfma_f32_16x16x32_bf16(
              pf[mi], vf[k2 * 2 + n], acc_o[mi][n], 0, 0, 0);
      }
      __builtin_amdgcn_s_setprio(0);
    }
  }

  // ---- epilogue: O / l -> o_b[b*2048 + row][h*128 + d] ----
#pragma unroll
  for (int mi = 0; mi < 2; ++mi)
#pragma unroll
    for (int r = 0; r < 4; ++r) {
      const int row = bx * 64 + wmi * 32 + mi * 16 + lh * 4 + r;
      const float inv = 1.0f / accl[mi][r];
      unsigned short* dst = o_b + (long)(b * 2048 + row) * 2048 + hh * 128 + wni * 32;
#pragma unroll
      for (int n = 0; n < 2; ++n)
        dst[n * 16 + lg] = bfc(acc_o[mi][n][r] * inv);
    }
}

// ---------- generic 128x128 bf16 GEMM (m97-class), odd shapes (kv_full) ----------
template <int MODE>
__global__ __launch_bounds__(256) void gemm_bt2(
    const unsigned short* __restrict__ A, const unsigned short* __restrict__ B,
    void* __restrict__ Cv, float* __restrict__ laux,
    int M, int Nstore, int K, int lda, int ldb, int ldc, int zs,
    long sAh, long sAl, long sBh, long sBl, long sCh, long sCl, float alpha)
{
  __shared__ unsigned short As[128 * 32];
  __shared__ unsigned short Bs[128 * 32];
  const int tid = threadIdx.x;
  const int w = tid >> 6, l = tid & 63, lg = l & 15, lh = l >> 4;

  int bx, by, z;
  map_block(bx, by, z);

  const int zh = z >> zs, zl = z & ((1 << zs) - 1);
  const unsigned short* Ab = A + zh * sAh + zl * sAl + (long)(bx * 128) * lda;
  const unsigned short* Bb = B + zh * sBh + zl * sBl + (long)(by * 128) * ldb;
  const int srow = l >> 2;
  const int scol = (((l & 3) ^ ((l >> 3) & 3)) * 8);
  const int wm = (w >> 1) * 64, wn = (w & 1) * 64;
  f32x4 acc[4][4] = {};

  const long ra0 = (long)(w * 16 + srow) * lda + scol;
  const long ra1 = (long)(64 + w * 16 + srow) * lda + scol;
  const long rb0 = (long)(w * 16 + srow) * ldb + scol;
  const long rb1 = (long)(64 + w * 16 + srow) * ldb + scol;
  unsigned short* lA0 = &As[(w * 16) * 32];
  unsigned short* lA1 = &As[(64 + w * 16) * 32];
  unsigned short* lB0 = &Bs[(w * 16) * 32];
  unsigned short* lB1 = &Bs[(64 + w * 16) * 32];

  const int rsw = ((lh ^ ((lg >> 1) & 3)) * 8);

  for (int k0 = 0; k0 < K; k0 += 32) {
    __syncthreads();
    GLOAD16(Ab + ra0 + k0, lA0);
    GLOAD16(Ab + ra1 + k0, lA1);
    GLOAD16(Bb + rb0 + k0, lB0);
    GLOAD16(Bb + rb1 + k0, lB1);
    __syncthreads();
    bf16x8 af[4], bfr[4];
#pragma unroll
    for (int m = 0; m < 4; m++) af[m] = *(const bf16x8*)&As[(wm + m * 16 + lg) * 32 + rsw];
#pragma unroll
    for (int n = 0; n < 4; n++) bfr[n] = *(const bf16x8*)&Bs[(wn + n * 16 + lg) * 32 + rsw];
#pragma unroll
    for (int m = 0; m < 4; m++)
#pragma unroll
      for (int n = 0; n < 4; n++)
        acc[m][n] = __builtin_amdgcn_mfma_f32_16x16x32_bf16(af[m], bfr[n], acc[m][n], 0, 0, 0);
  }

  const int row0 = bx * 128 + wm, col0 = by * 128 + wn;
  long coff = zh * sCh + zl * sCl;

#pragma unroll
  for (int m = 0; m < 4; m++)
#pragma unroll
    for (int r = 0; r < 4; r++) {
      const int row = row0 + m * 16 + lh * 4 + r;
#pragma unroll
      for (int n = 0; n < 4; n++) {
        int col = col0 + n * 16 + lg;
        if (col < Nstore) {
          float v = acc[m][n][r] * alpha;
          if (MODE == 0)
            ((float*)Cv)[coff + (long)row * ldc + col] = v;
          else
            ((unsigned short*)Cv)[coff + (long)row * ldc + col] = bf16r(v);
        }
      }
    }
}

// ---------- kv epilogue: tanh-norm -> kvn bf16; roped k_pe -> kh[...][128:192) x16 heads ----
__global__ void kv_epilogue(const float* __restrict__ kvf, const float* __restrict__ fc,
                            const float* __restrict__ fs, const float* __restrict__ alpha,
                            const float* __restrict__ gamma, const float* __restrict__ beta,
                            unsigned short* __restrict__ kvn, unsigned short* __restrict__ kh) {
  const int n = blockIdx.x;
  const int b = n >> 11, s = n & 2047;
  const int tid = threadIdx.x;
  const float a = alpha[0];
  const float* src = kvf + (long)n * 576;
  unsigned short* dst = kvn + (long)n * 512;
#pragma unroll
  for (int c0 = 0; c0 < 512; c0 += 256) {
    int c = c0 + tid;
    float v = tanhf(a * src[c]) * gamma[c] + beta[c];
    dst[c] = bf16r(v);
  }
  if (tid < 32) {
    int i = tid;
    float re = src[512 + 2 * i], im = src[512 + 2 * i + 1];
    float co = fc[s * 32 + i], si = fs[s * 32 + i];
    ushort2 v;
    v.x = bf16r(re * co - im * si);
    v.y = bf16r(re * si + im * co);
#pragma unroll
    for (int h = 0; h < 16; h++)
      *(ushort2*)&kh[((long)(b * 16 + h) * 2048 + s) * 192 + 128 + 2 * i] = v;
  }
}

// ---------- q rope fixup: in-place rotate q192[...][128:192) (values pre-scaled) ----------
__global__ void q_ropefix(unsigned short* __restrict__ q192, const float* __restrict__ fc,
                          const float* __restrict__ fs) {
  const int n = blockIdx.x;
  const int b = n >> 11, s = n & 2047;
  const int tid = threadIdx.x;
  for (int it = tid; it < 512; it += 256) {
    int h = it >> 5, i = it & 31;
    unsigned short* dd = q192 + ((long)(b * 16 + h) * 2048 + s) * 192 + 128 + 2 * i;
    float re = bf2f(dd[0]), im = bf2f(dd[1]);
    float co = fc[s * 32 + i], si = fs[s * 32 + i];
    ushort2 o;
    o.x = bf16r(re * co - im * si);
    o.y = bf16r(re * si + im * co);
    *(ushort2*)dd = o;
  }
}

// ---------- host launcher ----------
extern "C" void kernel_launch(void* const* d_in, const int* in_sizes, int n_in,
                              void* d_out, int out_size, void* d_ws, size_t ws_size,
                              hipStream_t stream) {
  const float* x = (const float*)d_in[0];
  const float* fc = (const float*)d_in[1];
  const float* fs = (const float*)d_in[2];
  const float* wq = (const float*)d_in[3];
  const float* wkva = (const float*)d_in[4];
  const float* wkvb = (const float*)d_in[5];
  const float* wo = (const float*)d_in[6];
  const float* alpha = (const float*)d_in[7];
  const float* gamma = (const float*)d_in[8];
  const float* beta = (const float*)d_in[9];
  float* out = (float*)d_out;

  char* p = (char*)d_ws;
  auto take = [&](size_t bytes) {
    char* r = p;
    p += (bytes + 255) & ~(size_t)255;
    return r;
  };
  unsigned short* wqb   = (unsigned short*)take(6291456ull * 2);    // wq bf16 [3072][2048]
  float*          kvf   = (float*)take(2359296ull * 4);             // kv_full f32 [4096][576]
  unsigned short* xb    = (unsigned short*)take(8388608ull * 2);    // x bf16 [4096][2048]
  unsigned short* wab   = (unsigned short*)take(1310720ull * 2);    // wkv_a bf16 padded [640][2048]
  unsigned short* wbb   = (unsigned short*)take(2097152ull * 2);    // wkv_b bf16 [4096][512]
  unsigned short* wob   = (unsigned short*)take(4194304ull * 2);    // wo bf16 [2048][2048]
  unsigned short* kvn   = (unsigned short*)take(2097152ull * 2);    // [4096][512]
  unsigned short* kh    = (unsigned short*)take(12582912ull * 2);   // [32][2048][192]
  unsigned short* q192  = (unsigned short*)take(12582912ull * 2);   // [32][2048][192]
  unsigned short* vhT   = (unsigned short*)take(8388608ull * 2);    // [32][128][2048]
  unsigned short* o_b   = (unsigned short*)take(8388608ull * 2);    // [4096][2048]

  const float scale = 1.0f / sqrtf(192.0f);

  // fused conversions
  conv_all<<<21760, 256, 0, stream>>>(x, wq, wkva, wkvb, wo, xb, wqb, wab, wbb, wob);

  // q192 = scale * (x @ wq^T) scattered head-major -- 8-phase 256x192
  gemm8p<192, 4><<<dim3(16, 16, 1), 512, 0, stream>>>(
      xb, wqb, q192, nullptr, 4096, 2048, 2048, 2048, 192, 0, 0, 0, 0, 0, 0, 0, scale);
  // kv_full = x @ wkv_a^T (f32)
  gemm_bt2<0><<<dim3(32, 5, 1), 256, 0, stream>>>(xb, wab, kvf, nullptr, 4096, 576, 2048,
                                                  2048, 2048, 576, 0, 0, 0, 0, 0, 0, 0, 1.0f);
  // kvn (tanh-norm) + roped k_pe broadcast into kh[...][128:192)
  kv_epilogue<<<4096, 256, 0, stream>>>(kvf, fc, fs, alpha, gamma, beta, kvn, kh);
  // k_abs[h] = kvn @ wk_h^T -> kh[:, :, 0:128) -- 4-wave, grid 512, 2/CU
  gemm4w<1><<<dim3(16, 1, 32), 256, 0, stream>>>(
      kvn, wbb, kh, nullptr, 2048, 512, 512, 512, 192, 4,
      1048576, 0, 0, 131072, 6291456, 393216, 1.0f);
  // rope the pe part of q192 in place
  q_ropefix<<<4096, 256, 0, stream>>>(q192, fc, fs);
  // vhT[g] = wv_h @ kvn_b^T [128][2048] -- 4-wave, grid 512
  gemm4w<1><<<dim3(1, 16, 32), 256, 0, stream>>>(
      wbb + 128 * 512, kvn, vhT, nullptr, 128, 512, 512, 512, 2048, 4,
      0, 131072, 1048576, 0, 4194304, 262144, 1.0f);

  // fused flash attention v3: 512 threads, 16 waves/CU
  attn_fused<<<1024, 512, 0, stream>>>(q192, kh, vhT, o_b);

  // out = o_b @ wo^T (f32) -- 4-wave co-resident, grid 512, L2-rect
  gemm4w<0><<<dim3(32, 16, 1), 256, 0, stream>>>(
      o_b, wob, out, nullptr, 4096, 2048, 2048, 2048, 2048, 0,
      0, 0, 0, 0, 0, 0, 1.0f);
}